// Round 1
// baseline (1160.882 us; speedup 1.0000x reference)
//
#include <hip/hip_runtime.h>
#include <math.h>

#define D_ 512
#define H_ 8
#define DFF_ 2048
#define SLOTS_ 1024
#define TOPK_ 5
#define NTOK_ 8192
#define SEQ_ 1024
#define LN_EPS_ 1e-5f

// ---------------------------------------------------------------- LayerNorm
__global__ __launch_bounds__(256) void ln_kernel(
    const float* __restrict__ x, const float* __restrict__ g,
    const float* __restrict__ be, float* __restrict__ y)
{
    const int row = blockIdx.x;
    const int t = threadIdx.x;
    const float a = x[(size_t)row * D_ + t];
    const float b = x[(size_t)row * D_ + t + 256];
    float s = a + b;
    float ss = a * a + b * b;
#pragma unroll
    for (int off = 32; off; off >>= 1) {
        s += __shfl_xor(s, off);
        ss += __shfl_xor(ss, off);
    }
    __shared__ float rs[4], rss[4];
    if ((t & 63) == 0) { rs[t >> 6] = s; rss[t >> 6] = ss; }
    __syncthreads();
    s = rs[0] + rs[1] + rs[2] + rs[3];
    ss = rss[0] + rss[1] + rss[2] + rss[3];
    const float mu = s * (1.0f / D_);
    const float var = ss * (1.0f / D_) - mu * mu;
    const float r = rsqrtf(var + LN_EPS_);
    y[(size_t)row * D_ + t] = (a - mu) * r * g[t] + be[t];
    y[(size_t)row * D_ + t + 256] = (b - mu) * r * g[t + 256] + be[t + 256];
}

// ------------------------------------------------- normalize memory rows
__global__ __launch_bounds__(64) void mn_kernel(
    const float* __restrict__ mem, float* __restrict__ mn)
{
    const int row = blockIdx.x;
    const int lane = threadIdx.x;
    float v[8];
    float ss = 0.0f;
#pragma unroll
    for (int j = 0; j < 8; ++j) {
        v[j] = mem[(size_t)row * D_ + j * 64 + lane];
        ss += v[j] * v[j];
    }
#pragma unroll
    for (int off = 32; off; off >>= 1) ss += __shfl_xor(ss, off);
    const float inv = 1.0f / fmaxf(sqrtf(ss), 1e-12f);
#pragma unroll
    for (int j = 0; j < 8; ++j)
        mn[(size_t)row * D_ + j * 64 + lane] = v[j] * inv;
}

// ------------------------------------------------- row inverse norms
__global__ __launch_bounds__(64) void rownorm_kernel(
    const float* __restrict__ x, float* __restrict__ invn)
{
    const int row = blockIdx.x;
    const int lane = threadIdx.x;
    float ss = 0.0f;
#pragma unroll
    for (int j = 0; j < 8; ++j) {
        const float v = x[(size_t)row * D_ + j * 64 + lane];
        ss += v * v;
    }
#pragma unroll
    for (int off = 32; off; off >>= 1) ss += __shfl_xor(ss, off);
    if (lane == 0) invn[row] = 1.0f / fmaxf(sqrtf(ss), 1e-12f);
}

// ------------------------------------------------- fp32 NT GEMM, 64x64 tile
enum { EP_BIAS = 0, EP_BIAS_RES = 1, EP_BIAS_GELU = 2, EP_ROWSCALE = 3 };

template <int MODE>
__global__ __launch_bounds__(256) void gemm_nt(
    const float* __restrict__ A, const float* __restrict__ Bm,
    const float* __restrict__ bias, const float* __restrict__ res,
    const float* __restrict__ rowscale, float* __restrict__ C,
    int M, int N, int K)
{
    __shared__ float As[32][68];   // [k][m]
    __shared__ float Bs[32][68];   // [k][n]
    const int tid = threadIdx.x;
    const int tx = tid & 15, ty = tid >> 4;
    const int m0 = blockIdx.x * 64, n0 = blockIdx.y * 64;
    const int f = tid & 7, r = tid >> 3;
    float acc[4][4] = {{0.0f}};

    for (int k0 = 0; k0 < K; k0 += 32) {
#pragma unroll
        for (int i = 0; i < 2; ++i) {
            const int row = r + i * 32;
            const float4 av = *(const float4*)(A + (size_t)(m0 + row) * K + k0 + f * 4);
            const float4 bv = *(const float4*)(Bm + (size_t)(n0 + row) * K + k0 + f * 4);
            As[f * 4 + 0][row] = av.x; As[f * 4 + 1][row] = av.y;
            As[f * 4 + 2][row] = av.z; As[f * 4 + 3][row] = av.w;
            Bs[f * 4 + 0][row] = bv.x; Bs[f * 4 + 1][row] = bv.y;
            Bs[f * 4 + 2][row] = bv.z; Bs[f * 4 + 3][row] = bv.w;
        }
        __syncthreads();
#pragma unroll
        for (int kk = 0; kk < 32; ++kk) {
            const float4 a4 = *(const float4*)&As[kk][ty * 4];
            const float4 b4 = *(const float4*)&Bs[kk][tx * 4];
            const float a[4] = {a4.x, a4.y, a4.z, a4.w};
            const float b[4] = {b4.x, b4.y, b4.z, b4.w};
#pragma unroll
            for (int i = 0; i < 4; ++i)
#pragma unroll
                for (int j = 0; j < 4; ++j)
                    acc[i][j] = fmaf(a[i], b[j], acc[i][j]);
        }
        __syncthreads();
    }

#pragma unroll
    for (int i = 0; i < 4; ++i) {
        const int gm = m0 + ty * 4 + i;
        float vv[4];
#pragma unroll
        for (int j = 0; j < 4; ++j) {
            const int gn = n0 + tx * 4 + j;
            float v = acc[i][j];
            if (MODE == EP_ROWSCALE) {
                v *= rowscale[gm];
            } else {
                v += bias[gn];
                if (MODE == EP_BIAS_RES) v += res[(size_t)gm * N + gn];
                if (MODE == EP_BIAS_GELU)
                    v = 0.5f * v * (1.0f + erff(v * 0.70710678118654752f));
            }
            vv[j] = v;
        }
        float4 o4 = make_float4(vv[0], vv[1], vv[2], vv[3]);
        *(float4*)(C + (size_t)gm * N + n0 + tx * 4) = o4;
    }
}

// ------------------------------------------------- flash attention fp32
__global__ __launch_bounds__(256) void attn_kernel(
    const float* __restrict__ qkv, float* __restrict__ ctx)
{
    const int qt = blockIdx.x;   // 0..15
    const int bh = blockIdx.y;   // 0..63
    const int b = bh >> 3, h = bh & 7;
    const int tok0 = b * SEQ_ + qt * 64;
    const int kbase0 = b * SEQ_;
    const int tid = threadIdx.x;
    const int tx = tid & 15, ty = tid >> 4;

    __shared__ float Qt[64][68];   // [d][m]
    __shared__ float Kt[64][68];   // [d][n]
    __shared__ float Vs[64][68];   // [k][d]
    __shared__ float Ss[64][68];   // [m][k]
    __shared__ float Mrow[64], Lrow[64], Alpha[64], Red[64][4];

    const int qoff = h * 64, koff = 512 + h * 64, voff = 1024 + h * 64;
#pragma unroll
    for (int i = 0; i < 4; ++i) {
        const int idx = tid + i * 256;
        const int rowq = idx >> 4, quad = idx & 15;
        const float4 v = *(const float4*)(qkv + (size_t)(tok0 + rowq) * 1536 + qoff + quad * 4);
        Qt[quad * 4 + 0][rowq] = v.x * 0.125f;
        Qt[quad * 4 + 1][rowq] = v.y * 0.125f;
        Qt[quad * 4 + 2][rowq] = v.z * 0.125f;
        Qt[quad * 4 + 3][rowq] = v.w * 0.125f;
    }
    if (tid < 64) { Mrow[tid] = -INFINITY; Lrow[tid] = 0.0f; }
    float o[4][4] = {{0.0f}};
    __syncthreads();

    for (int kt = 0; kt < 16; ++kt) {
#pragma unroll
        for (int i = 0; i < 4; ++i) {
            const int idx = tid + i * 256;
            const int rowk = idx >> 4, quad = idx & 15;
            const float4 kv = *(const float4*)(qkv + (size_t)(kbase0 + kt * 64 + rowk) * 1536 + koff + quad * 4);
            Kt[quad * 4 + 0][rowk] = kv.x; Kt[quad * 4 + 1][rowk] = kv.y;
            Kt[quad * 4 + 2][rowk] = kv.z; Kt[quad * 4 + 3][rowk] = kv.w;
            const float4 vv = *(const float4*)(qkv + (size_t)(kbase0 + kt * 64 + rowk) * 1536 + voff + quad * 4);
            *(float4*)&Vs[rowk][quad * 4] = vv;
        }
        __syncthreads();

        float s[4][4] = {{0.0f}};
#pragma unroll
        for (int d = 0; d < 64; ++d) {
            const float4 a4 = *(const float4*)&Qt[d][ty * 4];
            const float4 b4 = *(const float4*)&Kt[d][tx * 4];
            const float a[4] = {a4.x, a4.y, a4.z, a4.w};
            const float bb[4] = {b4.x, b4.y, b4.z, b4.w};
#pragma unroll
            for (int i = 0; i < 4; ++i)
#pragma unroll
                for (int j = 0; j < 4; ++j)
                    s[i][j] = fmaf(a[i], bb[j], s[i][j]);
        }
#pragma unroll
        for (int i = 0; i < 4; ++i)
            *(float4*)&Ss[ty * 4 + i][tx * 4] = make_float4(s[i][0], s[i][1], s[i][2], s[i][3]);
        __syncthreads();

        {
            const int rr = tid >> 2, p = tid & 3;
            float mx = -INFINITY;
#pragma unroll
            for (int c = 0; c < 16; ++c) mx = fmaxf(mx, Ss[rr][p * 16 + c]);
            Red[rr][p] = mx;
        }
        __syncthreads();
        if ((tid & 3) == 0) {
            const int rr = tid >> 2;
            float mnew = fmaxf(fmaxf(Red[rr][0], Red[rr][1]), fmaxf(Red[rr][2], Red[rr][3]));
            mnew = fmaxf(mnew, Mrow[rr]);
            Alpha[rr] = expf(Mrow[rr] - mnew);
            Mrow[rr] = mnew;
        }
        __syncthreads();
        {
            const int rr = tid >> 2, p = tid & 3;
            const float mrow = Mrow[rr];
            float sm = 0.0f;
#pragma unroll
            for (int c = 0; c < 16; ++c) {
                const float e = expf(Ss[rr][p * 16 + c] - mrow);
                Ss[rr][p * 16 + c] = e;
                sm += e;
            }
            Red[rr][p] = sm;
        }
        __syncthreads();
        if ((tid & 3) == 0) {
            const int rr = tid >> 2;
            Lrow[rr] = Lrow[rr] * Alpha[rr] + (Red[rr][0] + Red[rr][1] + Red[rr][2] + Red[rr][3]);
        }
#pragma unroll
        for (int i = 0; i < 4; ++i) {
            const float al = Alpha[ty * 4 + i];
#pragma unroll
            for (int j = 0; j < 4; ++j) o[i][j] *= al;
        }
#pragma unroll
        for (int kk = 0; kk < 64; ++kk) {
            const float4 v4 = *(const float4*)&Vs[kk][tx * 4];
#pragma unroll
            for (int i = 0; i < 4; ++i) {
                const float p_ = Ss[ty * 4 + i][kk];
                o[i][0] = fmaf(p_, v4.x, o[i][0]);
                o[i][1] = fmaf(p_, v4.y, o[i][1]);
                o[i][2] = fmaf(p_, v4.z, o[i][2]);
                o[i][3] = fmaf(p_, v4.w, o[i][3]);
            }
        }
        __syncthreads();
    }

#pragma unroll
    for (int i = 0; i < 4; ++i) {
        const int rr = ty * 4 + i;
        const float inv = 1.0f / Lrow[rr];
        const float4 ov = make_float4(o[i][0] * inv, o[i][1] * inv, o[i][2] * inv, o[i][3] * inv);
        *(float4*)(ctx + (size_t)(tok0 + rr) * D_ + h * 64 + tx * 4) = ov;
    }
}

// ------------------------------------------------- top-5 + softmax + gather
__global__ __launch_bounds__(64) void topk_kernel(
    const float* __restrict__ sim, const float* __restrict__ src2,
    const float* __restrict__ mem, const float* __restrict__ rs_ptr,
    float* __restrict__ out)
{
    const int row = blockIdx.x;
    const int lane = threadIdx.x;
    float v[16];
#pragma unroll
    for (int j = 0; j < 16; ++j)
        v[j] = sim[(size_t)row * SLOTS_ + j * 64 + lane];

    float wv[TOPK_];
    int wi[TOPK_];
#pragma unroll
    for (int t = 0; t < TOPK_; ++t) {
        float bv = -INFINITY;
        int bi = 0x7fffffff;
#pragma unroll
        for (int j = 0; j < 16; ++j) {
            const int idx = j * 64 + lane;
            if (v[j] > bv) { bv = v[j]; bi = idx; }
        }
#pragma unroll
        for (int off = 32; off; off >>= 1) {
            const float ov = __shfl_xor(bv, off);
            const int oi = __shfl_xor(bi, off);
            if (ov > bv || (ov == bv && oi < bi)) { bv = ov; bi = oi; }
        }
        wv[t] = bv;
        wi[t] = bi;
#pragma unroll
        for (int j = 0; j < 16; ++j)
            if (j * 64 + lane == bi) v[j] = -INFINITY;
    }

    float m = wv[0];
#pragma unroll
    for (int t = 1; t < TOPK_; ++t) m = fmaxf(m, wv[t]);
    float w[TOPK_], ssum = 0.0f;
#pragma unroll
    for (int t = 0; t < TOPK_; ++t) { w[t] = expf(wv[t] - m); ssum += w[t]; }
    const float scale = rs_ptr[0] / ssum;

#pragma unroll
    for (int j = 0; j < 8; ++j) {
        const int d = j * 64 + lane;
        float acc = 0.0f;
#pragma unroll
        for (int t = 0; t < TOPK_; ++t)
            acc += w[t] * mem[(size_t)wi[t] * D_ + d];
        out[(size_t)row * D_ + d] = src2[(size_t)row * D_ + d] + scale * acc;
    }
}

// ----------------------------------------------------------------- launch
extern "C" void kernel_launch(void* const* d_in, const int* in_sizes, int n_in,
                              void* d_out, int out_size, void* d_ws, size_t ws_size,
                              hipStream_t stream)
{
    const float* src  = (const float*)d_in[0];
    const float* inw  = (const float*)d_in[1];
    const float* inb  = (const float*)d_in[2];
    const float* outw = (const float*)d_in[3];
    const float* outb = (const float*)d_in[4];
    const float* mem  = (const float*)d_in[5];
    const float* rs   = (const float*)d_in[6];
    const float* ln1g = (const float*)d_in[7];
    const float* ln1b = (const float*)d_in[8];
    const float* ln2g = (const float*)d_in[9];
    const float* ln2b = (const float*)d_in[10];
    const float* w1   = (const float*)d_in[11];
    const float* b1   = (const float*)d_in[12];
    const float* w2   = (const float*)d_in[13];
    const float* b2   = (const float*)d_in[14];
    float* out = (float*)d_out;
    char* ws = (char*)d_ws;
    const size_t MB = 1024ull * 1024ull;

    float* mn   = (float*)(ws + 0);        // 2 MB      [K0 .. sim gemm]
    float* h    = (float*)(ws + 2 * MB);   // 16 MB     h -> ctx -> h2 (reused)
    float* qkv  = (float*)(ws + 18 * MB);  // 48 MB     [qkv gemm .. attn]
    float* src2 = (float*)(ws + 18 * MB);  // 16 MB     reuse (qkv dead)
    float* sim  = (float*)(ws + 34 * MB);  // 32 MB
    float* invn = (float*)(ws + 66 * MB);  // 32 KB
    float* G    = (float*)(ws + 18 * MB);  // 64 MB     reuse (src2/sim dead)
    float* ctx  = h;
    float* h2   = h;

    // 1) normalize memory rows
    mn_kernel<<<dim3(SLOTS_), dim3(64), 0, stream>>>(mem, mn);
    // 2) LN1
    ln_kernel<<<dim3(NTOK_), dim3(256), 0, stream>>>(src, ln1g, ln1b, h);
    // 3) QKV projection
    gemm_nt<EP_BIAS><<<dim3(128, 24), dim3(256), 0, stream>>>(
        h, inw, inb, nullptr, nullptr, qkv, NTOK_, 1536, 512);
    // 4) attention
    attn_kernel<<<dim3(16, 64), dim3(256), 0, stream>>>(qkv, ctx);
    // 5) out projection + residual
    gemm_nt<EP_BIAS_RES><<<dim3(128, 8), dim3(256), 0, stream>>>(
        ctx, outw, outb, src, nullptr, src2, NTOK_, 512, 512);
    // 6) row norms of src2
    rownorm_kernel<<<dim3(NTOK_), dim3(64), 0, stream>>>(src2, invn);
    // 7) sim = xn @ mn^T
    gemm_nt<EP_ROWSCALE><<<dim3(128, 16), dim3(256), 0, stream>>>(
        src2, mn, nullptr, nullptr, invn, sim, NTOK_, 1024, 512);
    // 8) top-5 + weighted retrieval -> d_out holds src3
    topk_kernel<<<dim3(NTOK_), dim3(64), 0, stream>>>(sim, src2, mem, rs, out);
    // 9) LN2
    ln_kernel<<<dim3(NTOK_), dim3(256), 0, stream>>>(out, ln2g, ln2b, h2);
    // 10) FFN1 + exact GELU
    gemm_nt<EP_BIAS_GELU><<<dim3(128, 32), dim3(256), 0, stream>>>(
        h2, w1, b1, nullptr, nullptr, G, NTOK_, 2048, 512);
    // 11) FFN2 + bias + residual (in-place on d_out)
    gemm_nt<EP_BIAS_RES><<<dim3(128, 8), dim3(256), 0, stream>>>(
        G, w2, b2, out, nullptr, out, NTOK_, 512, 2048);
}

// Round 2
// 650.375 us; speedup vs baseline: 1.7849x; 1.7849x over previous
//
#include <hip/hip_runtime.h>
#include <math.h>

#define D_ 512
#define H_ 8
#define DFF_ 2048
#define SLOTS_ 1024
#define TOPK_ 5
#define NTOK_ 8192
#define SEQ_ 1024
#define LN_EPS_ 1e-5f

typedef __attribute__((ext_vector_type(8))) short bf16x8;
typedef __attribute__((ext_vector_type(4))) float f32x4;

// split fp32 -> bf16 hi + bf16 lo (truncation; rem captured exactly to ~2^-16 rel)
__device__ inline void split2(float x, unsigned short& hi, unsigned short& lo) {
    unsigned u = __builtin_bit_cast(unsigned, x);
    hi = (unsigned short)(u >> 16);
    float h = __builtin_bit_cast(float, u & 0xFFFF0000u);
    float rem = x - h;
    lo = (unsigned short)(__builtin_bit_cast(unsigned, rem) >> 16);
}

// ---------------------------------------------------------------- LayerNorm
__global__ __launch_bounds__(256) void ln_kernel(
    const float* __restrict__ x, const float* __restrict__ g,
    const float* __restrict__ be, float* __restrict__ y)
{
    const int row = blockIdx.x;
    const int t = threadIdx.x;
    const float a = x[(size_t)row * D_ + t];
    const float b = x[(size_t)row * D_ + t + 256];
    float s = a + b;
    float ss = a * a + b * b;
#pragma unroll
    for (int off = 32; off; off >>= 1) {
        s += __shfl_xor(s, off);
        ss += __shfl_xor(ss, off);
    }
    __shared__ float rs[4], rss[4];
    if ((t & 63) == 0) { rs[t >> 6] = s; rss[t >> 6] = ss; }
    __syncthreads();
    s = rs[0] + rs[1] + rs[2] + rs[3];
    ss = rss[0] + rss[1] + rss[2] + rss[3];
    const float mu = s * (1.0f / D_);
    const float var = ss * (1.0f / D_) - mu * mu;
    const float r = rsqrtf(var + LN_EPS_);
    y[(size_t)row * D_ + t] = (a - mu) * r * g[t] + be[t];
    y[(size_t)row * D_ + t + 256] = (b - mu) * r * g[t + 256] + be[t + 256];
}

// ------------------------------------------------- normalize memory rows
__global__ __launch_bounds__(64) void mn_kernel(
    const float* __restrict__ mem, float* __restrict__ mn)
{
    const int row = blockIdx.x;
    const int lane = threadIdx.x;
    float v[8];
    float ss = 0.0f;
#pragma unroll
    for (int j = 0; j < 8; ++j) {
        v[j] = mem[(size_t)row * D_ + j * 64 + lane];
        ss += v[j] * v[j];
    }
#pragma unroll
    for (int off = 32; off; off >>= 1) ss += __shfl_xor(ss, off);
    const float inv = 1.0f / fmaxf(sqrtf(ss), 1e-12f);
#pragma unroll
    for (int j = 0; j < 8; ++j)
        mn[(size_t)row * D_ + j * 64 + lane] = v[j] * inv;
}

// ------------------------------------------------- row inverse norms
__global__ __launch_bounds__(64) void rownorm_kernel(
    const float* __restrict__ x, float* __restrict__ invn)
{
    const int row = blockIdx.x;
    const int lane = threadIdx.x;
    float ss = 0.0f;
#pragma unroll
    for (int j = 0; j < 8; ++j) {
        const float v = x[(size_t)row * D_ + j * 64 + lane];
        ss += v * v;
    }
#pragma unroll
    for (int off = 32; off; off >>= 1) ss += __shfl_xor(ss, off);
    if (lane == 0) invn[row] = 1.0f / fmaxf(sqrtf(ss), 1e-12f);
}

// ------------------------------------------------- MFMA GEMM (NT), 128x128 tile
// SPLIT=3: bf16x3 (fp32-accurate) ; SPLIT=1: plain bf16
enum { EP_BIAS = 0, EP_BIAS_RES = 1, EP_BIAS_GELU = 2, EP_ROWSCALE = 3 };

template <int SPLIT, int MODE>
__global__ __launch_bounds__(256) void gemm_mf(
    const float* __restrict__ A, const float* __restrict__ Bm,
    const float* __restrict__ bias, const float* __restrict__ res,
    const float* __restrict__ rowscale, float* __restrict__ C,
    int M, int N, int K)
{
    // planes: Ah [128][64], (Al), Bh [128][64], (Bl) — bf16, XOR chunk-swizzled
    __shared__ __align__(16) unsigned short sm[(SPLIT == 3 ? 4 : 2) * 8192];
    unsigned short* Ah = sm;
    unsigned short* Al = sm + 8192;                      // only SPLIT==3
    unsigned short* Bh = sm + (SPLIT == 3 ? 16384 : 8192);
    unsigned short* Bl = sm + 24576;                     // only SPLIT==3

    const int tid = threadIdx.x;
    const int lane = tid & 63;
    const int w = tid >> 6;
    const int wr = w >> 1, wc = w & 1;
    const int g = lane >> 4, ln = lane & 15;
    const int m0 = blockIdx.x * 128, n0 = blockIdx.y * 128;
    const int srow = tid >> 1, shalf = tid & 1;

    f32x4 acc[4][4];
#pragma unroll
    for (int i = 0; i < 4; ++i)
#pragma unroll
        for (int j = 0; j < 4; ++j) acc[i][j] = (f32x4){0.f, 0.f, 0.f, 0.f};

    for (int k0 = 0; k0 < K; k0 += 64) {
        // ---- stage A tile: thread -> (row=tid>>1, half=tid&1), 32 floats
        {
            const float* srcp = A + (size_t)(m0 + srow) * K + k0 + shalf * 32;
#pragma unroll
            for (int c4 = 0; c4 < 4; ++c4) {
                const float4 v0 = *(const float4*)(srcp + c4 * 8);
                const float4 v1 = *(const float4*)(srcp + c4 * 8 + 4);
                const float vv[8] = {v0.x, v0.y, v0.z, v0.w, v1.x, v1.y, v1.z, v1.w};
                bf16x8 hv, lv;
#pragma unroll
                for (int e = 0; e < 8; ++e) {
                    unsigned short h16, l16;
                    split2(vv[e], h16, l16);
                    hv[e] = (short)h16;
                    lv[e] = (short)l16;
                }
                const int c = (shalf * 4 + c4) ^ (srow & 7);
                *(bf16x8*)&Ah[srow * 64 + c * 8] = hv;
                if (SPLIT == 3) *(bf16x8*)&Al[srow * 64 + c * 8] = lv;
            }
        }
        // ---- stage B tile
        {
            const float* srcp = Bm + (size_t)(n0 + srow) * K + k0 + shalf * 32;
#pragma unroll
            for (int c4 = 0; c4 < 4; ++c4) {
                const float4 v0 = *(const float4*)(srcp + c4 * 8);
                const float4 v1 = *(const float4*)(srcp + c4 * 8 + 4);
                const float vv[8] = {v0.x, v0.y, v0.z, v0.w, v1.x, v1.y, v1.z, v1.w};
                bf16x8 hv, lv;
#pragma unroll
                for (int e = 0; e < 8; ++e) {
                    unsigned short h16, l16;
                    split2(vv[e], h16, l16);
                    hv[e] = (short)h16;
                    lv[e] = (short)l16;
                }
                const int c = (shalf * 4 + c4) ^ (srow & 7);
                *(bf16x8*)&Bh[srow * 64 + c * 8] = hv;
                if (SPLIT == 3) *(bf16x8*)&Bl[srow * 64 + c * 8] = lv;
            }
        }
        __syncthreads();

#pragma unroll
        for (int ks = 0; ks < 2; ++ks) {
            bf16x8 a_h[4], a_l[4], b_h[4], b_l[4];
#pragma unroll
            for (int mi = 0; mi < 4; ++mi) {
                const int r = wr * 64 + mi * 16 + ln;
                const int c = (ks * 4 + g) ^ (r & 7);
                a_h[mi] = *(const bf16x8*)&Ah[r * 64 + c * 8];
                if (SPLIT == 3) a_l[mi] = *(const bf16x8*)&Al[r * 64 + c * 8];
            }
#pragma unroll
            for (int ni = 0; ni < 4; ++ni) {
                const int r = wc * 64 + ni * 16 + ln;
                const int c = (ks * 4 + g) ^ (r & 7);
                b_h[ni] = *(const bf16x8*)&Bh[r * 64 + c * 8];
                if (SPLIT == 3) b_l[ni] = *(const bf16x8*)&Bl[r * 64 + c * 8];
            }
#pragma unroll
            for (int mi = 0; mi < 4; ++mi)
#pragma unroll
                for (int ni = 0; ni < 4; ++ni) {
                    acc[mi][ni] = __builtin_amdgcn_mfma_f32_16x16x32_bf16(
                        a_h[mi], b_h[ni], acc[mi][ni], 0, 0, 0);
                    if (SPLIT == 3) {
                        acc[mi][ni] = __builtin_amdgcn_mfma_f32_16x16x32_bf16(
                            a_h[mi], b_l[ni], acc[mi][ni], 0, 0, 0);
                        acc[mi][ni] = __builtin_amdgcn_mfma_f32_16x16x32_bf16(
                            a_l[mi], b_h[ni], acc[mi][ni], 0, 0, 0);
                    }
                }
        }
        __syncthreads();
    }

    // ---- epilogue: C/D layout col=lane&15, row=(lane>>4)*4+reg
#pragma unroll
    for (int mi = 0; mi < 4; ++mi) {
#pragma unroll
        for (int ni = 0; ni < 4; ++ni) {
            const int gn = n0 + wc * 64 + ni * 16 + ln;
            const float bz = (MODE == EP_ROWSCALE) ? 0.0f : bias[gn];
#pragma unroll
            for (int r2 = 0; r2 < 4; ++r2) {
                const int gm = m0 + wr * 64 + mi * 16 + g * 4 + r2;
                float v = acc[mi][ni][r2];
                if (MODE == EP_ROWSCALE) {
                    v *= rowscale[gm];
                } else {
                    v += bz;
                    if (MODE == EP_BIAS_RES) v += res[(size_t)gm * N + gn];
                    if (MODE == EP_BIAS_GELU)
                        v = 0.5f * v * (1.0f + erff(v * 0.70710678118654752f));
                }
                C[(size_t)gm * N + gn] = v;
            }
        }
    }
}

// ------------------------------------------------- flash attention fp32
__global__ __launch_bounds__(256) void attn_kernel(
    const float* __restrict__ qkv, float* __restrict__ ctx)
{
    const int qt = blockIdx.x;   // 0..15
    const int bh = blockIdx.y;   // 0..63
    const int b = bh >> 3, h = bh & 7;
    const int tok0 = b * SEQ_ + qt * 64;
    const int kbase0 = b * SEQ_;
    const int tid = threadIdx.x;
    const int tx = tid & 15, ty = tid >> 4;

    __shared__ float Qt[64][68];   // [d][m]
    __shared__ float Kt[64][68];   // [d][n]
    __shared__ float Vs[64][68];   // [k][d]
    __shared__ float Ss[64][68];   // [m][k]
    __shared__ float Mrow[64], Lrow[64], Alpha[64], Red[64][4];

    const int qoff = h * 64, koff = 512 + h * 64, voff = 1024 + h * 64;
#pragma unroll
    for (int i = 0; i < 4; ++i) {
        const int idx = tid + i * 256;
        const int rowq = idx >> 4, quad = idx & 15;
        const float4 v = *(const float4*)(qkv + (size_t)(tok0 + rowq) * 1536 + qoff + quad * 4);
        Qt[quad * 4 + 0][rowq] = v.x * 0.125f;
        Qt[quad * 4 + 1][rowq] = v.y * 0.125f;
        Qt[quad * 4 + 2][rowq] = v.z * 0.125f;
        Qt[quad * 4 + 3][rowq] = v.w * 0.125f;
    }
    if (tid < 64) { Mrow[tid] = -INFINITY; Lrow[tid] = 0.0f; }
    float o[4][4] = {{0.0f}};
    __syncthreads();

    for (int kt = 0; kt < 16; ++kt) {
#pragma unroll
        for (int i = 0; i < 4; ++i) {
            const int idx = tid + i * 256;
            const int rowk = idx >> 4, quad = idx & 15;
            const float4 kv = *(const float4*)(qkv + (size_t)(kbase0 + kt * 64 + rowk) * 1536 + koff + quad * 4);
            Kt[quad * 4 + 0][rowk] = kv.x; Kt[quad * 4 + 1][rowk] = kv.y;
            Kt[quad * 4 + 2][rowk] = kv.z; Kt[quad * 4 + 3][rowk] = kv.w;
            const float4 vv = *(const float4*)(qkv + (size_t)(kbase0 + kt * 64 + rowk) * 1536 + voff + quad * 4);
            *(float4*)&Vs[rowk][quad * 4] = vv;
        }
        __syncthreads();

        float s[4][4] = {{0.0f}};
#pragma unroll
        for (int d = 0; d < 64; ++d) {
            const float4 a4 = *(const float4*)&Qt[d][ty * 4];
            const float4 b4 = *(const float4*)&Kt[d][tx * 4];
            const float a[4] = {a4.x, a4.y, a4.z, a4.w};
            const float bb[4] = {b4.x, b4.y, b4.z, b4.w};
#pragma unroll
            for (int i = 0; i < 4; ++i)
#pragma unroll
                for (int j = 0; j < 4; ++j)
                    s[i][j] = fmaf(a[i], bb[j], s[i][j]);
        }
#pragma unroll
        for (int i = 0; i < 4; ++i)
            *(float4*)&Ss[ty * 4 + i][tx * 4] = make_float4(s[i][0], s[i][1], s[i][2], s[i][3]);
        __syncthreads();

        {
            const int rr = tid >> 2, p = tid & 3;
            float mx = -INFINITY;
#pragma unroll
            for (int c = 0; c < 16; ++c) mx = fmaxf(mx, Ss[rr][p * 16 + c]);
            Red[rr][p] = mx;
        }
        __syncthreads();
        if ((tid & 3) == 0) {
            const int rr = tid >> 2;
            float mnew = fmaxf(fmaxf(Red[rr][0], Red[rr][1]), fmaxf(Red[rr][2], Red[rr][3]));
            mnew = fmaxf(mnew, Mrow[rr]);
            Alpha[rr] = expf(Mrow[rr] - mnew);
            Mrow[rr] = mnew;
        }
        __syncthreads();
        {
            const int rr = tid >> 2, p = tid & 3;
            const float mrow = Mrow[rr];
            float sm_ = 0.0f;
#pragma unroll
            for (int c = 0; c < 16; ++c) {
                const float e = expf(Ss[rr][p * 16 + c] - mrow);
                Ss[rr][p * 16 + c] = e;
                sm_ += e;
            }
            Red[rr][p] = sm_;
        }
        __syncthreads();
        if ((tid & 3) == 0) {
            const int rr = tid >> 2;
            Lrow[rr] = Lrow[rr] * Alpha[rr] + (Red[rr][0] + Red[rr][1] + Red[rr][2] + Red[rr][3]);
        }
#pragma unroll
        for (int i = 0; i < 4; ++i) {
            const float al = Alpha[ty * 4 + i];
#pragma unroll
            for (int j = 0; j < 4; ++j) o[i][j] *= al;
        }
#pragma unroll
        for (int kk = 0; kk < 64; ++kk) {
            const float4 v4 = *(const float4*)&Vs[kk][tx * 4];
#pragma unroll
            for (int i = 0; i < 4; ++i) {
                const float p_ = Ss[ty * 4 + i][kk];
                o[i][0] = fmaf(p_, v4.x, o[i][0]);
                o[i][1] = fmaf(p_, v4.y, o[i][1]);
                o[i][2] = fmaf(p_, v4.z, o[i][2]);
                o[i][3] = fmaf(p_, v4.w, o[i][3]);
            }
        }
        __syncthreads();
    }

#pragma unroll
    for (int i = 0; i < 4; ++i) {
        const int rr = ty * 4 + i;
        const float inv = 1.0f / Lrow[rr];
        const float4 ov = make_float4(o[i][0] * inv, o[i][1] * inv, o[i][2] * inv, o[i][3] * inv);
        *(float4*)(ctx + (size_t)(tok0 + rr) * D_ + h * 64 + tx * 4) = ov;
    }
}

// ------------------------------------------------- top-5 + softmax + gather
__global__ __launch_bounds__(64) void topk_kernel(
    const float* __restrict__ sim, const float* __restrict__ src2,
    const float* __restrict__ mem, const float* __restrict__ rs_ptr,
    float* __restrict__ out)
{
    const int row = blockIdx.x;
    const int lane = threadIdx.x;
    float v[16];
#pragma unroll
    for (int j = 0; j < 16; ++j)
        v[j] = sim[(size_t)row * SLOTS_ + j * 64 + lane];

    float wv[TOPK_];
    int wi[TOPK_];
#pragma unroll
    for (int t = 0; t < TOPK_; ++t) {
        float bv = -INFINITY;
        int bi = 0x7fffffff;
#pragma unroll
        for (int j = 0; j < 16; ++j) {
            const int idx = j * 64 + lane;
            if (v[j] > bv) { bv = v[j]; bi = idx; }
        }
#pragma unroll
        for (int off = 32; off; off >>= 1) {
            const float ov = __shfl_xor(bv, off);
            const int oi = __shfl_xor(bi, off);
            if (ov > bv || (ov == bv && oi < bi)) { bv = ov; bi = oi; }
        }
        wv[t] = bv;
        wi[t] = bi;
#pragma unroll
        for (int j = 0; j < 16; ++j)
            if (j * 64 + lane == bi) v[j] = -INFINITY;
    }

    float m = wv[0];
#pragma unroll
    for (int t = 1; t < TOPK_; ++t) m = fmaxf(m, wv[t]);
    float w[TOPK_], ssum = 0.0f;
#pragma unroll
    for (int t = 0; t < TOPK_; ++t) { w[t] = expf(wv[t] - m); ssum += w[t]; }
    const float scale = rs_ptr[0] / ssum;

#pragma unroll
    for (int j = 0; j < 8; ++j) {
        const int d = j * 64 + lane;
        float acc = 0.0f;
#pragma unroll
        for (int t = 0; t < TOPK_; ++t)
            acc += w[t] * mem[(size_t)wi[t] * D_ + d];
        out[(size_t)row * D_ + d] = src2[(size_t)row * D_ + d] + scale * acc;
    }
}

// ----------------------------------------------------------------- launch
extern "C" void kernel_launch(void* const* d_in, const int* in_sizes, int n_in,
                              void* d_out, int out_size, void* d_ws, size_t ws_size,
                              hipStream_t stream)
{
    const float* src  = (const float*)d_in[0];
    const float* inw  = (const float*)d_in[1];
    const float* inb  = (const float*)d_in[2];
    const float* outw = (const float*)d_in[3];
    const float* outb = (const float*)d_in[4];
    const float* mem  = (const float*)d_in[5];
    const float* rs   = (const float*)d_in[6];
    const float* ln1g = (const float*)d_in[7];
    const float* ln1b = (const float*)d_in[8];
    const float* ln2g = (const float*)d_in[9];
    const float* ln2b = (const float*)d_in[10];
    const float* w1   = (const float*)d_in[11];
    const float* b1   = (const float*)d_in[12];
    const float* w2   = (const float*)d_in[13];
    const float* b2   = (const float*)d_in[14];
    float* out = (float*)d_out;
    char* ws = (char*)d_ws;
    const size_t MB = 1024ull * 1024ull;

    float* mn   = (float*)(ws + 0);        // 2 MB      [K0 .. sim gemm]
    float* h    = (float*)(ws + 2 * MB);   // 16 MB     h -> ctx -> h2 (reused)
    float* qkv  = (float*)(ws + 18 * MB);  // 48 MB     [qkv gemm .. attn]
    float* src2 = (float*)(ws + 18 * MB);  // 16 MB     reuse (qkv dead)
    float* sim  = (float*)(ws + 34 * MB);  // 32 MB
    float* invn = (float*)(ws + 66 * MB);  // 32 KB
    float* G    = (float*)(ws + 18 * MB);  // 64 MB     reuse (src2/sim dead)
    float* ctx  = h;
    float* h2   = h;

    // 1) normalize memory rows
    mn_kernel<<<dim3(SLOTS_), dim3(64), 0, stream>>>(mem, mn);
    // 2) LN1
    ln_kernel<<<dim3(NTOK_), dim3(256), 0, stream>>>(src, ln1g, ln1b, h);
    // 3) QKV projection (bf16x3)
    gemm_mf<3, EP_BIAS><<<dim3(64, 12), dim3(256), 0, stream>>>(
        h, inw, inb, nullptr, nullptr, qkv, NTOK_, 1536, 512);
    // 4) attention (fp32)
    attn_kernel<<<dim3(16, 64), dim3(256), 0, stream>>>(qkv, ctx);
    // 5) out projection + residual (bf16x3)
    gemm_mf<3, EP_BIAS_RES><<<dim3(64, 4), dim3(256), 0, stream>>>(
        ctx, outw, outb, src, nullptr, src2, NTOK_, 512, 512);
    // 6) row norms of src2
    rownorm_kernel<<<dim3(NTOK_), dim3(64), 0, stream>>>(src2, invn);
    // 7) sim = (src2 @ mn^T) * invn  (bf16x3)
    gemm_mf<3, EP_ROWSCALE><<<dim3(64, 8), dim3(256), 0, stream>>>(
        src2, mn, nullptr, nullptr, invn, sim, NTOK_, 1024, 512);
    // 8) top-5 + weighted retrieval -> d_out holds src3
    topk_kernel<<<dim3(NTOK_), dim3(64), 0, stream>>>(sim, src2, mem, rs, out);
    // 9) LN2
    ln_kernel<<<dim3(NTOK_), dim3(256), 0, stream>>>(out, ln2g, ln2b, h2);
    // 10) FFN1 + exact GELU (bf16)
    gemm_mf<1, EP_BIAS_GELU><<<dim3(64, 16), dim3(256), 0, stream>>>(
        h2, w1, b1, nullptr, nullptr, G, NTOK_, 2048, 512);
    // 11) FFN2 + bias + residual (bf16, in-place on d_out)
    gemm_mf<1, EP_BIAS_RES><<<dim3(64, 4), dim3(256), 0, stream>>>(
        G, w2, b2, out, nullptr, out, NTOK_, 512, 2048);
}

// Round 4
// 533.361 us; speedup vs baseline: 2.1765x; 1.2194x over previous
//
#include <hip/hip_runtime.h>
#include <math.h>

#define D_ 512
#define H_ 8
#define DFF_ 2048
#define SLOTS_ 1024
#define TOPK_ 5
#define NCAND_ 8
#define NTOK_ 8192
#define SEQ_ 1024
#define LN_EPS_ 1e-5f

typedef __attribute__((ext_vector_type(8))) short bf16x8;
typedef __attribute__((ext_vector_type(4))) float f32x4;

// split fp32 -> bf16 hi + bf16 lo (truncation; rem captured to ~2^-16 rel)
__device__ inline void split2(float x, unsigned short& hi, unsigned short& lo) {
    unsigned u = __builtin_bit_cast(unsigned, x);
    hi = (unsigned short)(u >> 16);
    float h = __builtin_bit_cast(float, u & 0xFFFF0000u);
    float rem = x - h;
    lo = (unsigned short)(__builtin_bit_cast(unsigned, rem) >> 16);
}

// ---------------------------------------------------------------- LayerNorm
__global__ __launch_bounds__(256) void ln_kernel(
    const float* __restrict__ x, const float* __restrict__ g,
    const float* __restrict__ be, float* __restrict__ y)
{
    const int row = blockIdx.x;
    const int t = threadIdx.x;
    const float a = x[(size_t)row * D_ + t];
    const float b = x[(size_t)row * D_ + t + 256];
    float s = a + b;
    float ss = a * a + b * b;
#pragma unroll
    for (int off = 32; off; off >>= 1) {
        s += __shfl_xor(s, off);
        ss += __shfl_xor(ss, off);
    }
    __shared__ float rs[4], rss[4];
    if ((t & 63) == 0) { rs[t >> 6] = s; rss[t >> 6] = ss; }
    __syncthreads();
    s = rs[0] + rs[1] + rs[2] + rs[3];
    ss = rss[0] + rss[1] + rss[2] + rss[3];
    const float mu = s * (1.0f / D_);
    const float var = ss * (1.0f / D_) - mu * mu;
    const float r = rsqrtf(var + LN_EPS_);
    y[(size_t)row * D_ + t] = (a - mu) * r * g[t] + be[t];
    y[(size_t)row * D_ + t + 256] = (b - mu) * r * g[t + 256] + be[t + 256];
}

// ------------------------------------------------- normalize memory rows
__global__ __launch_bounds__(64) void mn_kernel(
    const float* __restrict__ mem, float* __restrict__ mn)
{
    const int row = blockIdx.x;
    const int lane = threadIdx.x;
    float v[8];
    float ss = 0.0f;
#pragma unroll
    for (int j = 0; j < 8; ++j) {
        v[j] = mem[(size_t)row * D_ + j * 64 + lane];
        ss += v[j] * v[j];
    }
#pragma unroll
    for (int off = 32; off; off >>= 1) ss += __shfl_xor(ss, off);
    const float inv = 1.0f / fmaxf(sqrtf(ss), 1e-12f);
#pragma unroll
    for (int j = 0; j < 8; ++j)
        mn[(size_t)row * D_ + j * 64 + lane] = v[j] * inv;
}

// ------------------------------------------------- row inverse norms
__global__ __launch_bounds__(64) void rownorm_kernel(
    const float* __restrict__ x, float* __restrict__ invn)
{
    const int row = blockIdx.x;
    const int lane = threadIdx.x;
    float ss = 0.0f;
#pragma unroll
    for (int j = 0; j < 8; ++j) {
        const float v = x[(size_t)row * D_ + j * 64 + lane];
        ss += v * v;
    }
#pragma unroll
    for (int off = 32; off; off >>= 1) ss += __shfl_xor(ss, off);
    if (lane == 0) invn[row] = 1.0f / fmaxf(sqrtf(ss), 1e-12f);
}

// ------------------------------------------------- MFMA GEMM (NT), 128x128 tile
enum { EP_BIAS = 0, EP_BIAS_RES = 1, EP_BIAS_GELU = 2, EP_ROWSCALE = 3 };

template <int SPLIT, int MODE>
__global__ __launch_bounds__(256) void gemm_mf(
    const float* __restrict__ A, const float* __restrict__ Bm,
    const float* __restrict__ bias, const float* __restrict__ res,
    const float* __restrict__ rowscale, float* __restrict__ C,
    int M, int N, int K)
{
    __shared__ __align__(16) unsigned short sm[(SPLIT == 3 ? 4 : 2) * 8192];
    unsigned short* Ah = sm;
    unsigned short* Al = sm + 8192;
    unsigned short* Bh = sm + (SPLIT == 3 ? 16384 : 8192);
    unsigned short* Bl = sm + 24576;

    const int tid = threadIdx.x;
    const int lane = tid & 63;
    const int w = tid >> 6;
    const int wr = w >> 1, wc = w & 1;
    const int g = lane >> 4, ln = lane & 15;
    const int m0 = blockIdx.x * 128, n0 = blockIdx.y * 128;
    const int srow = tid >> 1, shalf = tid & 1;

    f32x4 acc[4][4];
#pragma unroll
    for (int i = 0; i < 4; ++i)
#pragma unroll
        for (int j = 0; j < 4; ++j) acc[i][j] = (f32x4){0.f, 0.f, 0.f, 0.f};

    for (int k0 = 0; k0 < K; k0 += 64) {
        {
            const float* srcp = A + (size_t)(m0 + srow) * K + k0 + shalf * 32;
#pragma unroll
            for (int c4 = 0; c4 < 4; ++c4) {
                const float4 v0 = *(const float4*)(srcp + c4 * 8);
                const float4 v1 = *(const float4*)(srcp + c4 * 8 + 4);
                const float vv[8] = {v0.x, v0.y, v0.z, v0.w, v1.x, v1.y, v1.z, v1.w};
                bf16x8 hv, lv;
#pragma unroll
                for (int e = 0; e < 8; ++e) {
                    unsigned short h16, l16;
                    split2(vv[e], h16, l16);
                    hv[e] = (short)h16;
                    lv[e] = (short)l16;
                }
                const int c = (shalf * 4 + c4) ^ (srow & 7);
                *(bf16x8*)&Ah[srow * 64 + c * 8] = hv;
                if (SPLIT == 3) *(bf16x8*)&Al[srow * 64 + c * 8] = lv;
            }
        }
        {
            const float* srcp = Bm + (size_t)(n0 + srow) * K + k0 + shalf * 32;
#pragma unroll
            for (int c4 = 0; c4 < 4; ++c4) {
                const float4 v0 = *(const float4*)(srcp + c4 * 8);
                const float4 v1 = *(const float4*)(srcp + c4 * 8 + 4);
                const float vv[8] = {v0.x, v0.y, v0.z, v0.w, v1.x, v1.y, v1.z, v1.w};
                bf16x8 hv, lv;
#pragma unroll
                for (int e = 0; e < 8; ++e) {
                    unsigned short h16, l16;
                    split2(vv[e], h16, l16);
                    hv[e] = (short)h16;
                    lv[e] = (short)l16;
                }
                const int c = (shalf * 4 + c4) ^ (srow & 7);
                *(bf16x8*)&Bh[srow * 64 + c * 8] = hv;
                if (SPLIT == 3) *(bf16x8*)&Bl[srow * 64 + c * 8] = lv;
            }
        }
        __syncthreads();

#pragma unroll
        for (int ks = 0; ks < 2; ++ks) {
            bf16x8 a_h[4], a_l[4], b_h[4], b_l[4];
#pragma unroll
            for (int mi = 0; mi < 4; ++mi) {
                const int r = wr * 64 + mi * 16 + ln;
                const int c = (ks * 4 + g) ^ (r & 7);
                a_h[mi] = *(const bf16x8*)&Ah[r * 64 + c * 8];
                if (SPLIT == 3) a_l[mi] = *(const bf16x8*)&Al[r * 64 + c * 8];
            }
#pragma unroll
            for (int ni = 0; ni < 4; ++ni) {
                const int r = wc * 64 + ni * 16 + ln;
                const int c = (ks * 4 + g) ^ (r & 7);
                b_h[ni] = *(const bf16x8*)&Bh[r * 64 + c * 8];
                if (SPLIT == 3) b_l[ni] = *(const bf16x8*)&Bl[r * 64 + c * 8];
            }
#pragma unroll
            for (int mi = 0; mi < 4; ++mi)
#pragma unroll
                for (int ni = 0; ni < 4; ++ni) {
                    acc[mi][ni] = __builtin_amdgcn_mfma_f32_16x16x32_bf16(
                        a_h[mi], b_h[ni], acc[mi][ni], 0, 0, 0);
                    if (SPLIT == 3) {
                        acc[mi][ni] = __builtin_amdgcn_mfma_f32_16x16x32_bf16(
                            a_h[mi], b_l[ni], acc[mi][ni], 0, 0, 0);
                        acc[mi][ni] = __builtin_amdgcn_mfma_f32_16x16x32_bf16(
                            a_l[mi], b_h[ni], acc[mi][ni], 0, 0, 0);
                    }
                }
        }
        __syncthreads();
    }

#pragma unroll
    for (int mi = 0; mi < 4; ++mi) {
#pragma unroll
        for (int ni = 0; ni < 4; ++ni) {
            const int gn = n0 + wc * 64 + ni * 16 + ln;
            const float bz = (MODE == EP_ROWSCALE) ? 0.0f : bias[gn];
#pragma unroll
            for (int r2 = 0; r2 < 4; ++r2) {
                const int gm = m0 + wr * 64 + mi * 16 + g * 4 + r2;
                float v = acc[mi][ni][r2];
                if (MODE == EP_ROWSCALE) {
                    v *= rowscale[gm];
                } else {
                    v += bz;
                    if (MODE == EP_BIAS_RES) v += res[(size_t)gm * N + gn];
                    if (MODE == EP_BIAS_GELU)
                        v = 0.5f * v * (1.0f + erff(v * 0.70710678118654752f));
                }
                C[(size_t)gm * N + gn] = v;
            }
        }
    }
}

// ------------------------------------------------- flash attention, MFMA bf16x3
#define AST 72   // LDS row stride (bf16 elems) for all attn planes

__global__ __launch_bounds__(256) void attn_kernel(
    const float* __restrict__ qkv, float* __restrict__ ctx)
{
    const int id = blockIdx.x;          // 0..1023
    const int bh = id & 63;             // stride-64 blocks share (b,h) -> same XCD slot
    const int qt = id >> 6;
    const int b = bh >> 3, h = bh & 7;
    const int tok0 = b * SEQ_ + qt * 64;
    const int kbase0 = b * SEQ_;
    const int tid = threadIdx.x;
    const int lane = tid & 63;
    const int w = tid >> 6;             // wave: 16-row m-strip
    const int ln = lane & 15, g = lane >> 4;

    // 6 planes x 64 rows x AST bf16: 0 Qh->Ph, 1 Ql->Pl, 2 Kh, 3 Kl, 4 Vth, 5 Vtl
    __shared__ __align__(16) unsigned short sm[6 * 64 * AST];
    unsigned short* Ph  = sm;
    unsigned short* Pl  = sm + 1 * 64 * AST;
    unsigned short* Kh  = sm + 2 * 64 * AST;
    unsigned short* Kl  = sm + 3 * 64 * AST;
    unsigned short* Vth = sm + 4 * 64 * AST;
    unsigned short* Vtl = sm + 5 * 64 * AST;

    const int qoff = h * 64, koff = 512 + h * 64, voff = 1024 + h * 64;

    // ---- stage Q (scaled) into planes 0/1, then hoist fragments to regs
    {
        const int row = tid >> 2, q4 = tid & 3;
        const float* srcp = qkv + (size_t)(tok0 + row) * 1536 + qoff + q4 * 16;
#pragma unroll
        for (int half = 0; half < 2; ++half) {
            bf16x8 hv, lv;
#pragma unroll
            for (int c = 0; c < 2; ++c) {
                const float4 v = *(const float4*)(srcp + half * 8 + c * 4);
                const float vv[4] = {v.x, v.y, v.z, v.w};
#pragma unroll
                for (int e = 0; e < 4; ++e) {
                    unsigned short h16, l16;
                    split2(vv[e] * 0.125f, h16, l16);
                    hv[c * 4 + e] = (short)h16;
                    lv[c * 4 + e] = (short)l16;
                }
            }
            *(bf16x8*)&Ph[row * AST + q4 * 16 + half * 8] = hv;
            *(bf16x8*)&Pl[row * AST + q4 * 16 + half * 8] = lv;
        }
    }
    __syncthreads();
    bf16x8 qfh[2], qfl[2];
#pragma unroll
    for (int ks = 0; ks < 2; ++ks) {
        qfh[ks] = *(const bf16x8*)&Ph[(w * 16 + ln) * AST + ks * 32 + g * 8];
        qfl[ks] = *(const bf16x8*)&Pl[(w * 16 + ln) * AST + ks * 32 + g * 8];
    }

    f32x4 o[4];
#pragma unroll
    for (int ni = 0; ni < 4; ++ni) o[ni] = (f32x4){0.f, 0.f, 0.f, 0.f};
    float mrow[4] = {-INFINITY, -INFINITY, -INFINITY, -INFINITY};
    float lrow[4] = {0.f, 0.f, 0.f, 0.f};

    for (int kt = 0; kt < 16; ++kt) {
        const int kb2 = kbase0 + kt * 64;
        // ---- stage K (row-major) into planes 2/3
        {
            const int row = tid >> 2, q4 = tid & 3;
            const float* srcp = qkv + (size_t)(kb2 + row) * 1536 + koff + q4 * 16;
#pragma unroll
            for (int half = 0; half < 2; ++half) {
                bf16x8 hv, lv;
#pragma unroll
                for (int c = 0; c < 2; ++c) {
                    const float4 v = *(const float4*)(srcp + half * 8 + c * 4);
                    const float vv[4] = {v.x, v.y, v.z, v.w};
#pragma unroll
                    for (int e = 0; e < 4; ++e) {
                        unsigned short h16, l16;
                        split2(vv[e], h16, l16);
                        hv[c * 4 + e] = (short)h16;
                        lv[c * 4 + e] = (short)l16;
                    }
                }
                *(bf16x8*)&Kh[row * AST + q4 * 16 + half * 8] = hv;
                *(bf16x8*)&Kl[row * AST + q4 * 16 + half * 8] = lv;
            }
        }
        // ---- stage V transposed into planes 4/5 (lane = krow -> contiguous writes)
        {
            const int krow = tid & 63, dc = tid >> 6;
            const float* srcp = qkv + (size_t)(kb2 + krow) * 1536 + voff + dc * 16;
#pragma unroll
            for (int c = 0; c < 4; ++c) {
                const float4 v = *(const float4*)(srcp + c * 4);
                const float vv[4] = {v.x, v.y, v.z, v.w};
#pragma unroll
                for (int e = 0; e < 4; ++e) {
                    unsigned short h16, l16;
                    split2(vv[e], h16, l16);
                    const int dh = dc * 16 + c * 4 + e;
                    Vth[dh * AST + krow] = h16;
                    Vtl[dh * AST + krow] = l16;
                }
            }
        }
        __syncthreads();

        // ---- S = Q K^T (bf16x3)
        f32x4 s[4];
#pragma unroll
        for (int ni = 0; ni < 4; ++ni) s[ni] = (f32x4){0.f, 0.f, 0.f, 0.f};
#pragma unroll
        for (int ks = 0; ks < 2; ++ks) {
#pragma unroll
            for (int ni = 0; ni < 4; ++ni) {
                const bf16x8 kbh = *(const bf16x8*)&Kh[(ni * 16 + ln) * AST + ks * 32 + g * 8];
                const bf16x8 kbl = *(const bf16x8*)&Kl[(ni * 16 + ln) * AST + ks * 32 + g * 8];
                s[ni] = __builtin_amdgcn_mfma_f32_16x16x32_bf16(qfh[ks], kbh, s[ni], 0, 0, 0);
                s[ni] = __builtin_amdgcn_mfma_f32_16x16x32_bf16(qfh[ks], kbl, s[ni], 0, 0, 0);
                s[ni] = __builtin_amdgcn_mfma_f32_16x16x32_bf16(qfl[ks], kbh, s[ni], 0, 0, 0);
            }
        }

        // ---- online softmax (rows w*16 + 4g+r2; cols 16ni+ln)
        float tm[4];
#pragma unroll
        for (int r2 = 0; r2 < 4; ++r2)
            tm[r2] = fmaxf(fmaxf(s[0][r2], s[1][r2]), fmaxf(s[2][r2], s[3][r2]));
#pragma unroll
        for (int off = 1; off < 16; off <<= 1)
#pragma unroll
            for (int r2 = 0; r2 < 4; ++r2)
                tm[r2] = fmaxf(tm[r2], __shfl_xor(tm[r2], off));

        float alpha[4], psum[4];
#pragma unroll
        for (int r2 = 0; r2 < 4; ++r2) {
            const float mnew = fmaxf(mrow[r2], tm[r2]);
            alpha[r2] = expf(mrow[r2] - mnew);
            mrow[r2] = mnew;
            psum[r2] = 0.f;
        }
#pragma unroll
        for (int ni = 0; ni < 4; ++ni) {
#pragma unroll
            for (int r2 = 0; r2 < 4; ++r2) {
                const float p = expf(s[ni][r2] - mrow[r2]);
                psum[r2] += p;
                unsigned short h16, l16;
                split2(p, h16, l16);
                Ph[(w * 16 + g * 4 + r2) * AST + ni * 16 + ln] = h16;
                Pl[(w * 16 + g * 4 + r2) * AST + ni * 16 + ln] = l16;
            }
        }
#pragma unroll
        for (int off = 1; off < 16; off <<= 1)
#pragma unroll
            for (int r2 = 0; r2 < 4; ++r2)
                psum[r2] += __shfl_xor(psum[r2], off);
#pragma unroll
        for (int r2 = 0; r2 < 4; ++r2)
            lrow[r2] = lrow[r2] * alpha[r2] + psum[r2];
#pragma unroll
        for (int ni = 0; ni < 4; ++ni)
#pragma unroll
            for (int r2 = 0; r2 < 4; ++r2)
                o[ni][r2] *= alpha[r2];
        // no barrier: each wave writes/reads only its own 16 P rows

        // ---- O += P V (bf16x3)
#pragma unroll
        for (int ks = 0; ks < 2; ++ks) {
            const bf16x8 pah = *(const bf16x8*)&Ph[(w * 16 + ln) * AST + ks * 32 + g * 8];
            const bf16x8 pal = *(const bf16x8*)&Pl[(w * 16 + ln) * AST + ks * 32 + g * 8];
#pragma unroll
            for (int ni = 0; ni < 4; ++ni) {
                const bf16x8 vbh = *(const bf16x8*)&Vth[(ni * 16 + ln) * AST + ks * 32 + g * 8];
                const bf16x8 vbl = *(const bf16x8*)&Vtl[(ni * 16 + ln) * AST + ks * 32 + g * 8];
                o[ni] = __builtin_amdgcn_mfma_f32_16x16x32_bf16(pah, vbh, o[ni], 0, 0, 0);
                o[ni] = __builtin_amdgcn_mfma_f32_16x16x32_bf16(pah, vbl, o[ni], 0, 0, 0);
                o[ni] = __builtin_amdgcn_mfma_f32_16x16x32_bf16(pal, vbh, o[ni], 0, 0, 0);
            }
        }
        __syncthreads();   // PV done before next staging overwrites K/V
    }

    // ---- epilogue
#pragma unroll
    for (int r2 = 0; r2 < 4; ++r2) {
        const float inv = 1.0f / lrow[r2];
        const int row = tok0 + w * 16 + g * 4 + r2;
#pragma unroll
        for (int ni = 0; ni < 4; ++ni)
            ctx[(size_t)row * D_ + h * 64 + ni * 16 + ln] = o[ni][r2] * inv;
    }
}

// ---------------- top-8 candidates -> fp32 refine -> top-5 + softmax + gather
__global__ __launch_bounds__(64) void topk_kernel(
    const float* __restrict__ sim, const float* __restrict__ src2,
    const float* __restrict__ mn, const float* __restrict__ mem,
    const float* __restrict__ rs_ptr, float* __restrict__ out)
{
    const int row = blockIdx.x;
    const int lane = threadIdx.x;
    float v[16];
#pragma unroll
    for (int j = 0; j < 16; ++j)
        v[j] = sim[(size_t)row * SLOTS_ + j * 64 + lane];

    // ---- approximate top-8 candidate selection
    int ci[NCAND_];
#pragma unroll
    for (int t = 0; t < NCAND_; ++t) {
        float bv = -INFINITY;
        int bi = 0x7fffffff;
#pragma unroll
        for (int j = 0; j < 16; ++j) {
            const int idx = j * 64 + lane;
            if (v[j] > bv) { bv = v[j]; bi = idx; }
        }
#pragma unroll
        for (int off = 32; off; off >>= 1) {
            const float ov = __shfl_xor(bv, off);
            const int oi = __shfl_xor(bi, off);
            if (ov > bv || (ov == bv && oi < bi)) { bv = ov; bi = oi; }
        }
        ci[t] = bi;
#pragma unroll
        for (int j = 0; j < 16; ++j)
            if (j * 64 + lane == bi) v[j] = -INFINITY;
    }

    // ---- load src2 row, compute inv norm
    float x[8];
    float ss = 0.0f;
#pragma unroll
    for (int j = 0; j < 8; ++j) {
        x[j] = src2[(size_t)row * D_ + j * 64 + lane];
        ss += x[j] * x[j];
    }
#pragma unroll
    for (int off = 32; off; off >>= 1) ss += __shfl_xor(ss, off);
    const float invn = 1.0f / fmaxf(sqrtf(ss), 1e-12f);

    // ---- fp32-exact refinement of the 8 candidate scores
    float rv[NCAND_];
#pragma unroll
    for (int t = 0; t < NCAND_; ++t) {
        const float* mrow = mn + (size_t)ci[t] * D_;
        float acc = 0.0f;
#pragma unroll
        for (int j = 0; j < 8; ++j)
            acc = fmaf(x[j], mrow[j * 64 + lane], acc);
#pragma unroll
        for (int off = 32; off; off >>= 1) acc += __shfl_xor(acc, off);
        rv[t] = acc * invn;
    }

    // ---- re-rank: top-5 of the 8 refined (ties -> lower slot index)
    float wv[TOPK_];
    int wi[TOPK_];
    bool used[NCAND_];
#pragma unroll
    for (int t = 0; t < NCAND_; ++t) used[t] = false;
#pragma unroll
    for (int t = 0; t < TOPK_; ++t) {
        float bv = -INFINITY;
        int bi = 0x7fffffff, bu = 0;
#pragma unroll
        for (int u = 0; u < NCAND_; ++u) {
            if (!used[u] && (rv[u] > bv || (rv[u] == bv && ci[u] < bi))) {
                bv = rv[u]; bi = ci[u]; bu = u;
            }
        }
        used[bu] = true;
        wv[t] = bv;
        wi[t] = bi;
    }

    // ---- softmax over refined scores + weighted gather of ORIGINAL mem rows
    float m = wv[0];
#pragma unroll
    for (int t = 1; t < TOPK_; ++t) m = fmaxf(m, wv[t]);
    float w[TOPK_], ssum = 0.0f;
#pragma unroll
    for (int t = 0; t < TOPK_; ++t) { w[t] = expf(wv[t] - m); ssum += w[t]; }
    const float scale = rs_ptr[0] / ssum;

#pragma unroll
    for (int j = 0; j < 8; ++j) {
        const int d = j * 64 + lane;
        float acc = 0.0f;
#pragma unroll
        for (int t = 0; t < TOPK_; ++t)
            acc += w[t] * mem[(size_t)wi[t] * D_ + d];
        out[(size_t)row * D_ + d] = x[j] + scale * acc;
    }
}

// ----------------------------------------------------------------- launch
extern "C" void kernel_launch(void* const* d_in, const int* in_sizes, int n_in,
                              void* d_out, int out_size, void* d_ws, size_t ws_size,
                              hipStream_t stream)
{
    const float* src  = (const float*)d_in[0];
    const float* inw  = (const float*)d_in[1];
    const float* inb  = (const float*)d_in[2];
    const float* outw = (const float*)d_in[3];
    const float* outb = (const float*)d_in[4];
    const float* mem  = (const float*)d_in[5];
    const float* rs   = (const float*)d_in[6];
    const float* ln1g = (const float*)d_in[7];
    const float* ln1b = (const float*)d_in[8];
    const float* ln2g = (const float*)d_in[9];
    const float* ln2b = (const float*)d_in[10];
    const float* w1   = (const float*)d_in[11];
    const float* b1   = (const float*)d_in[12];
    const float* w2   = (const float*)d_in[13];
    const float* b2   = (const float*)d_in[14];
    float* out = (float*)d_out;
    char* ws = (char*)d_ws;
    const size_t MB = 1024ull * 1024ull;

    float* mn   = (float*)(ws + 0);        // 2 MB   [K0 .. topk]
    float* h    = (float*)(ws + 2 * MB);   // 16 MB  h -> ctx -> h2
    float* qkv  = (float*)(ws + 18 * MB);  // 48 MB
    float* src2 = (float*)(ws + 18 * MB);  // 16 MB  (qkv dead)
    float* sim  = (float*)(ws + 34 * MB);  // 32 MB
    float* invn = (float*)(ws + 66 * MB);  // 32 KB
    float* G    = (float*)(ws + 18 * MB);  // 64 MB  (src2/sim dead after topk)
    float* ctx  = h;
    float* h2   = h;

    mn_kernel<<<dim3(SLOTS_), dim3(64), 0, stream>>>(mem, mn);
    ln_kernel<<<dim3(NTOK_), dim3(256), 0, stream>>>(src, ln1g, ln1b, h);
    gemm_mf<3, EP_BIAS><<<dim3(64, 12), dim3(256), 0, stream>>>(
        h, inw, inb, nullptr, nullptr, qkv, NTOK_, 1536, 512);
    attn_kernel<<<dim3(1024), dim3(256), 0, stream>>>(qkv, ctx);
    gemm_mf<3, EP_BIAS_RES><<<dim3(64, 4), dim3(256), 0, stream>>>(
        ctx, outw, outb, src, nullptr, src2, NTOK_, 512, 512);
    rownorm_kernel<<<dim3(NTOK_), dim3(64), 0, stream>>>(src2, invn);
    gemm_mf<3, EP_ROWSCALE><<<dim3(64, 8), dim3(256), 0, stream>>>(
        src2, mn, nullptr, nullptr, invn, sim, NTOK_, 1024, 512);
    topk_kernel<<<dim3(NTOK_), dim3(64), 0, stream>>>(sim, src2, mn, mem, rs, out);
    ln_kernel<<<dim3(NTOK_), dim3(256), 0, stream>>>(out, ln2g, ln2b, h2);
    gemm_mf<1, EP_BIAS_GELU><<<dim3(64, 16), dim3(256), 0, stream>>>(
        h2, w1, b1, nullptr, nullptr, G, NTOK_, 2048, 512);
    gemm_mf<1, EP_BIAS_RES><<<dim3(64, 4), dim3(256), 0, stream>>>(
        G, w2, b2, out, nullptr, out, NTOK_, 512, 2048);
}

// Round 5
// 411.171 us; speedup vs baseline: 2.8234x; 1.2972x over previous
//
#include <hip/hip_runtime.h>
#include <math.h>

#define D_ 512
#define H_ 8
#define DFF_ 2048
#define SLOTS_ 1024
#define TOPK_ 5
#define NCAND_ 8
#define NTOK_ 8192
#define SEQ_ 1024
#define LN_EPS_ 1e-5f

typedef __attribute__((ext_vector_type(8))) short bf16x8;
typedef __attribute__((ext_vector_type(4))) float f32x4;

// split fp32 -> bf16 hi + bf16 lo (truncation; rem captured to ~2^-16 rel)
__device__ inline void split2(float x, unsigned short& hi, unsigned short& lo) {
    unsigned u = __builtin_bit_cast(unsigned, x);
    hi = (unsigned short)(u >> 16);
    float h = __builtin_bit_cast(float, u & 0xFFFF0000u);
    float rem = x - h;
    lo = (unsigned short)(__builtin_bit_cast(unsigned, rem) >> 16);
}

// ---------------------------------------------------------------- splitter
__global__ __launch_bounds__(256) void split_kernel(
    const float* __restrict__ x, unsigned short* __restrict__ hi,
    unsigned short* __restrict__ lo, int n)
{
    const int i = (blockIdx.x * 256 + threadIdx.x) * 4;
    if (i >= n) return;
    const float4 v = *(const float4*)(x + i);
    const float vv[4] = {v.x, v.y, v.z, v.w};
    unsigned short h[4], l[4];
#pragma unroll
    for (int e = 0; e < 4; ++e) split2(vv[e], h[e], l[e]);
    hi[i + 0] = h[0]; hi[i + 1] = h[1]; hi[i + 2] = h[2]; hi[i + 3] = h[3];
    if (lo) { lo[i + 0] = l[0]; lo[i + 1] = l[1]; lo[i + 2] = l[2]; lo[i + 3] = l[3]; }
}

// ---------------------------------------------------------------- LayerNorm -> planes
template <int WLO>
__global__ __launch_bounds__(256) void ln_kernel(
    const float* __restrict__ x, const float* __restrict__ g,
    const float* __restrict__ be, unsigned short* __restrict__ yh,
    unsigned short* __restrict__ yl)
{
    const int row = blockIdx.x;
    const int t = threadIdx.x;
    const float a = x[(size_t)row * D_ + t];
    const float b = x[(size_t)row * D_ + t + 256];
    float s = a + b;
    float ss = a * a + b * b;
#pragma unroll
    for (int off = 32; off; off >>= 1) {
        s += __shfl_xor(s, off);
        ss += __shfl_xor(ss, off);
    }
    __shared__ float rs[4], rss[4];
    if ((t & 63) == 0) { rs[t >> 6] = s; rss[t >> 6] = ss; }
    __syncthreads();
    s = rs[0] + rs[1] + rs[2] + rs[3];
    ss = rss[0] + rss[1] + rss[2] + rss[3];
    const float mu = s * (1.0f / D_);
    const float var = ss * (1.0f / D_) - mu * mu;
    const float r = rsqrtf(var + LN_EPS_);
    const float y0 = (a - mu) * r * g[t] + be[t];
    const float y1 = (b - mu) * r * g[t + 256] + be[t + 256];
    unsigned short h0, l0, h1, l1;
    split2(y0, h0, l0);
    split2(y1, h1, l1);
    yh[(size_t)row * D_ + t] = h0;
    yh[(size_t)row * D_ + t + 256] = h1;
    if (WLO) {
        yl[(size_t)row * D_ + t] = l0;
        yl[(size_t)row * D_ + t + 256] = l1;
    }
}

// ------------------------------------------------- normalize memory rows (+planes)
__global__ __launch_bounds__(64) void mn_kernel(
    const float* __restrict__ mem, float* __restrict__ mn,
    unsigned short* __restrict__ mnh, unsigned short* __restrict__ mnl)
{
    const int row = blockIdx.x;
    const int lane = threadIdx.x;
    float v[8];
    float ss = 0.0f;
#pragma unroll
    for (int j = 0; j < 8; ++j) {
        v[j] = mem[(size_t)row * D_ + j * 64 + lane];
        ss += v[j] * v[j];
    }
#pragma unroll
    for (int off = 32; off; off >>= 1) ss += __shfl_xor(ss, off);
    const float inv = 1.0f / fmaxf(sqrtf(ss), 1e-12f);
#pragma unroll
    for (int j = 0; j < 8; ++j) {
        const float y = v[j] * inv;
        mn[(size_t)row * D_ + j * 64 + lane] = y;
        unsigned short h, l;
        split2(y, h, l);
        mnh[(size_t)row * D_ + j * 64 + lane] = h;
        mnl[(size_t)row * D_ + j * 64 + lane] = l;
    }
}

// ------------------------------------------------- row inverse norms
__global__ __launch_bounds__(64) void rownorm_kernel(
    const float* __restrict__ x, float* __restrict__ invn)
{
    const int row = blockIdx.x;
    const int lane = threadIdx.x;
    float ss = 0.0f;
#pragma unroll
    for (int j = 0; j < 8; ++j) {
        const float v = x[(size_t)row * D_ + j * 64 + lane];
        ss += v * v;
    }
#pragma unroll
    for (int off = 32; off; off >>= 1) ss += __shfl_xor(ss, off);
    if (lane == 0) invn[row] = 1.0f / fmaxf(sqrtf(ss), 1e-12f);
}

// ------------------------------------------------- MFMA GEMM (NT), 128x128 tile
// operands pre-split into bf16 hi/lo planes
enum { EP_QKV = 0, EP_OUTPROJ = 1, EP_SIM = 2, EP_FFN1 = 3, EP_FFN2 = 4 };

template <int SPLIT, int MODE>
__global__ __launch_bounds__(256) void gemm_mf(
    const unsigned short* __restrict__ Ahg, const unsigned short* __restrict__ Alg,
    const unsigned short* __restrict__ Bhg, const unsigned short* __restrict__ Blg,
    const float* __restrict__ bias, const float* __restrict__ res,
    const float* __restrict__ rowscale, float* __restrict__ C,
    unsigned short* __restrict__ Ch, unsigned short* __restrict__ Cl,
    int M, int N, int K)
{
    __shared__ __align__(16) unsigned short sm[(SPLIT == 3 ? 4 : 2) * 8192];
    unsigned short* Ah = sm;
    unsigned short* Al = sm + 8192;
    unsigned short* Bh = sm + (SPLIT == 3 ? 16384 : 8192);
    unsigned short* Bl = sm + 24576;

    const int tid = threadIdx.x;
    const int lane = tid & 63;
    const int w = tid >> 6;
    const int wr = w >> 1, wc = w & 1;
    const int g = lane >> 4, ln = lane & 15;
    const int m0 = blockIdx.x * 128, n0 = blockIdx.y * 128;
    const int srow = tid >> 1, shalf = tid & 1;

    f32x4 acc[4][4];
#pragma unroll
    for (int i = 0; i < 4; ++i)
#pragma unroll
        for (int j = 0; j < 4; ++j) acc[i][j] = (f32x4){0.f, 0.f, 0.f, 0.f};

    for (int k0 = 0; k0 < K; k0 += 64) {
        const size_t abase = (size_t)(m0 + srow) * K + k0 + shalf * 32;
        const size_t bbase = (size_t)(n0 + srow) * K + k0 + shalf * 32;
#pragma unroll
        for (int c4 = 0; c4 < 4; ++c4) {
            const int c = (shalf * 4 + c4) ^ (srow & 7);
            *(bf16x8*)&Ah[srow * 64 + c * 8] = *(const bf16x8*)(Ahg + abase + c4 * 8);
            if (SPLIT == 3)
                *(bf16x8*)&Al[srow * 64 + c * 8] = *(const bf16x8*)(Alg + abase + c4 * 8);
            *(bf16x8*)&Bh[srow * 64 + c * 8] = *(const bf16x8*)(Bhg + bbase + c4 * 8);
            if (SPLIT == 3)
                *(bf16x8*)&Bl[srow * 64 + c * 8] = *(const bf16x8*)(Blg + bbase + c4 * 8);
        }
        __syncthreads();

#pragma unroll
        for (int ks = 0; ks < 2; ++ks) {
            bf16x8 a_h[4], a_l[4], b_h[4], b_l[4];
#pragma unroll
            for (int mi = 0; mi < 4; ++mi) {
                const int r = wr * 64 + mi * 16 + ln;
                const int c = (ks * 4 + g) ^ (r & 7);
                a_h[mi] = *(const bf16x8*)&Ah[r * 64 + c * 8];
                if (SPLIT == 3) a_l[mi] = *(const bf16x8*)&Al[r * 64 + c * 8];
            }
#pragma unroll
            for (int ni = 0; ni < 4; ++ni) {
                const int r = wc * 64 + ni * 16 + ln;
                const int c = (ks * 4 + g) ^ (r & 7);
                b_h[ni] = *(const bf16x8*)&Bh[r * 64 + c * 8];
                if (SPLIT == 3) b_l[ni] = *(const bf16x8*)&Bl[r * 64 + c * 8];
            }
#pragma unroll
            for (int mi = 0; mi < 4; ++mi)
#pragma unroll
                for (int ni = 0; ni < 4; ++ni) {
                    acc[mi][ni] = __builtin_amdgcn_mfma_f32_16x16x32_bf16(
                        a_h[mi], b_h[ni], acc[mi][ni], 0, 0, 0);
                    if (SPLIT == 3) {
                        acc[mi][ni] = __builtin_amdgcn_mfma_f32_16x16x32_bf16(
                            a_h[mi], b_l[ni], acc[mi][ni], 0, 0, 0);
                        acc[mi][ni] = __builtin_amdgcn_mfma_f32_16x16x32_bf16(
                            a_l[mi], b_h[ni], acc[mi][ni], 0, 0, 0);
                    }
                }
        }
        __syncthreads();
    }

#pragma unroll
    for (int mi = 0; mi < 4; ++mi) {
#pragma unroll
        for (int ni = 0; ni < 4; ++ni) {
            const int gn = n0 + wc * 64 + ni * 16 + ln;
            const float bz = (MODE == EP_SIM) ? 0.0f : bias[gn];
#pragma unroll
            for (int r2 = 0; r2 < 4; ++r2) {
                const int gm = m0 + wr * 64 + mi * 16 + g * 4 + r2;
                float v = acc[mi][ni][r2];
                if (MODE == EP_SIM) {
                    v *= rowscale[gm];
                    C[(size_t)gm * N + gn] = v;
                } else if (MODE == EP_QKV) {
                    v += bz;
                    if (gn < D_) v *= 0.125f;   // fold 1/sqrt(DH) into Q
                    unsigned short h16, l16;
                    split2(v, h16, l16);
                    Ch[(size_t)gm * N + gn] = h16;
                    Cl[(size_t)gm * N + gn] = l16;
                } else if (MODE == EP_OUTPROJ) {
                    v += bz + res[(size_t)gm * N + gn];
                    C[(size_t)gm * N + gn] = v;
                    unsigned short h16, l16;
                    split2(v, h16, l16);
                    Ch[(size_t)gm * N + gn] = h16;
                    Cl[(size_t)gm * N + gn] = l16;
                } else if (MODE == EP_FFN1) {
                    v += bz;
                    v = 0.5f * v * (1.0f + erff(v * 0.70710678118654752f));
                    unsigned short h16, l16;
                    split2(v, h16, l16);
                    Ch[(size_t)gm * N + gn] = h16;
                } else {   // EP_FFN2
                    v += bz + res[(size_t)gm * N + gn];
                    C[(size_t)gm * N + gn] = v;
                }
            }
        }
    }
}

// ------------------------------------------------- flash attention, MFMA bf16x3
#define AST 72   // LDS row stride (bf16 elems) for all attn planes

__global__ __launch_bounds__(256) void attn_kernel(
    const unsigned short* __restrict__ qkvh, const unsigned short* __restrict__ qkvl,
    unsigned short* __restrict__ ctxh, unsigned short* __restrict__ ctxl)
{
    const int id = blockIdx.x;          // 0..1023
    const int bh = id & 63;             // stride-64 blocks share (b,h)
    const int qt = id >> 6;
    const int b = bh >> 3, h = bh & 7;
    const int tok0 = b * SEQ_ + qt * 64;
    const int kbase0 = b * SEQ_;
    const int tid = threadIdx.x;
    const int lane = tid & 63;
    const int w = tid >> 6;             // wave: 16-row m-strip
    const int ln = lane & 15, g = lane >> 4;

    __shared__ __align__(16) unsigned short sm[6 * 64 * AST];
    unsigned short* Ph  = sm;
    unsigned short* Pl  = sm + 1 * 64 * AST;
    unsigned short* Kh  = sm + 2 * 64 * AST;
    unsigned short* Kl  = sm + 3 * 64 * AST;
    unsigned short* Vth = sm + 4 * 64 * AST;
    unsigned short* Vtl = sm + 5 * 64 * AST;

    const int qoff = h * 64, koff = 512 + h * 64, voff = 1024 + h * 64;

    // ---- stage Q (pre-scaled at QKV epilogue) into planes 0/1, hoist to regs
    {
        const int row = tid >> 2, q4 = tid & 3;
        const size_t base = (size_t)(tok0 + row) * 1536 + qoff + q4 * 16;
#pragma unroll
        for (int half = 0; half < 2; ++half) {
            *(bf16x8*)&Ph[row * AST + q4 * 16 + half * 8] = *(const bf16x8*)(qkvh + base + half * 8);
            *(bf16x8*)&Pl[row * AST + q4 * 16 + half * 8] = *(const bf16x8*)(qkvl + base + half * 8);
        }
    }
    __syncthreads();
    bf16x8 qfh[2], qfl[2];
#pragma unroll
    for (int ks = 0; ks < 2; ++ks) {
        qfh[ks] = *(const bf16x8*)&Ph[(w * 16 + ln) * AST + ks * 32 + g * 8];
        qfl[ks] = *(const bf16x8*)&Pl[(w * 16 + ln) * AST + ks * 32 + g * 8];
    }

    f32x4 o[4];
#pragma unroll
    for (int ni = 0; ni < 4; ++ni) o[ni] = (f32x4){0.f, 0.f, 0.f, 0.f};
    float mrow[4] = {-INFINITY, -INFINITY, -INFINITY, -INFINITY};
    float lrow[4] = {0.f, 0.f, 0.f, 0.f};

    for (int kt = 0; kt < 16; ++kt) {
        const int kb2 = kbase0 + kt * 64;
        // ---- stage K (row-major)
        {
            const int row = tid >> 2, q4 = tid & 3;
            const size_t base = (size_t)(kb2 + row) * 1536 + koff + q4 * 16;
#pragma unroll
            for (int half = 0; half < 2; ++half) {
                *(bf16x8*)&Kh[row * AST + q4 * 16 + half * 8] = *(const bf16x8*)(qkvh + base + half * 8);
                *(bf16x8*)&Kl[row * AST + q4 * 16 + half * 8] = *(const bf16x8*)(qkvl + base + half * 8);
            }
        }
        // ---- stage V transposed (lane = krow -> contiguous 2B writes)
        {
            const int krow = tid & 63, dc = tid >> 6;
            const size_t base = (size_t)(kb2 + krow) * 1536 + voff + dc * 16;
            const bf16x8 hv0 = *(const bf16x8*)(qkvh + base);
            const bf16x8 hv1 = *(const bf16x8*)(qkvh + base + 8);
            const bf16x8 lv0 = *(const bf16x8*)(qkvl + base);
            const bf16x8 lv1 = *(const bf16x8*)(qkvl + base + 8);
#pragma unroll
            for (int e = 0; e < 8; ++e) {
                Vth[(dc * 16 + e) * AST + krow] = (unsigned short)hv0[e];
                Vth[(dc * 16 + 8 + e) * AST + krow] = (unsigned short)hv1[e];
                Vtl[(dc * 16 + e) * AST + krow] = (unsigned short)lv0[e];
                Vtl[(dc * 16 + 8 + e) * AST + krow] = (unsigned short)lv1[e];
            }
        }
        __syncthreads();

        // ---- S = Q K^T (bf16x3)
        f32x4 s[4];
#pragma unroll
        for (int ni = 0; ni < 4; ++ni) s[ni] = (f32x4){0.f, 0.f, 0.f, 0.f};
#pragma unroll
        for (int ks = 0; ks < 2; ++ks) {
#pragma unroll
            for (int ni = 0; ni < 4; ++ni) {
                const bf16x8 kbh = *(const bf16x8*)&Kh[(ni * 16 + ln) * AST + ks * 32 + g * 8];
                const bf16x8 kbl = *(const bf16x8*)&Kl[(ni * 16 + ln) * AST + ks * 32 + g * 8];
                s[ni] = __builtin_amdgcn_mfma_f32_16x16x32_bf16(qfh[ks], kbh, s[ni], 0, 0, 0);
                s[ni] = __builtin_amdgcn_mfma_f32_16x16x32_bf16(qfh[ks], kbl, s[ni], 0, 0, 0);
                s[ni] = __builtin_amdgcn_mfma_f32_16x16x32_bf16(qfl[ks], kbh, s[ni], 0, 0, 0);
            }
        }

        // ---- online softmax (rows w*16 + 4g+r2; cols 16ni+ln)
        float tm[4];
#pragma unroll
        for (int r2 = 0; r2 < 4; ++r2)
            tm[r2] = fmaxf(fmaxf(s[0][r2], s[1][r2]), fmaxf(s[2][r2], s[3][r2]));
#pragma unroll
        for (int off = 1; off < 16; off <<= 1)
#pragma unroll
            for (int r2 = 0; r2 < 4; ++r2)
                tm[r2] = fmaxf(tm[r2], __shfl_xor(tm[r2], off));

        float alpha[4], psum[4];
#pragma unroll
        for (int r2 = 0; r2 < 4; ++r2) {
            const float mnew = fmaxf(mrow[r2], tm[r2]);
            alpha[r2] = expf(mrow[r2] - mnew);
            mrow[r2] = mnew;
            psum[r2] = 0.f;
        }
#pragma unroll
        for (int ni = 0; ni < 4; ++ni) {
#pragma unroll
            for (int r2 = 0; r2 < 4; ++r2) {
                const float p = expf(s[ni][r2] - mrow[r2]);
                psum[r2] += p;
                unsigned short h16, l16;
                split2(p, h16, l16);
                Ph[(w * 16 + g * 4 + r2) * AST + ni * 16 + ln] = h16;
                Pl[(w * 16 + g * 4 + r2) * AST + ni * 16 + ln] = l16;
            }
        }
#pragma unroll
        for (int off = 1; off < 16; off <<= 1)
#pragma unroll
            for (int r2 = 0; r2 < 4; ++r2)
                psum[r2] += __shfl_xor(psum[r2], off);
#pragma unroll
        for (int r2 = 0; r2 < 4; ++r2)
            lrow[r2] = lrow[r2] * alpha[r2] + psum[r2];
#pragma unroll
        for (int ni = 0; ni < 4; ++ni)
#pragma unroll
            for (int r2 = 0; r2 < 4; ++r2)
                o[ni][r2] *= alpha[r2];
        // no barrier: each wave owns its 16 P rows

        // ---- O += P V (bf16x3)
#pragma unroll
        for (int ks = 0; ks < 2; ++ks) {
            const bf16x8 pah = *(const bf16x8*)&Ph[(w * 16 + ln) * AST + ks * 32 + g * 8];
            const bf16x8 pal = *(const bf16x8*)&Pl[(w * 16 + ln) * AST + ks * 32 + g * 8];
#pragma unroll
            for (int ni = 0; ni < 4; ++ni) {
                const bf16x8 vbh = *(const bf16x8*)&Vth[(ni * 16 + ln) * AST + ks * 32 + g * 8];
                const bf16x8 vbl = *(const bf16x8*)&Vtl[(ni * 16 + ln) * AST + ks * 32 + g * 8];
                o[ni] = __builtin_amdgcn_mfma_f32_16x16x32_bf16(pah, vbh, o[ni], 0, 0, 0);
                o[ni] = __builtin_amdgcn_mfma_f32_16x16x32_bf16(pah, vbl, o[ni], 0, 0, 0);
                o[ni] = __builtin_amdgcn_mfma_f32_16x16x32_bf16(pal, vbh, o[ni], 0, 0, 0);
            }
        }
        __syncthreads();   // PV done before next staging overwrites K/V
    }

    // ---- epilogue: write ctx hi/lo planes
#pragma unroll
    for (int r2 = 0; r2 < 4; ++r2) {
        const float inv = 1.0f / lrow[r2];
        const int row = tok0 + w * 16 + g * 4 + r2;
#pragma unroll
        for (int ni = 0; ni < 4; ++ni) {
            const float v = o[ni][r2] * inv;
            unsigned short h16, l16;
            split2(v, h16, l16);
            ctxh[(size_t)row * D_ + h * 64 + ni * 16 + ln] = h16;
            ctxl[(size_t)row * D_ + h * 64 + ni * 16 + ln] = l16;
        }
    }
}

// ---------------- top-8 candidates -> fp32 refine -> top-5 + softmax + gather
__global__ __launch_bounds__(64) void topk_kernel(
    const float* __restrict__ sim, const float* __restrict__ src2,
    const float* __restrict__ mn, const float* __restrict__ mem,
    const float* __restrict__ rs_ptr, float* __restrict__ out)
{
    const int row = blockIdx.x;
    const int lane = threadIdx.x;
    float v[16];
#pragma unroll
    for (int j = 0; j < 16; ++j)
        v[j] = sim[(size_t)row * SLOTS_ + j * 64 + lane];

    int ci[NCAND_];
#pragma unroll
    for (int t = 0; t < NCAND_; ++t) {
        float bv = -INFINITY;
        int bi = 0x7fffffff;
#pragma unroll
        for (int j = 0; j < 16; ++j) {
            const int idx = j * 64 + lane;
            if (v[j] > bv) { bv = v[j]; bi = idx; }
        }
#pragma unroll
        for (int off = 32; off; off >>= 1) {
            const float ov = __shfl_xor(bv, off);
            const int oi = __shfl_xor(bi, off);
            if (ov > bv || (ov == bv && oi < bi)) { bv = ov; bi = oi; }
        }
        ci[t] = bi;
#pragma unroll
        for (int j = 0; j < 16; ++j)
            if (j * 64 + lane == bi) v[j] = -INFINITY;
    }

    float x[8];
    float ss = 0.0f;
#pragma unroll
    for (int j = 0; j < 8; ++j) {
        x[j] = src2[(size_t)row * D_ + j * 64 + lane];
        ss += x[j] * x[j];
    }
#pragma unroll
    for (int off = 32; off; off >>= 1) ss += __shfl_xor(ss, off);
    const float invn = 1.0f / fmaxf(sqrtf(ss), 1e-12f);

    float rv[NCAND_];
#pragma unroll
    for (int t = 0; t < NCAND_; ++t) {
        const float* mrow = mn + (size_t)ci[t] * D_;
        float acc = 0.0f;
#pragma unroll
        for (int j = 0; j < 8; ++j)
            acc = fmaf(x[j], mrow[j * 64 + lane], acc);
#pragma unroll
        for (int off = 32; off; off >>= 1) acc += __shfl_xor(acc, off);
        rv[t] = acc * invn;
    }

    float wv[TOPK_];
    int wi[TOPK_];
    bool used[NCAND_];
#pragma unroll
    for (int t = 0; t < NCAND_; ++t) used[t] = false;
#pragma unroll
    for (int t = 0; t < TOPK_; ++t) {
        float bv = -INFINITY;
        int bi = 0x7fffffff, bu = 0;
#pragma unroll
        for (int u = 0; u < NCAND_; ++u) {
            if (!used[u] && (rv[u] > bv || (rv[u] == bv && ci[u] < bi))) {
                bv = rv[u]; bi = ci[u]; bu = u;
            }
        }
        used[bu] = true;
        wv[t] = bv;
        wi[t] = bi;
    }

    float m = wv[0];
#pragma unroll
    for (int t = 1; t < TOPK_; ++t) m = fmaxf(m, wv[t]);
    float w[TOPK_], ssum = 0.0f;
#pragma unroll
    for (int t = 0; t < TOPK_; ++t) { w[t] = expf(wv[t] - m); ssum += w[t]; }
    const float scale = rs_ptr[0] / ssum;

#pragma unroll
    for (int j = 0; j < 8; ++j) {
        const int d = j * 64 + lane;
        float acc = 0.0f;
#pragma unroll
        for (int t = 0; t < TOPK_; ++t)
            acc += w[t] * mem[(size_t)wi[t] * D_ + d];
        out[(size_t)row * D_ + d] = x[j] + scale * acc;
    }
}

// ----------------------------------------------------------------- launch
extern "C" void kernel_launch(void* const* d_in, const int* in_sizes, int n_in,
                              void* d_out, int out_size, void* d_ws, size_t ws_size,
                              hipStream_t stream)
{
    const float* src  = (const float*)d_in[0];
    const float* inw  = (const float*)d_in[1];
    const float* inb  = (const float*)d_in[2];
    const float* outw = (const float*)d_in[3];
    const float* outb = (const float*)d_in[4];
    const float* mem  = (const float*)d_in[5];
    const float* rs   = (const float*)d_in[6];
    const float* ln1g = (const float*)d_in[7];
    const float* ln1b = (const float*)d_in[8];
    const float* ln2g = (const float*)d_in[9];
    const float* ln2b = (const float*)d_in[10];
    const float* w1   = (const float*)d_in[11];
    const float* b1   = (const float*)d_in[12];
    const float* w2   = (const float*)d_in[13];
    const float* b2   = (const float*)d_in[14];
    float* out = (float*)d_out;
    char* ws = (char*)d_ws;
    const size_t MB = 1024ull * 1024ull;
    typedef unsigned short u16;

    // fixed region [0,13) MB
    float* mn   = (float*)(ws + 0);            // 2 MB
    u16* mnh    = (u16*)(ws + 2 * MB);         // 1
    u16* mnl    = (u16*)(ws + 3 * MB);         // 1
    u16* inwh   = (u16*)(ws + 4 * MB);         // 1.5
    u16* inwl   = (u16*)(ws + 5 * MB + 512 * 1024);
    u16* outwh  = (u16*)(ws + 7 * MB);         // 0.5
    u16* outwl  = (u16*)(ws + 7 * MB + 512 * 1024);
    u16* w1h    = (u16*)(ws + 8 * MB);         // 2
    u16* w2h    = (u16*)(ws + 10 * MB);        // 2
    float* invn = (float*)(ws + 12 * MB);      // 32 KB
    // dynamic
    u16* hh     = (u16*)(ws + 13 * MB);        // 8   [ln1 .. qkv]
    u16* hl     = (u16*)(ws + 21 * MB);        // 8
    u16* qkvh   = (u16*)(ws + 29 * MB);        // 24  [qkv .. attn]
    u16* qkvl   = (u16*)(ws + 53 * MB);        // 24
    u16* ctxh   = (u16*)(ws + 13 * MB);        // 8   [attn .. outproj] (reuse hh/hl)
    u16* ctxl   = (u16*)(ws + 21 * MB);        // 8
    float* sim  = (float*)(ws + 13 * MB);      // 32  [sim .. topk] (ctx dead)
    float* src2 = (float*)(ws + 45 * MB);      // 16  [outproj .. topk] (qkv dead)
    u16* src2h  = (u16*)(ws + 61 * MB);        // 8   [outproj .. sim]
    u16* src2l  = (u16*)(ws + 69 * MB);        // 8
    u16* h2h    = (u16*)(ws + 13 * MB);        // 8   [ln2 .. ffn1] (sim dead)
    u16* Gbf    = (u16*)(ws + 21 * MB);        // 32  [ffn1 .. ffn2]

    // 0) split weights into bf16 planes
    split_kernel<<<dim3(768), dim3(256), 0, stream>>>(inw, inwh, inwl, 3 * D_ * D_);
    split_kernel<<<dim3(256), dim3(256), 0, stream>>>(outw, outwh, outwl, D_ * D_);
    split_kernel<<<dim3(1024), dim3(256), 0, stream>>>(w1, w1h, nullptr, DFF_ * D_);
    split_kernel<<<dim3(1024), dim3(256), 0, stream>>>(w2, w2h, nullptr, D_ * DFF_);
    // 1) normalize memory rows (fp32 + planes)
    mn_kernel<<<dim3(SLOTS_), dim3(64), 0, stream>>>(mem, mn, mnh, mnl);
    // 2) LN1 -> planes
    ln_kernel<1><<<dim3(NTOK_), dim3(256), 0, stream>>>(src, ln1g, ln1b, hh, hl);
    // 3) QKV projection -> qkv planes (Q pre-scaled)
    gemm_mf<3, EP_QKV><<<dim3(64, 12), dim3(256), 0, stream>>>(
        hh, hl, inwh, inwl, inb, nullptr, nullptr, nullptr, qkvh, qkvl, NTOK_, 1536, 512);
    // 4) attention -> ctx planes
    attn_kernel<<<dim3(1024), dim3(256), 0, stream>>>(qkvh, qkvl, ctxh, ctxl);
    // 5) out projection + residual -> src2 fp32 + planes
    gemm_mf<3, EP_OUTPROJ><<<dim3(64, 4), dim3(256), 0, stream>>>(
        ctxh, ctxl, outwh, outwl, outb, src, nullptr, src2, src2h, src2l, NTOK_, 512, 512);
    // 6) row norms of src2
    rownorm_kernel<<<dim3(NTOK_), dim3(64), 0, stream>>>(src2, invn);
    // 7) sim = (src2 @ mn^T) * invn
    gemm_mf<3, EP_SIM><<<dim3(64, 8), dim3(256), 0, stream>>>(
        src2h, src2l, mnh, mnl, nullptr, nullptr, invn, sim, nullptr, nullptr, NTOK_, 1024, 512);
    // 8) top-5 (refined) + weighted retrieval -> d_out
    topk_kernel<<<dim3(NTOK_), dim3(64), 0, stream>>>(sim, src2, mn, mem, rs, out);
    // 9) LN2 -> h2 hi plane
    ln_kernel<0><<<dim3(NTOK_), dim3(256), 0, stream>>>(out, ln2g, ln2b, h2h, nullptr);
    // 10) FFN1 + GELU -> G bf16
    gemm_mf<1, EP_FFN1><<<dim3(64, 16), dim3(256), 0, stream>>>(
        h2h, nullptr, w1h, nullptr, b1, nullptr, nullptr, nullptr, Gbf, nullptr, NTOK_, 2048, 512);
    // 11) FFN2 + bias + residual -> d_out
    gemm_mf<1, EP_FFN2><<<dim3(64, 4), dim3(256), 0, stream>>>(
        Gbf, nullptr, w2h, nullptr, b2, out, nullptr, out, nullptr, nullptr, NTOK_, 512, 2048);
}

// Round 6
// 360.799 us; speedup vs baseline: 3.2175x; 1.1396x over previous
//
#include <hip/hip_runtime.h>
#include <math.h>

#define D_ 512
#define H_ 8
#define DFF_ 2048
#define SLOTS_ 1024
#define TOPK_ 5
#define NCAND_ 8
#define NTOK_ 8192
#define SEQ_ 1024
#define LN_EPS_ 1e-5f

typedef __attribute__((ext_vector_type(8))) short bf16x8;
typedef __attribute__((ext_vector_type(4))) float f32x4;

// split fp32 -> bf16 hi + bf16 lo (truncation; rem captured to ~2^-16 rel)
__device__ inline void split2(float x, unsigned short& hi, unsigned short& lo) {
    unsigned u = __builtin_bit_cast(unsigned, x);
    hi = (unsigned short)(u >> 16);
    float h = __builtin_bit_cast(float, u & 0xFFFF0000u);
    float rem = x - h;
    lo = (unsigned short)(__builtin_bit_cast(unsigned, rem) >> 16);
}

// async global->LDS, 16B per lane; LDS dest must be wave-uniform base
__device__ __forceinline__ void gld16(const void* g, void* l) {
    __builtin_amdgcn_global_load_lds(
        (const __attribute__((address_space(1))) void*)g,
        (__attribute__((address_space(3))) void*)l, 16, 0, 0);
}

// row swizzle for 64-col (8-chunk) bf16 planes
__device__ __forceinline__ int SW7(int r) { return (r ^ (r >> 3)) & 7; }
// swizzled fragment address: row r, chunk c (8 bf16 per chunk)
__device__ __forceinline__ const bf16x8* frag(const unsigned short* p, int r, int c) {
    return (const bf16x8*)(p + r * 64 + ((c ^ SW7(r)) << 3));
}

// ---------------------------------------------------------------- splitter
__global__ __launch_bounds__(256) void split_kernel(
    const float* __restrict__ x, unsigned short* __restrict__ hi,
    unsigned short* __restrict__ lo, int n)
{
    const int i = (blockIdx.x * 256 + threadIdx.x) * 4;
    if (i >= n) return;
    const float4 v = *(const float4*)(x + i);
    const float vv[4] = {v.x, v.y, v.z, v.w};
    unsigned short h[4], l[4];
#pragma unroll
    for (int e = 0; e < 4; ++e) split2(vv[e], h[e], l[e]);
    hi[i + 0] = h[0]; hi[i + 1] = h[1]; hi[i + 2] = h[2]; hi[i + 3] = h[3];
    if (lo) { lo[i + 0] = l[0]; lo[i + 1] = l[1]; lo[i + 2] = l[2]; lo[i + 3] = l[3]; }
}

// ---------------------------------------------------------------- LayerNorm -> planes
template <int WLO>
__global__ __launch_bounds__(256) void ln_kernel(
    const float* __restrict__ x, const float* __restrict__ g,
    const float* __restrict__ be, unsigned short* __restrict__ yh,
    unsigned short* __restrict__ yl)
{
    const int row = blockIdx.x;
    const int t = threadIdx.x;
    const float a = x[(size_t)row * D_ + t];
    const float b = x[(size_t)row * D_ + t + 256];
    float s = a + b;
    float ss = a * a + b * b;
#pragma unroll
    for (int off = 32; off; off >>= 1) {
        s += __shfl_xor(s, off);
        ss += __shfl_xor(ss, off);
    }
    __shared__ float rs[4], rss[4];
    if ((t & 63) == 0) { rs[t >> 6] = s; rss[t >> 6] = ss; }
    __syncthreads();
    s = rs[0] + rs[1] + rs[2] + rs[3];
    ss = rss[0] + rss[1] + rss[2] + rss[3];
    const float mu = s * (1.0f / D_);
    const float var = ss * (1.0f / D_) - mu * mu;
    const float r = rsqrtf(var + LN_EPS_);
    const float y0 = (a - mu) * r * g[t] + be[t];
    const float y1 = (b - mu) * r * g[t + 256] + be[t + 256];
    unsigned short h0, l0, h1, l1;
    split2(y0, h0, l0);
    split2(y1, h1, l1);
    yh[(size_t)row * D_ + t] = h0;
    yh[(size_t)row * D_ + t + 256] = h1;
    if (WLO) {
        yl[(size_t)row * D_ + t] = l0;
        yl[(size_t)row * D_ + t + 256] = l1;
    }
}

// ------------------------------------------------- normalize memory rows (+planes)
__global__ __launch_bounds__(64) void mn_kernel(
    const float* __restrict__ mem, float* __restrict__ mn,
    unsigned short* __restrict__ mnh, unsigned short* __restrict__ mnl)
{
    const int row = blockIdx.x;
    const int lane = threadIdx.x;
    float v[8];
    float ss = 0.0f;
#pragma unroll
    for (int j = 0; j < 8; ++j) {
        v[j] = mem[(size_t)row * D_ + j * 64 + lane];
        ss += v[j] * v[j];
    }
#pragma unroll
    for (int off = 32; off; off >>= 1) ss += __shfl_xor(ss, off);
    const float inv = 1.0f / fmaxf(sqrtf(ss), 1e-12f);
#pragma unroll
    for (int j = 0; j < 8; ++j) {
        const float y = v[j] * inv;
        mn[(size_t)row * D_ + j * 64 + lane] = y;
        unsigned short h, l;
        split2(y, h, l);
        mnh[(size_t)row * D_ + j * 64 + lane] = h;
        mnl[(size_t)row * D_ + j * 64 + lane] = l;
    }
}

// ------------------------------------------------- row inverse norms
__global__ __launch_bounds__(64) void rownorm_kernel(
    const float* __restrict__ x, float* __restrict__ invn)
{
    const int row = blockIdx.x;
    const int lane = threadIdx.x;
    float ss = 0.0f;
#pragma unroll
    for (int j = 0; j < 8; ++j) {
        const float v = x[(size_t)row * D_ + j * 64 + lane];
        ss += v * v;
    }
#pragma unroll
    for (int off = 32; off; off >>= 1) ss += __shfl_xor(ss, off);
    if (lane == 0) invn[row] = 1.0f / fmaxf(sqrtf(ss), 1e-12f);
}

// ------------------------------------------------- MFMA GEMM (NT), 128x128 tile
// operands pre-split bf16 planes; staging via global_load_lds, pre-swizzled src
enum { EP_QKV = 0, EP_OUTPROJ = 1, EP_SIM = 2, EP_FFN1 = 3, EP_FFN2 = 4 };

template <int SPLIT, int MODE>
__global__ __launch_bounds__(256) void gemm_mf(
    const unsigned short* __restrict__ Ahg, const unsigned short* __restrict__ Alg,
    const unsigned short* __restrict__ Bhg, const unsigned short* __restrict__ Blg,
    const float* __restrict__ bias, const float* __restrict__ res,
    const float* __restrict__ rowscale, float* __restrict__ C,
    unsigned short* __restrict__ Ch, unsigned short* __restrict__ Cl,
    int M, int N, int K)
{
    __shared__ __align__(16) unsigned short sm[(SPLIT == 3 ? 4 : 2) * 8192];
    unsigned short* Ah = sm;
    unsigned short* Al = sm + 8192;
    unsigned short* Bh = sm + (SPLIT == 3 ? 16384 : 8192);
    unsigned short* Bl = sm + 24576;

    const int tid = threadIdx.x;
    const int lane = tid & 63;
    const int w = tid >> 6;
    const int wr = w >> 1, wc = w & 1;
    const int g = lane >> 4, ln = lane & 15;
    const int m0 = blockIdx.x * 128, n0 = blockIdx.y * 128;
    const int lrow8 = lane >> 3, lchunk = lane & 7;

    // per-wave staging plane
    const unsigned short* gsrc;
    unsigned short* lds;
    int rbase, rofs, nblk;
    if (SPLIT == 3) {
        nblk = 16; rofs = 0;
        if (w == 0)      { gsrc = Ahg; lds = Ah; rbase = m0; }
        else if (w == 1) { gsrc = Alg; lds = Al; rbase = m0; }
        else if (w == 2) { gsrc = Bhg; lds = Bh; rbase = n0; }
        else             { gsrc = Blg; lds = Bl; rbase = n0; }
    } else {
        nblk = 8; rofs = (w & 1) * 64;
        if (w < 2) { gsrc = Ahg; lds = Ah; rbase = m0; }
        else       { gsrc = Bhg; lds = Bh; rbase = n0; }
    }

    f32x4 acc[4][4];
#pragma unroll
    for (int i = 0; i < 4; ++i)
#pragma unroll
        for (int j = 0; j < 4; ++j) acc[i][j] = (f32x4){0.f, 0.f, 0.f, 0.f};

    for (int k0 = 0; k0 < K; k0 += 64) {
#pragma unroll
        for (int blk = 0; blk < nblk; ++blk) {
            const int row = rofs + blk * 8 + lrow8;
            const int sc = lchunk ^ SW7(row);
            gld16(gsrc + (size_t)(rbase + row) * K + k0 + sc * 8,
                  lds + (rofs + blk * 8) * 64);
        }
        __syncthreads();

#pragma unroll
        for (int ks = 0; ks < 2; ++ks) {
            bf16x8 a_h[4], a_l[4], b_h[4], b_l[4];
#pragma unroll
            for (int mi = 0; mi < 4; ++mi) {
                a_h[mi] = *frag(Ah, wr * 64 + mi * 16 + ln, ks * 4 + g);
                if (SPLIT == 3) a_l[mi] = *frag(Al, wr * 64 + mi * 16 + ln, ks * 4 + g);
            }
#pragma unroll
            for (int ni = 0; ni < 4; ++ni) {
                b_h[ni] = *frag(Bh, wc * 64 + ni * 16 + ln, ks * 4 + g);
                if (SPLIT == 3) b_l[ni] = *frag(Bl, wc * 64 + ni * 16 + ln, ks * 4 + g);
            }
#pragma unroll
            for (int mi = 0; mi < 4; ++mi)
#pragma unroll
                for (int ni = 0; ni < 4; ++ni) {
                    acc[mi][ni] = __builtin_amdgcn_mfma_f32_16x16x32_bf16(
                        a_h[mi], b_h[ni], acc[mi][ni], 0, 0, 0);
                    if (SPLIT == 3) {
                        acc[mi][ni] = __builtin_amdgcn_mfma_f32_16x16x32_bf16(
                            a_h[mi], b_l[ni], acc[mi][ni], 0, 0, 0);
                        acc[mi][ni] = __builtin_amdgcn_mfma_f32_16x16x32_bf16(
                            a_l[mi], b_h[ni], acc[mi][ni], 0, 0, 0);
                    }
                }
        }
        __syncthreads();
    }

#pragma unroll
    for (int mi = 0; mi < 4; ++mi) {
#pragma unroll
        for (int ni = 0; ni < 4; ++ni) {
            const int gn = n0 + wc * 64 + ni * 16 + ln;
            const float bz = (MODE == EP_SIM) ? 0.0f : bias[gn];
#pragma unroll
            for (int r2 = 0; r2 < 4; ++r2) {
                const int gm = m0 + wr * 64 + mi * 16 + g * 4 + r2;
                float v = acc[mi][ni][r2];
                if (MODE == EP_SIM) {
                    v *= rowscale[gm];
                    C[(size_t)gm * N + gn] = v;
                } else if (MODE == EP_QKV) {
                    v += bz;
                    if (gn < D_) v *= 0.125f;   // fold 1/sqrt(DH) into Q
                    unsigned short h16, l16;
                    split2(v, h16, l16);
                    Ch[(size_t)gm * N + gn] = h16;
                    Cl[(size_t)gm * N + gn] = l16;
                } else if (MODE == EP_OUTPROJ) {
                    v += bz + res[(size_t)gm * N + gn];
                    C[(size_t)gm * N + gn] = v;
                    unsigned short h16, l16;
                    split2(v, h16, l16);
                    Ch[(size_t)gm * N + gn] = h16;
                    Cl[(size_t)gm * N + gn] = l16;
                } else if (MODE == EP_FFN1) {
                    v += bz;
                    v = 0.5f * v * (1.0f + erff(v * 0.70710678118654752f));
                    unsigned short h16, l16;
                    split2(v, h16, l16);
                    Ch[(size_t)gm * N + gn] = h16;
                } else {   // EP_FFN2
                    v += bz + res[(size_t)gm * N + gn];
                    C[(size_t)gm * N + gn] = v;
                }
            }
        }
    }
}

// ------------------------------------------------- flash attention, MFMA bf16x3
#define AST 72   // LDS row stride for Vt planes only

__global__ __launch_bounds__(256) void attn_kernel(
    const unsigned short* __restrict__ qkvh, const unsigned short* __restrict__ qkvl,
    unsigned short* __restrict__ ctxh, unsigned short* __restrict__ ctxl)
{
    const int id = blockIdx.x;          // 0..1023
    const int bh = id & 63;             // stride-64 blocks share (b,h)
    const int qt = id >> 6;
    const int b = bh >> 3, h = bh & 7;
    const int tok0 = b * SEQ_ + qt * 64;
    const int kbase0 = b * SEQ_;
    const int tid = threadIdx.x;
    const int lane = tid & 63;
    const int w = tid >> 6;             // wave: 16-row m-strip
    const int ln = lane & 15, g = lane >> 4;
    const int lrow8 = lane >> 3, lchunk = lane & 7;

    // Ph,Pl,Kh,Kl: [64][64] swizzled; Vth,Vtl: [64 d][AST krow]
    __shared__ __align__(16) unsigned short sm[4 * 4096 + 2 * 64 * AST];
    unsigned short* Ph  = sm;
    unsigned short* Pl  = sm + 4096;
    unsigned short* Kh  = sm + 8192;
    unsigned short* Kl  = sm + 12288;
    unsigned short* Vth = sm + 16384;
    unsigned short* Vtl = sm + 16384 + 64 * AST;

    const int qoff = h * 64, koff = 512 + h * 64, voff = 1024 + h * 64;

    // ---- stage Q (pre-scaled at QKV epilogue) via gld, then hoist to regs
#pragma unroll
    for (int blk = 0; blk < 2; ++blk) {
        const int row = w * 16 + blk * 8 + lrow8;
        const int sc = lchunk ^ SW7(row);
        gld16(qkvh + (size_t)(tok0 + row) * 1536 + qoff + sc * 8,
              Ph + (w * 16 + blk * 8) * 64);
        gld16(qkvl + (size_t)(tok0 + row) * 1536 + qoff + sc * 8,
              Pl + (w * 16 + blk * 8) * 64);
    }
    __syncthreads();
    bf16x8 qfh[2], qfl[2];
#pragma unroll
    for (int ks = 0; ks < 2; ++ks) {
        qfh[ks] = *frag(Ph, w * 16 + ln, ks * 4 + g);
        qfl[ks] = *frag(Pl, w * 16 + ln, ks * 4 + g);
    }

    f32x4 o[4];
#pragma unroll
    for (int ni = 0; ni < 4; ++ni) o[ni] = (f32x4){0.f, 0.f, 0.f, 0.f};
    float mrow[4] = {-INFINITY, -INFINITY, -INFINITY, -INFINITY};
    float lrow[4] = {0.f, 0.f, 0.f, 0.f};

    const int p2 = tid & 31, dc = tid >> 5;   // V staging partition

    for (int kt = 0; kt < 16; ++kt) {
        const int kb2 = kbase0 + kt * 64;
        // ---- stage K via gld (linear LDS, pre-swizzled source)
#pragma unroll
        for (int blk = 0; blk < 2; ++blk) {
            const int row = w * 16 + blk * 8 + lrow8;
            const int sc = lchunk ^ SW7(row);
            gld16(qkvh + (size_t)(kb2 + row) * 1536 + koff + sc * 8,
                  Kh + (w * 16 + blk * 8) * 64);
            gld16(qkvl + (size_t)(kb2 + row) * 1536 + koff + sc * 8,
                  Kl + (w * 16 + blk * 8) * 64);
        }
        // ---- stage V transposed: 2 krows x 8 d per thread, packed b32 stores
        {
            const size_t b0 = (size_t)(kb2 + 2 * p2) * 1536 + voff + dc * 8;
            const bf16x8 h0 = *(const bf16x8*)(qkvh + b0);
            const bf16x8 h1 = *(const bf16x8*)(qkvh + b0 + 1536);
            const bf16x8 l0 = *(const bf16x8*)(qkvl + b0);
            const bf16x8 l1 = *(const bf16x8*)(qkvl + b0 + 1536);
#pragma unroll
            for (int j = 0; j < 8; ++j) {
                const unsigned hv = (unsigned)(unsigned short)h0[j]
                                  | ((unsigned)(unsigned short)h1[j] << 16);
                const unsigned lv = (unsigned)(unsigned short)l0[j]
                                  | ((unsigned)(unsigned short)l1[j] << 16);
                *(unsigned*)&Vth[(dc * 8 + j) * AST + 2 * p2] = hv;
                *(unsigned*)&Vtl[(dc * 8 + j) * AST + 2 * p2] = lv;
            }
        }
        __syncthreads();

        // ---- S = Q K^T (bf16x3)
        f32x4 s[4];
#pragma unroll
        for (int ni = 0; ni < 4; ++ni) s[ni] = (f32x4){0.f, 0.f, 0.f, 0.f};
#pragma unroll
        for (int ks = 0; ks < 2; ++ks) {
#pragma unroll
            for (int ni = 0; ni < 4; ++ni) {
                const bf16x8 kbh = *frag(Kh, ni * 16 + ln, ks * 4 + g);
                const bf16x8 kbl = *frag(Kl, ni * 16 + ln, ks * 4 + g);
                s[ni] = __builtin_amdgcn_mfma_f32_16x16x32_bf16(qfh[ks], kbh, s[ni], 0, 0, 0);
                s[ni] = __builtin_amdgcn_mfma_f32_16x16x32_bf16(qfh[ks], kbl, s[ni], 0, 0, 0);
                s[ni] = __builtin_amdgcn_mfma_f32_16x16x32_bf16(qfl[ks], kbh, s[ni], 0, 0, 0);
            }
        }

        // ---- online softmax (rows w*16 + 4g+r2; cols 16ni+ln)
        float tm[4];
#pragma unroll
        for (int r2 = 0; r2 < 4; ++r2)
            tm[r2] = fmaxf(fmaxf(s[0][r2], s[1][r2]), fmaxf(s[2][r2], s[3][r2]));
#pragma unroll
        for (int off = 1; off < 16; off <<= 1)
#pragma unroll
            for (int r2 = 0; r2 < 4; ++r2)
                tm[r2] = fmaxf(tm[r2], __shfl_xor(tm[r2], off));

        float alpha[4], psum[4];
#pragma unroll
        for (int r2 = 0; r2 < 4; ++r2) {
            const float mnew = fmaxf(mrow[r2], tm[r2]);
            alpha[r2] = __expf(mrow[r2] - mnew);
            mrow[r2] = mnew;
            psum[r2] = 0.f;
        }
#pragma unroll
        for (int ni = 0; ni < 4; ++ni) {
#pragma unroll
            for (int r2 = 0; r2 < 4; ++r2) {
                const float p = __expf(s[ni][r2] - mrow[r2]);
                psum[r2] += p;
                unsigned short h16, l16;
                split2(p, h16, l16);
                const int prow = w * 16 + g * 4 + r2;
                const int pc = (2 * ni + (ln >> 3)) ^ SW7(prow);
                Ph[prow * 64 + pc * 8 + (ln & 7)] = h16;
                Pl[prow * 64 + pc * 8 + (ln & 7)] = l16;
            }
        }
#pragma unroll
        for (int off = 1; off < 16; off <<= 1)
#pragma unroll
            for (int r2 = 0; r2 < 4; ++r2)
                psum[r2] += __shfl_xor(psum[r2], off);
#pragma unroll
        for (int r2 = 0; r2 < 4; ++r2)
            lrow[r2] = lrow[r2] * alpha[r2] + psum[r2];
#pragma unroll
        for (int ni = 0; ni < 4; ++ni)
#pragma unroll
            for (int r2 = 0; r2 < 4; ++r2)
                o[ni][r2] *= alpha[r2];
        // no barrier: each wave owns its 16 P rows

        // ---- O += P V (bf16x3)
#pragma unroll
        for (int ks = 0; ks < 2; ++ks) {
            const bf16x8 pah = *frag(Ph, w * 16 + ln, ks * 4 + g);
            const bf16x8 pal = *frag(Pl, w * 16 + ln, ks * 4 + g);
#pragma unroll
            for (int ni = 0; ni < 4; ++ni) {
                const bf16x8 vbh = *(const bf16x8*)&Vth[(ni * 16 + ln) * AST + ks * 32 + g * 8];
                const bf16x8 vbl = *(const bf16x8*)&Vtl[(ni * 16 + ln) * AST + ks * 32 + g * 8];
                o[ni] = __builtin_amdgcn_mfma_f32_16x16x32_bf16(pah, vbh, o[ni], 0, 0, 0);
                o[ni] = __builtin_amdgcn_mfma_f32_16x16x32_bf16(pah, vbl, o[ni], 0, 0, 0);
                o[ni] = __builtin_amdgcn_mfma_f32_16x16x32_bf16(pal, vbh, o[ni], 0, 0, 0);
            }
        }
        __syncthreads();   // PV done before next staging overwrites K/V
    }

    // ---- epilogue: write ctx hi/lo planes
#pragma unroll
    for (int r2 = 0; r2 < 4; ++r2) {
        const float inv = 1.0f / lrow[r2];
        const int row = tok0 + w * 16 + g * 4 + r2;
#pragma unroll
        for (int ni = 0; ni < 4; ++ni) {
            const float v = o[ni][r2] * inv;
            unsigned short h16, l16;
            split2(v, h16, l16);
            ctxh[(size_t)row * D_ + h * 64 + ni * 16 + ln] = h16;
            ctxl[(size_t)row * D_ + h * 64 + ni * 16 + ln] = l16;
        }
    }
}

// ---------------- top-8 candidates -> fp32 refine -> top-5 + softmax + gather
__global__ __launch_bounds__(64) void topk_kernel(
    const float* __restrict__ sim, const float* __restrict__ src2,
    const float* __restrict__ mn, const float* __restrict__ mem,
    const float* __restrict__ rs_ptr, float* __restrict__ out)
{
    const int row = blockIdx.x;
    const int lane = threadIdx.x;
    float v[16];
#pragma unroll
    for (int j = 0; j < 16; ++j)
        v[j] = sim[(size_t)row * SLOTS_ + j * 64 + lane];

    int ci[NCAND_];
#pragma unroll
    for (int t = 0; t < NCAND_; ++t) {
        float bv = -INFINITY;
        int bi = 0x7fffffff;
#pragma unroll
        for (int j = 0; j < 16; ++j) {
            const int idx = j * 64 + lane;
            if (v[j] > bv) { bv = v[j]; bi = idx; }
        }
#pragma unroll
        for (int off = 32; off; off >>= 1) {
            const float ov = __shfl_xor(bv, off);
            const int oi = __shfl_xor(bi, off);
            if (ov > bv || (ov == bv && oi < bi)) { bv = ov; bi = oi; }
        }
        ci[t] = bi;
#pragma unroll
        for (int j = 0; j < 16; ++j)
            if (j * 64 + lane == bi) v[j] = -INFINITY;
    }

    float x[8];
    float ss = 0.0f;
#pragma unroll
    for (int j = 0; j < 8; ++j) {
        x[j] = src2[(size_t)row * D_ + j * 64 + lane];
        ss += x[j] * x[j];
    }
#pragma unroll
    for (int off = 32; off; off >>= 1) ss += __shfl_xor(ss, off);
    const float invn = 1.0f / fmaxf(sqrtf(ss), 1e-12f);

    float rv[NCAND_];
#pragma unroll
    for (int t = 0; t < NCAND_; ++t) {
        const float* mrow = mn + (size_t)ci[t] * D_;
        float acc = 0.0f;
#pragma unroll
        for (int j = 0; j < 8; ++j)
            acc = fmaf(x[j], mrow[j * 64 + lane], acc);
#pragma unroll
        for (int off = 32; off; off >>= 1) acc += __shfl_xor(acc, off);
        rv[t] = acc * invn;
    }

    float wv[TOPK_];
    int wi[TOPK_];
    bool used[NCAND_];
#pragma unroll
    for (int t = 0; t < NCAND_; ++t) used[t] = false;
#pragma unroll
    for (int t = 0; t < TOPK_; ++t) {
        float bv = -INFINITY;
        int bi = 0x7fffffff, bu = 0;
#pragma unroll
        for (int u = 0; u < NCAND_; ++u) {
            if (!used[u] && (rv[u] > bv || (rv[u] == bv && ci[u] < bi))) {
                bv = rv[u]; bi = ci[u]; bu = u;
            }
        }
        used[bu] = true;
        wv[t] = bv;
        wi[t] = bi;
    }

    float m = wv[0];
#pragma unroll
    for (int t = 1; t < TOPK_; ++t) m = fmaxf(m, wv[t]);
    float w[TOPK_], ssum = 0.0f;
#pragma unroll
    for (int t = 0; t < TOPK_; ++t) { w[t] = expf(wv[t] - m); ssum += w[t]; }
    const float scale = rs_ptr[0] / ssum;

#pragma unroll
    for (int j = 0; j < 8; ++j) {
        const int d = j * 64 + lane;
        float acc = 0.0f;
#pragma unroll
        for (int t = 0; t < TOPK_; ++t)
            acc += w[t] * mem[(size_t)wi[t] * D_ + d];
        out[(size_t)row * D_ + d] = x[j] + scale * acc;
    }
}

// ----------------------------------------------------------------- launch
extern "C" void kernel_launch(void* const* d_in, const int* in_sizes, int n_in,
                              void* d_out, int out_size, void* d_ws, size_t ws_size,
                              hipStream_t stream)
{
    const float* src  = (const float*)d_in[0];
    const float* inw  = (const float*)d_in[1];
    const float* inb  = (const float*)d_in[2];
    const float* outw = (const float*)d_in[3];
    const float* outb = (const float*)d_in[4];
    const float* mem  = (const float*)d_in[5];
    const float* rs   = (const float*)d_in[6];
    const float* ln1g = (const float*)d_in[7];
    const float* ln1b = (const float*)d_in[8];
    const float* ln2g = (const float*)d_in[9];
    const float* ln2b = (const float*)d_in[10];
    const float* w1   = (const float*)d_in[11];
    const float* b1   = (const float*)d_in[12];
    const float* w2   = (const float*)d_in[13];
    const float* b2   = (const float*)d_in[14];
    float* out = (float*)d_out;
    char* ws = (char*)d_ws;
    const size_t MB = 1024ull * 1024ull;
    typedef unsigned short u16;

    // fixed region [0,13) MB
    float* mn   = (float*)(ws + 0);            // 2 MB
    u16* mnh    = (u16*)(ws + 2 * MB);         // 1
    u16* mnl    = (u16*)(ws + 3 * MB);         // 1
    u16* inwh   = (u16*)(ws + 4 * MB);         // 1.5
    u16* inwl   = (u16*)(ws + 5 * MB + 512 * 1024);
    u16* outwh  = (u16*)(ws + 7 * MB);         // 0.5
    u16* outwl  = (u16*)(ws + 7 * MB + 512 * 1024);
    u16* w1h    = (u16*)(ws + 8 * MB);         // 2
    u16* w2h    = (u16*)(ws + 10 * MB);        // 2
    float* invn = (float*)(ws + 12 * MB);      // 32 KB
    // dynamic
    u16* hh     = (u16*)(ws + 13 * MB);        // 8   [ln1 .. qkv]
    u16* hl     = (u16*)(ws + 21 * MB);        // 8
    u16* qkvh   = (u16*)(ws + 29 * MB);        // 24  [qkv .. attn]
    u16* qkvl   = (u16*)(ws + 53 * MB);        // 24
    u16* ctxh   = (u16*)(ws + 13 * MB);        // 8   [attn .. outproj] (reuse hh/hl)
    u16* ctxl   = (u16*)(ws + 21 * MB);        // 8
    float* sim  = (float*)(ws + 13 * MB);      // 32  [sim .. topk] (ctx dead)
    float* src2 = (float*)(ws + 45 * MB);      // 16  [outproj .. topk] (qkv dead)
    u16* src2h  = (u16*)(ws + 61 * MB);        // 8   [outproj .. sim]
    u16* src2l  = (u16*)(ws + 69 * MB);        // 8
    u16* h2h    = (u16*)(ws + 13 * MB);        // 8   [ln2 .. ffn1] (sim dead)
    u16* Gbf    = (u16*)(ws + 21 * MB);        // 32  [ffn1 .. ffn2]

    // 0) split weights into bf16 planes
    split_kernel<<<dim3(768), dim3(256), 0, stream>>>(inw, inwh, inwl, 3 * D_ * D_);
    split_kernel<<<dim3(256), dim3(256), 0, stream>>>(outw, outwh, outwl, D_ * D_);
    split_kernel<<<dim3(1024), dim3(256), 0, stream>>>(w1, w1h, nullptr, DFF_ * D_);
    split_kernel<<<dim3(1024), dim3(256), 0, stream>>>(w2, w2h, nullptr, D_ * DFF_);
    // 1) normalize memory rows (fp32 + planes)
    mn_kernel<<<dim3(SLOTS_), dim3(64), 0, stream>>>(mem, mn, mnh, mnl);
    // 2) LN1 -> planes
    ln_kernel<1><<<dim3(NTOK_), dim3(256), 0, stream>>>(src, ln1g, ln1b, hh, hl);
    // 3) QKV projection -> qkv planes (Q pre-scaled)
    gemm_mf<3, EP_QKV><<<dim3(64, 12), dim3(256), 0, stream>>>(
        hh, hl, inwh, inwl, inb, nullptr, nullptr, nullptr, qkvh, qkvl, NTOK_, 1536, 512);
    // 4) attention -> ctx planes
    attn_kernel<<<dim3(1024), dim3(256), 0, stream>>>(qkvh, qkvl, ctxh, ctxl);
    // 5) out projection + residual -> src2 fp32 + planes
    gemm_mf<3, EP_OUTPROJ><<<dim3(64, 4), dim3(256), 0, stream>>>(
        ctxh, ctxl, outwh, outwl, outb, src, nullptr, src2, src2h, src2l, NTOK_, 512, 512);
    // 6) row norms of src2
    rownorm_kernel<<<dim3(NTOK_), dim3(64), 0, stream>>>(src2, invn);
    // 7) sim = (src2 @ mn^T) * invn
    gemm_mf<3, EP_SIM><<<dim3(64, 8), dim3(256), 0, stream>>>(
        src2h, src2l, mnh, mnl, nullptr, nullptr, invn, sim, nullptr, nullptr, NTOK_, 1024, 512);
    // 8) top-5 (refined) + weighted retrieval -> d_out
    topk_kernel<<<dim3(NTOK_), dim3(64), 0, stream>>>(sim, src2, mn, mem, rs, out);
    // 9) LN2 -> h2 hi plane
    ln_kernel<0><<<dim3(NTOK_), dim3(256), 0, stream>>>(out, ln2g, ln2b, h2h, nullptr);
    // 10) FFN1 + GELU -> G bf16
    gemm_mf<1, EP_FFN1><<<dim3(64, 16), dim3(256), 0, stream>>>(
        h2h, nullptr, w1h, nullptr, b1, nullptr, nullptr, nullptr, Gbf, nullptr, NTOK_, 2048, 512);
    // 11) FFN2 + bias + residual -> d_out
    gemm_mf<1, EP_FFN2><<<dim3(64, 4), dim3(256), 0, stream>>>(
        Gbf, nullptr, w2h, nullptr, b2, out, nullptr, out, nullptr, nullptr, NTOK_, 512, 2048);
}

// Round 7
// 337.209 us; speedup vs baseline: 3.4426x; 1.0700x over previous
//
#include <hip/hip_runtime.h>
#include <math.h>

#define D_ 512
#define H_ 8
#define DFF_ 2048
#define SLOTS_ 1024
#define TOPK_ 5
#define NCAND_ 8
#define NTOK_ 8192
#define SEQ_ 1024
#define LN_EPS_ 1e-5f

typedef __attribute__((ext_vector_type(8))) short bf16x8;
typedef __attribute__((ext_vector_type(4))) float f32x4;
typedef __attribute__((ext_vector_type(4))) unsigned u32x4;

// split fp32 -> bf16 hi + bf16 lo (truncation; rem captured to ~2^-16 rel)
__device__ inline void split2(float x, unsigned short& hi, unsigned short& lo) {
    unsigned u = __builtin_bit_cast(unsigned, x);
    hi = (unsigned short)(u >> 16);
    float h = __builtin_bit_cast(float, u & 0xFFFF0000u);
    float rem = x - h;
    lo = (unsigned short)(__builtin_bit_cast(unsigned, rem) >> 16);
}

// async global->LDS, 16B per lane; LDS dest is wave-uniform base + lane*16
__device__ __forceinline__ void gld16(const void* g, void* l) {
    __builtin_amdgcn_global_load_lds(
        (const __attribute__((address_space(1))) void*)g,
        (__attribute__((address_space(3))) void*)l, 16, 0, 0);
}

// row swizzle for 64-col (8-chunk) bf16 planes
__device__ __forceinline__ int SW7(int r) { return (r ^ (r >> 3)) & 7; }
__device__ __forceinline__ const bf16x8* frag(const unsigned short* p, int r, int c) {
    return (const bf16x8*)(p + r * 64 + ((c ^ SW7(r)) << 3));
}

// ---------------------------------------------------------------- splitter
__global__ __launch_bounds__(256) void split_kernel(
    const float* __restrict__ x, unsigned short* __restrict__ hi,
    unsigned short* __restrict__ lo, int n)
{
    const int i = (blockIdx.x * 256 + threadIdx.x) * 4;
    if (i >= n) return;
    const float4 v = *(const float4*)(x + i);
    const float vv[4] = {v.x, v.y, v.z, v.w};
    unsigned short h[4], l[4];
#pragma unroll
    for (int e = 0; e < 4; ++e) split2(vv[e], h[e], l[e]);
    hi[i + 0] = h[0]; hi[i + 1] = h[1]; hi[i + 2] = h[2]; hi[i + 3] = h[3];
    if (lo) { lo[i + 0] = l[0]; lo[i + 1] = l[1]; lo[i + 2] = l[2]; lo[i + 3] = l[3]; }
}

// ---------------------------------------------------------------- LayerNorm -> planes
template <int WLO>
__global__ __launch_bounds__(256) void ln_kernel(
    const float* __restrict__ x, const float* __restrict__ g,
    const float* __restrict__ be, unsigned short* __restrict__ yh,
    unsigned short* __restrict__ yl)
{
    const int row = blockIdx.x;
    const int t = threadIdx.x;
    const float a = x[(size_t)row * D_ + t];
    const float b = x[(size_t)row * D_ + t + 256];
    float s = a + b;
    float ss = a * a + b * b;
#pragma unroll
    for (int off = 32; off; off >>= 1) {
        s += __shfl_xor(s, off);
        ss += __shfl_xor(ss, off);
    }
    __shared__ float rs[4], rss[4];
    if ((t & 63) == 0) { rs[t >> 6] = s; rss[t >> 6] = ss; }
    __syncthreads();
    s = rs[0] + rs[1] + rs[2] + rs[3];
    ss = rss[0] + rss[1] + rss[2] + rss[3];
    const float mu = s * (1.0f / D_);
    const float var = ss * (1.0f / D_) - mu * mu;
    const float r = rsqrtf(var + LN_EPS_);
    const float y0 = (a - mu) * r * g[t] + be[t];
    const float y1 = (b - mu) * r * g[t + 256] + be[t + 256];
    unsigned short h0, l0, h1, l1;
    split2(y0, h0, l0);
    split2(y1, h1, l1);
    yh[(size_t)row * D_ + t] = h0;
    yh[(size_t)row * D_ + t + 256] = h1;
    if (WLO) {
        yl[(size_t)row * D_ + t] = l0;
        yl[(size_t)row * D_ + t + 256] = l1;
    }
}

// ------------------------------------------------- normalize memory rows (+planes)
__global__ __launch_bounds__(64) void mn_kernel(
    const float* __restrict__ mem, float* __restrict__ mn,
    unsigned short* __restrict__ mnh, unsigned short* __restrict__ mnl)
{
    const int row = blockIdx.x;
    const int lane = threadIdx.x;
    float v[8];
    float ss = 0.0f;
#pragma unroll
    for (int j = 0; j < 8; ++j) {
        v[j] = mem[(size_t)row * D_ + j * 64 + lane];
        ss += v[j] * v[j];
    }
#pragma unroll
    for (int off = 32; off; off >>= 1) ss += __shfl_xor(ss, off);
    const float inv = 1.0f / fmaxf(sqrtf(ss), 1e-12f);
#pragma unroll
    for (int j = 0; j < 8; ++j) {
        const float y = v[j] * inv;
        mn[(size_t)row * D_ + j * 64 + lane] = y;
        unsigned short h, l;
        split2(y, h, l);
        mnh[(size_t)row * D_ + j * 64 + lane] = h;
        mnl[(size_t)row * D_ + j * 64 + lane] = l;
    }
}

// ------------------------------------------------- row inverse norms
__global__ __launch_bounds__(64) void rownorm_kernel(
    const float* __restrict__ x, float* __restrict__ invn)
{
    const int row = blockIdx.x;
    const int lane = threadIdx.x;
    float ss = 0.0f;
#pragma unroll
    for (int j = 0; j < 8; ++j) {
        const float v = x[(size_t)row * D_ + j * 64 + lane];
        ss += v * v;
    }
#pragma unroll
    for (int off = 32; off; off >>= 1) ss += __shfl_xor(ss, off);
    if (lane == 0) invn[row] = 1.0f / fmaxf(sqrtf(ss), 1e-12f);
}

// ------------------------------------------------- MFMA GEMM (NT), 128x128 tile
enum { EP_QKV = 0, EP_OUTPROJ = 1, EP_SIM = 2, EP_FFN1 = 3, EP_FFN2 = 4 };

template <int SPLIT, int MODE>
__global__ __launch_bounds__(256) void gemm_mf(
    const unsigned short* __restrict__ Ahg, const unsigned short* __restrict__ Alg,
    const unsigned short* __restrict__ Bhg, const unsigned short* __restrict__ Blg,
    const float* __restrict__ bias, const float* __restrict__ res,
    const float* __restrict__ rowscale, float* __restrict__ C,
    unsigned short* __restrict__ Ch, unsigned short* __restrict__ Cl,
    int M, int N, int K)
{
    __shared__ __align__(16) unsigned short sm[(SPLIT == 3 ? 4 : 2) * 8192];
    unsigned short* Ah = sm;
    unsigned short* Al = sm + 8192;
    unsigned short* Bh = sm + (SPLIT == 3 ? 16384 : 8192);
    unsigned short* Bl = sm + 24576;

    const int tid = threadIdx.x;
    const int lane = tid & 63;
    const int w = tid >> 6;
    const int wr = w >> 1, wc = w & 1;
    const int g = lane >> 4, ln = lane & 15;
    const int m0 = blockIdx.x * 128, n0 = blockIdx.y * 128;
    const int lrow8 = lane >> 3, lchunk = lane & 7;

    const unsigned short* gsrc;
    unsigned short* lds;
    int rbase, rofs, nblk;
    if (SPLIT == 3) {
        nblk = 16; rofs = 0;
        if (w == 0)      { gsrc = Ahg; lds = Ah; rbase = m0; }
        else if (w == 1) { gsrc = Alg; lds = Al; rbase = m0; }
        else if (w == 2) { gsrc = Bhg; lds = Bh; rbase = n0; }
        else             { gsrc = Blg; lds = Bl; rbase = n0; }
    } else {
        nblk = 8; rofs = (w & 1) * 64;
        if (w < 2) { gsrc = Ahg; lds = Ah; rbase = m0; }
        else       { gsrc = Bhg; lds = Bh; rbase = n0; }
    }

    f32x4 acc[4][4];
#pragma unroll
    for (int i = 0; i < 4; ++i)
#pragma unroll
        for (int j = 0; j < 4; ++j) acc[i][j] = (f32x4){0.f, 0.f, 0.f, 0.f};

    for (int k0 = 0; k0 < K; k0 += 64) {
#pragma unroll
        for (int blk = 0; blk < nblk; ++blk) {
            const int row = rofs + blk * 8 + lrow8;
            const int sc = lchunk ^ SW7(row);
            gld16(gsrc + (size_t)(rbase + row) * K + k0 + sc * 8,
                  lds + (rofs + blk * 8) * 64);
        }
        __syncthreads();

#pragma unroll
        for (int ks = 0; ks < 2; ++ks) {
            bf16x8 a_h[4], a_l[4], b_h[4], b_l[4];
#pragma unroll
            for (int mi = 0; mi < 4; ++mi) {
                a_h[mi] = *frag(Ah, wr * 64 + mi * 16 + ln, ks * 4 + g);
                if (SPLIT == 3) a_l[mi] = *frag(Al, wr * 64 + mi * 16 + ln, ks * 4 + g);
            }
#pragma unroll
            for (int ni = 0; ni < 4; ++ni) {
                b_h[ni] = *frag(Bh, wc * 64 + ni * 16 + ln, ks * 4 + g);
                if (SPLIT == 3) b_l[ni] = *frag(Bl, wc * 64 + ni * 16 + ln, ks * 4 + g);
            }
#pragma unroll
            for (int mi = 0; mi < 4; ++mi)
#pragma unroll
                for (int ni = 0; ni < 4; ++ni) {
                    acc[mi][ni] = __builtin_amdgcn_mfma_f32_16x16x32_bf16(
                        a_h[mi], b_h[ni], acc[mi][ni], 0, 0, 0);
                    if (SPLIT == 3) {
                        acc[mi][ni] = __builtin_amdgcn_mfma_f32_16x16x32_bf16(
                            a_h[mi], b_l[ni], acc[mi][ni], 0, 0, 0);
                        acc[mi][ni] = __builtin_amdgcn_mfma_f32_16x16x32_bf16(
                            a_l[mi], b_h[ni], acc[mi][ni], 0, 0, 0);
                    }
                }
        }
        __syncthreads();
    }

#pragma unroll
    for (int mi = 0; mi < 4; ++mi) {
#pragma unroll
        for (int ni = 0; ni < 4; ++ni) {
            const int gn = n0 + wc * 64 + ni * 16 + ln;
            const float bz = (MODE == EP_SIM) ? 0.0f : bias[gn];
#pragma unroll
            for (int r2 = 0; r2 < 4; ++r2) {
                const int gm = m0 + wr * 64 + mi * 16 + g * 4 + r2;
                float v = acc[mi][ni][r2];
                if (MODE == EP_SIM) {
                    v *= rowscale[gm];
                    C[(size_t)gm * N + gn] = v;
                } else if (MODE == EP_QKV) {
                    v += bz;
                    if (gn < D_) v *= 0.125f;   // fold 1/sqrt(DH) into Q
                    unsigned short h16, l16;
                    split2(v, h16, l16);
                    Ch[(size_t)gm * N + gn] = h16;
                    Cl[(size_t)gm * N + gn] = l16;
                } else if (MODE == EP_OUTPROJ) {
                    v += bz + res[(size_t)gm * N + gn];
                    C[(size_t)gm * N + gn] = v;
                    unsigned short h16, l16;
                    split2(v, h16, l16);
                    Ch[(size_t)gm * N + gn] = h16;
                    Cl[(size_t)gm * N + gn] = l16;
                } else if (MODE == EP_FFN1) {
                    v += bz;
                    v = 0.5f * v * (1.0f + erff(v * 0.70710678118654752f));
                    unsigned short h16, l16;
                    split2(v, h16, l16);
                    Ch[(size_t)gm * N + gn] = h16;
                } else {   // EP_FFN2
                    v += bz + res[(size_t)gm * N + gn];
                    C[(size_t)gm * N + gn] = v;
                }
            }
        }
    }
}

// ------------------------------------------------- flash attention, MFMA bf16x3
// 128 q-rows/block, 4 waves x 32 rows; P packed u32 (h | l<<16)
__global__ __launch_bounds__(256, 2) void attn_kernel(
    const unsigned short* __restrict__ qkvh, const unsigned short* __restrict__ qkvl,
    unsigned short* __restrict__ ctxh, unsigned short* __restrict__ ctxl)
{
    const int id = blockIdx.x;          // 0..511
    const int bh = id & 63;             // stride-64 blocks share (b,h) -> same XCD
    const int qt = id >> 6;             // 0..7
    const int b = bh >> 3, h = bh & 7;
    const int tok0 = b * SEQ_ + qt * 128;
    const int kbase0 = b * SEQ_;
    const int tid = threadIdx.x;
    const int lane = tid & 63;
    const int w = tid >> 6;             // wave: 32-row m-strip
    const int ln = lane & 15, g = lane >> 4;
    const int lrow8 = lane >> 3, lchunk = lane & 7;

    // 64 KB: PP u32[128][64] (Q staged here first) | Kh Kl Vth Vtl u16[64][64]
    __shared__ __align__(16) unsigned char smb[65536];
    unsigned*       PP  = (unsigned*)smb;
    unsigned short* Qh  = (unsigned short*)smb;
    unsigned short* Ql  = (unsigned short*)(smb + 16384);
    unsigned short* Kh  = (unsigned short*)(smb + 32768);
    unsigned short* Kl  = (unsigned short*)(smb + 40960);
    unsigned short* Vth = (unsigned short*)(smb + 49152);
    unsigned short* Vtl = (unsigned short*)(smb + 57344);

    const int qoff = h * 64, koff = 512 + h * 64, voff = 1024 + h * 64;

    // ---- stage Q rows w*32..w*32+31 (both planes), then hoist fragments
#pragma unroll
    for (int blk = 0; blk < 4; ++blk) {
        const int row = w * 32 + blk * 8 + lrow8;
        const int sc = lchunk ^ SW7(row);
        gld16(qkvh + (size_t)(tok0 + row) * 1536 + qoff + sc * 8,
              Qh + (w * 32 + blk * 8) * 64);
        gld16(qkvl + (size_t)(tok0 + row) * 1536 + qoff + sc * 8,
              Ql + (w * 32 + blk * 8) * 64);
    }
    __syncthreads();
    bf16x8 qfh[2][2], qfl[2][2];
#pragma unroll
    for (int mi = 0; mi < 2; ++mi)
#pragma unroll
        for (int ks = 0; ks < 2; ++ks) {
            qfh[mi][ks] = *frag(Qh, w * 32 + mi * 16 + ln, ks * 4 + g);
            qfl[mi][ks] = *frag(Ql, w * 32 + mi * 16 + ln, ks * 4 + g);
        }

    f32x4 o[2][4];
#pragma unroll
    for (int mi = 0; mi < 2; ++mi)
#pragma unroll
        for (int ni = 0; ni < 4; ++ni) o[mi][ni] = (f32x4){0.f, 0.f, 0.f, 0.f};
    float mrow[2][4], lrow[2][4];
#pragma unroll
    for (int mi = 0; mi < 2; ++mi)
#pragma unroll
        for (int r2 = 0; r2 < 4; ++r2) { mrow[mi][r2] = -INFINITY; lrow[mi][r2] = 0.f; }

    const int p2 = tid & 31, dc = tid >> 5;   // V staging partition

    for (int kt = 0; kt < 16; ++kt) {
        const int kb2 = kbase0 + kt * 64;
        // ---- stage K: wave w stages rows w*16..w*16+15, both planes
#pragma unroll
        for (int blk = 0; blk < 2; ++blk) {
            const int row = w * 16 + blk * 8 + lrow8;
            const int sc = lchunk ^ SW7(row);
            gld16(qkvh + (size_t)(kb2 + row) * 1536 + koff + sc * 8,
                  Kh + (w * 16 + blk * 8) * 64);
            gld16(qkvl + (size_t)(kb2 + row) * 1536 + koff + sc * 8,
                  Kl + (w * 16 + blk * 8) * 64);
        }
        // ---- stage V transposed into swizzled [d][64k] planes (b32 pair stores)
        {
            const size_t b0 = (size_t)(kb2 + 2 * p2) * 1536 + voff + dc * 8;
            const bf16x8 h0 = *(const bf16x8*)(qkvh + b0);
            const bf16x8 h1 = *(const bf16x8*)(qkvh + b0 + 1536);
            const bf16x8 l0 = *(const bf16x8*)(qkvl + b0);
            const bf16x8 l1 = *(const bf16x8*)(qkvl + b0 + 1536);
#pragma unroll
            for (int j = 0; j < 8; ++j) {
                const int d = dc * 8 + j;
                const int idx = d * 64 + (((p2 >> 2) ^ SW7(d)) << 3) + ((p2 & 3) << 1);
                *(unsigned*)&Vth[idx] = (unsigned)(unsigned short)h0[j]
                                      | ((unsigned)(unsigned short)h1[j] << 16);
                *(unsigned*)&Vtl[idx] = (unsigned)(unsigned short)l0[j]
                                      | ((unsigned)(unsigned short)l1[j] << 16);
            }
        }
        __syncthreads();

        // ---- S = Q K^T (bf16x3)
        f32x4 s[2][4];
#pragma unroll
        for (int mi = 0; mi < 2; ++mi)
#pragma unroll
            for (int ni = 0; ni < 4; ++ni) s[mi][ni] = (f32x4){0.f, 0.f, 0.f, 0.f};
#pragma unroll
        for (int ks = 0; ks < 2; ++ks) {
            bf16x8 kbh[4], kbl[4];
#pragma unroll
            for (int ni = 0; ni < 4; ++ni) {
                kbh[ni] = *frag(Kh, ni * 16 + ln, ks * 4 + g);
                kbl[ni] = *frag(Kl, ni * 16 + ln, ks * 4 + g);
            }
#pragma unroll
            for (int mi = 0; mi < 2; ++mi)
#pragma unroll
                for (int ni = 0; ni < 4; ++ni) {
                    s[mi][ni] = __builtin_amdgcn_mfma_f32_16x16x32_bf16(qfh[mi][ks], kbh[ni], s[mi][ni], 0, 0, 0);
                    s[mi][ni] = __builtin_amdgcn_mfma_f32_16x16x32_bf16(qfh[mi][ks], kbl[ni], s[mi][ni], 0, 0, 0);
                    s[mi][ni] = __builtin_amdgcn_mfma_f32_16x16x32_bf16(qfl[mi][ks], kbh[ni], s[mi][ni], 0, 0, 0);
                }
        }

        // ---- online softmax (rows w*32 + mi*16 + g*4 + r2; cols 16ni+ln)
        float tm[2][4];
#pragma unroll
        for (int mi = 0; mi < 2; ++mi)
#pragma unroll
            for (int r2 = 0; r2 < 4; ++r2)
                tm[mi][r2] = fmaxf(fmaxf(s[mi][0][r2], s[mi][1][r2]),
                                   fmaxf(s[mi][2][r2], s[mi][3][r2]));
#pragma unroll
        for (int off = 1; off < 16; off <<= 1)
#pragma unroll
            for (int mi = 0; mi < 2; ++mi)
#pragma unroll
                for (int r2 = 0; r2 < 4; ++r2)
                    tm[mi][r2] = fmaxf(tm[mi][r2], __shfl_xor(tm[mi][r2], off));

        float alpha[2][4], psum[2][4];
#pragma unroll
        for (int mi = 0; mi < 2; ++mi)
#pragma unroll
            for (int r2 = 0; r2 < 4; ++r2) {
                const float mnew = fmaxf(mrow[mi][r2], tm[mi][r2]);
                alpha[mi][r2] = __expf(mrow[mi][r2] - mnew);
                mrow[mi][r2] = mnew;
                psum[mi][r2] = 0.f;
            }
#pragma unroll
        for (int mi = 0; mi < 2; ++mi)
#pragma unroll
            for (int ni = 0; ni < 4; ++ni)
#pragma unroll
                for (int r2 = 0; r2 < 4; ++r2) {
                    const float p = __expf(s[mi][ni][r2] - mrow[mi][r2]);
                    psum[mi][r2] += p;
                    unsigned short h16, l16;
                    split2(p, h16, l16);
                    const int prow = w * 32 + mi * 16 + g * 4 + r2;
                    PP[prow * 64 + (((2 * ni + (ln >> 3)) ^ SW7(prow)) << 3) + (ln & 7)]
                        = (unsigned)h16 | ((unsigned)l16 << 16);
                }
#pragma unroll
        for (int off = 1; off < 16; off <<= 1)
#pragma unroll
            for (int mi = 0; mi < 2; ++mi)
#pragma unroll
                for (int r2 = 0; r2 < 4; ++r2)
                    psum[mi][r2] += __shfl_xor(psum[mi][r2], off);
#pragma unroll
        for (int mi = 0; mi < 2; ++mi)
#pragma unroll
            for (int r2 = 0; r2 < 4; ++r2)
                lrow[mi][r2] = lrow[mi][r2] * alpha[mi][r2] + psum[mi][r2];
#pragma unroll
        for (int mi = 0; mi < 2; ++mi)
#pragma unroll
            for (int ni = 0; ni < 4; ++ni)
#pragma unroll
                for (int r2 = 0; r2 < 4; ++r2)
                    o[mi][ni][r2] *= alpha[mi][r2];
        // no barrier: each wave writes/reads only its own 32 P rows

        // ---- O += P V (bf16x3); P read via b128 + v_perm deinterleave
#pragma unroll
        for (int ks = 0; ks < 2; ++ks) {
            bf16x8 pah[2], pal[2];
#pragma unroll
            for (int mi = 0; mi < 2; ++mi) {
                const int r = w * 32 + mi * 16 + ln;
                const unsigned* pp = PP + r * 64 + (((ks * 4 + g) ^ SW7(r)) << 3);
                const u32x4 q0 = *(const u32x4*)pp;
                const u32x4 q1 = *(const u32x4*)(pp + 4);
                u32x4 hu, lu;
                hu[0] = __builtin_amdgcn_perm(q0[1], q0[0], 0x05040100u);
                hu[1] = __builtin_amdgcn_perm(q0[3], q0[2], 0x05040100u);
                hu[2] = __builtin_amdgcn_perm(q1[1], q1[0], 0x05040100u);
                hu[3] = __builtin_amdgcn_perm(q1[3], q1[2], 0x05040100u);
                lu[0] = __builtin_amdgcn_perm(q0[1], q0[0], 0x07060302u);
                lu[1] = __builtin_amdgcn_perm(q0[3], q0[2], 0x07060302u);
                lu[2] = __builtin_amdgcn_perm(q1[1], q1[0], 0x07060302u);
                lu[3] = __builtin_amdgcn_perm(q1[3], q1[2], 0x07060302u);
                pah[mi] = __builtin_bit_cast(bf16x8, hu);
                pal[mi] = __builtin_bit_cast(bf16x8, lu);
            }
#pragma unroll
            for (int ni = 0; ni < 4; ++ni) {
                const bf16x8 vbh = *frag(Vth, ni * 16 + ln, ks * 4 + g);
                const bf16x8 vbl = *frag(Vtl, ni * 16 + ln, ks * 4 + g);
#pragma unroll
                for (int mi = 0; mi < 2; ++mi) {
                    o[mi][ni] = __builtin_amdgcn_mfma_f32_16x16x32_bf16(pah[mi], vbh, o[mi][ni], 0, 0, 0);
                    o[mi][ni] = __builtin_amdgcn_mfma_f32_16x16x32_bf16(pah[mi], vbl, o[mi][ni], 0, 0, 0);
                    o[mi][ni] = __builtin_amdgcn_mfma_f32_16x16x32_bf16(pal[mi], vbh, o[mi][ni], 0, 0, 0);
                }
            }
        }
        __syncthreads();   // PV done before next staging overwrites K/V
    }

    // ---- epilogue: write ctx hi/lo planes
#pragma unroll
    for (int mi = 0; mi < 2; ++mi)
#pragma unroll
        for (int r2 = 0; r2 < 4; ++r2) {
            const float inv = 1.0f / lrow[mi][r2];
            const int row = tok0 + w * 32 + mi * 16 + g * 4 + r2;
#pragma unroll
            for (int ni = 0; ni < 4; ++ni) {
                const float v = o[mi][ni][r2] * inv;
                unsigned short h16, l16;
                split2(v, h16, l16);
                ctxh[(size_t)row * D_ + h * 64 + ni * 16 + ln] = h16;
                ctxl[(size_t)row * D_ + h * 64 + ni * 16 + ln] = l16;
            }
        }
}

// ---------------- top-8 candidates -> fp32 refine -> top-5 + softmax + gather
__global__ __launch_bounds__(64) void topk_kernel(
    const float* __restrict__ sim, const float* __restrict__ src2,
    const float* __restrict__ mn, const float* __restrict__ mem,
    const float* __restrict__ rs_ptr, float* __restrict__ out)
{
    const int row = blockIdx.x;
    const int lane = threadIdx.x;
    float v[16];
#pragma unroll
    for (int j = 0; j < 16; ++j)
        v[j] = sim[(size_t)row * SLOTS_ + j * 64 + lane];

    int ci[NCAND_];
#pragma unroll
    for (int t = 0; t < NCAND_; ++t) {
        float bv = -INFINITY;
        int bi = 0x7fffffff;
#pragma unroll
        for (int j = 0; j < 16; ++j) {
            const int idx = j * 64 + lane;
            if (v[j] > bv) { bv = v[j]; bi = idx; }
        }
#pragma unroll
        for (int off = 32; off; off >>= 1) {
            const float ov = __shfl_xor(bv, off);
            const int oi = __shfl_xor(bi, off);
            if (ov > bv || (ov == bv && oi < bi)) { bv = ov; bi = oi; }
        }
        ci[t] = bi;
#pragma unroll
        for (int j = 0; j < 16; ++j)
            if (j * 64 + lane == bi) v[j] = -INFINITY;
    }

    float x[8];
    float ss = 0.0f;
#pragma unroll
    for (int j = 0; j < 8; ++j) {
        x[j] = src2[(size_t)row * D_ + j * 64 + lane];
        ss += x[j] * x[j];
    }
#pragma unroll
    for (int off = 32; off; off >>= 1) ss += __shfl_xor(ss, off);
    const float invn = 1.0f / fmaxf(sqrtf(ss), 1e-12f);

    float rv[NCAND_];
#pragma unroll
    for (int t = 0; t < NCAND_; ++t) {
        const float* mrow = mn + (size_t)ci[t] * D_;
        float acc = 0.0f;
#pragma unroll
        for (int j = 0; j < 8; ++j)
            acc = fmaf(x[j], mrow[j * 64 + lane], acc);
#pragma unroll
        for (int off = 32; off; off >>= 1) acc += __shfl_xor(acc, off);
        rv[t] = acc * invn;
    }

    float wv[TOPK_];
    int wi[TOPK_];
    bool used[NCAND_];
#pragma unroll
    for (int t = 0; t < NCAND_; ++t) used[t] = false;
#pragma unroll
    for (int t = 0; t < TOPK_; ++t) {
        float bv = -INFINITY;
        int bi = 0x7fffffff, bu = 0;
#pragma unroll
        for (int u = 0; u < NCAND_; ++u) {
            if (!used[u] && (rv[u] > bv || (rv[u] == bv && ci[u] < bi))) {
                bv = rv[u]; bi = ci[u]; bu = u;
            }
        }
        used[bu] = true;
        wv[t] = bv;
        wi[t] = bi;
    }

    float m = wv[0];
#pragma unroll
    for (int t = 1; t < TOPK_; ++t) m = fmaxf(m, wv[t]);
    float w[TOPK_], ssum = 0.0f;
#pragma unroll
    for (int t = 0; t < TOPK_; ++t) { w[t] = expf(wv[t] - m); ssum += w[t]; }
    const float scale = rs_ptr[0] / ssum;

#pragma unroll
    for (int j = 0; j < 8; ++j) {
        const int d = j * 64 + lane;
        float acc = 0.0f;
#pragma unroll
        for (int t = 0; t < TOPK_; ++t)
            acc += w[t] * mem[(size_t)wi[t] * D_ + d];
        out[(size_t)row * D_ + d] = x[j] + scale * acc;
    }
}

// ----------------------------------------------------------------- launch
extern "C" void kernel_launch(void* const* d_in, const int* in_sizes, int n_in,
                              void* d_out, int out_size, void* d_ws, size_t ws_size,
                              hipStream_t stream)
{
    const float* src  = (const float*)d_in[0];
    const float* inw  = (const float*)d_in[1];
    const float* inb  = (const float*)d_in[2];
    const float* outw = (const float*)d_in[3];
    const float* outb = (const float*)d_in[4];
    const float* mem  = (const float*)d_in[5];
    const float* rs   = (const float*)d_in[6];
    const float* ln1g = (const float*)d_in[7];
    const float* ln1b = (const float*)d_in[8];
    const float* ln2g = (const float*)d_in[9];
    const float* ln2b = (const float*)d_in[10];
    const float* w1   = (const float*)d_in[11];
    const float* b1   = (const float*)d_in[12];
    const float* w2   = (const float*)d_in[13];
    const float* b2   = (const float*)d_in[14];
    float* out = (float*)d_out;
    char* ws = (char*)d_ws;
    const size_t MB = 1024ull * 1024ull;
    typedef unsigned short u16;

    // fixed region [0,13) MB
    float* mn   = (float*)(ws + 0);            // 2 MB
    u16* mnh    = (u16*)(ws + 2 * MB);         // 1
    u16* mnl    = (u16*)(ws + 3 * MB);         // 1
    u16* inwh   = (u16*)(ws + 4 * MB);         // 1.5
    u16* inwl   = (u16*)(ws + 5 * MB + 512 * 1024);
    u16* outwh  = (u16*)(ws + 7 * MB);         // 0.5
    u16* outwl  = (u16*)(ws + 7 * MB + 512 * 1024);
    u16* w1h    = (u16*)(ws + 8 * MB);         // 2
    u16* w2h    = (u16*)(ws + 10 * MB);        // 2
    float* invn = (float*)(ws + 12 * MB);      // 32 KB
    // dynamic
    u16* hh     = (u16*)(ws + 13 * MB);        // 8   [ln1 .. qkv]
    u16* hl     = (u16*)(ws + 21 * MB);        // 8
    u16* qkvh   = (u16*)(ws + 29 * MB);        // 24  [qkv .. attn]
    u16* qkvl   = (u16*)(ws + 53 * MB);        // 24
    u16* ctxh   = (u16*)(ws + 13 * MB);        // 8   [attn .. outproj] (reuse hh/hl)
    u16* ctxl   = (u16*)(ws + 21 * MB);        // 8
    float* sim  = (float*)(ws + 13 * MB);      // 32  [sim .. topk] (ctx dead)
    float* src2 = (float*)(ws + 45 * MB);      // 16  [outproj .. topk] (qkv dead)
    u16* src2h  = (u16*)(ws + 61 * MB);        // 8   [outproj .. sim]
    u16* src2l  = (u16*)(ws + 69 * MB);        // 8
    u16* h2h    = (u16*)(ws + 13 * MB);        // 8   [ln2 .. ffn1] (sim dead)
    u16* Gbf    = (u16*)(ws + 21 * MB);        // 32  [ffn1 .. ffn2]

    split_kernel<<<dim3(768), dim3(256), 0, stream>>>(inw, inwh, inwl, 3 * D_ * D_);
    split_kernel<<<dim3(256), dim3(256), 0, stream>>>(outw, outwh, outwl, D_ * D_);
    split_kernel<<<dim3(1024), dim3(256), 0, stream>>>(w1, w1h, nullptr, DFF_ * D_);
    split_kernel<<<dim3(1024), dim3(256), 0, stream>>>(w2, w2h, nullptr, D_ * DFF_);
    mn_kernel<<<dim3(SLOTS_), dim3(64), 0, stream>>>(mem, mn, mnh, mnl);
    ln_kernel<1><<<dim3(NTOK_), dim3(256), 0, stream>>>(src, ln1g, ln1b, hh, hl);
    gemm_mf<3, EP_QKV><<<dim3(64, 12), dim3(256), 0, stream>>>(
        hh, hl, inwh, inwl, inb, nullptr, nullptr, nullptr, qkvh, qkvl, NTOK_, 1536, 512);
    attn_kernel<<<dim3(512), dim3(256), 0, stream>>>(qkvh, qkvl, ctxh, ctxl);
    gemm_mf<3, EP_OUTPROJ><<<dim3(64, 4), dim3(256), 0, stream>>>(
        ctxh, ctxl, outwh, outwl, outb, src, nullptr, src2, src2h, src2l, NTOK_, 512, 512);
    rownorm_kernel<<<dim3(NTOK_), dim3(64), 0, stream>>>(src2, invn);
    gemm_mf<3, EP_SIM><<<dim3(64, 8), dim3(256), 0, stream>>>(
        src2h, src2l, mnh, mnl, nullptr, nullptr, invn, sim, nullptr, nullptr, NTOK_, 1024, 512);
    topk_kernel<<<dim3(NTOK_), dim3(64), 0, stream>>>(sim, src2, mn, mem, rs, out);
    ln_kernel<0><<<dim3(NTOK_), dim3(256), 0, stream>>>(out, ln2g, ln2b, h2h, nullptr);
    gemm_mf<1, EP_FFN1><<<dim3(64, 16), dim3(256), 0, stream>>>(
        h2h, nullptr, w1h, nullptr, b1, nullptr, nullptr, nullptr, Gbf, nullptr, NTOK_, 2048, 512);
    gemm_mf<1, EP_FFN2><<<dim3(64, 4), dim3(256), 0, stream>>>(
        Gbf, nullptr, w2h, nullptr, b2, out, nullptr, out, nullptr, nullptr, NTOK_, 512, 2048);
}

// Round 8
// 302.873 us; speedup vs baseline: 3.8329x; 1.1134x over previous
//
#include <hip/hip_runtime.h>
#include <math.h>

#define D_ 512
#define H_ 8
#define DFF_ 2048
#define SLOTS_ 1024
#define TOPK_ 5
#define NCAND_ 8
#define NTOK_ 8192
#define SEQ_ 1024
#define LN_EPS_ 1e-5f

typedef __attribute__((ext_vector_type(8))) short bf16x8;
typedef __attribute__((ext_vector_type(4))) float f32x4;
typedef __attribute__((ext_vector_type(4))) unsigned u32x4;

// split fp32 -> bf16 hi + bf16 lo (truncation; rem captured to ~2^-16 rel)
__device__ inline void split2(float x, unsigned short& hi, unsigned short& lo) {
    unsigned u = __builtin_bit_cast(unsigned, x);
    hi = (unsigned short)(u >> 16);
    float h = __builtin_bit_cast(float, u & 0xFFFF0000u);
    float rem = x - h;
    lo = (unsigned short)(__builtin_bit_cast(unsigned, rem) >> 16);
}

__device__ __forceinline__ void gld16(const void* g, void* l) {
    __builtin_amdgcn_global_load_lds(
        (const __attribute__((address_space(1))) void*)g,
        (__attribute__((address_space(3))) void*)l, 16, 0, 0);
}

__device__ __forceinline__ int SW7(int r) { return (r ^ (r >> 3)) & 7; }
__device__ __forceinline__ const bf16x8* frag(const unsigned short* p, int r, int c) {
    return (const bf16x8*)(p + r * 64 + ((c ^ SW7(r)) << 3));
}

// ---------------------------------------------------------------- weight splitter (all 4 weights)
__global__ __launch_bounds__(256) void splitall_kernel(
    const float* __restrict__ inw, const float* __restrict__ outw,
    const float* __restrict__ w1, const float* __restrict__ w2,
    unsigned short* __restrict__ inwh, unsigned short* __restrict__ inwl,
    unsigned short* __restrict__ outwh, unsigned short* __restrict__ outwl,
    unsigned short* __restrict__ w1h, unsigned short* __restrict__ w2h)
{
    const int i = (blockIdx.x * 256 + threadIdx.x) * 4;
    const float* x;
    unsigned short *hh, *ll;
    int base;
    if (i < 786432)       { x = inw;  hh = inwh;  ll = inwl;  base = 0; }
    else if (i < 1048576) { x = outw; hh = outwh; ll = outwl; base = 786432; }
    else if (i < 2097152) { x = w1;   hh = w1h;   ll = nullptr; base = 1048576; }
    else                  { x = w2;   hh = w2h;   ll = nullptr; base = 2097152; }
    const int j = i - base;
    const float4 v = *(const float4*)(x + j);
    const float vv[4] = {v.x, v.y, v.z, v.w};
    unsigned short h[4], l[4];
#pragma unroll
    for (int e = 0; e < 4; ++e) split2(vv[e], h[e], l[e]);
    hh[j + 0] = h[0]; hh[j + 1] = h[1]; hh[j + 2] = h[2]; hh[j + 3] = h[3];
    if (ll) { ll[j + 0] = l[0]; ll[j + 1] = l[1]; ll[j + 2] = l[2]; ll[j + 3] = l[3]; }
}

// ---------------------------------------------------------------- LayerNorm -> planes
__global__ __launch_bounds__(256) void ln_kernel(
    const float* __restrict__ x, const float* __restrict__ g,
    const float* __restrict__ be, unsigned short* __restrict__ yh,
    unsigned short* __restrict__ yl)
{
    const int row = blockIdx.x;
    const int t = threadIdx.x;
    const float a = x[(size_t)row * D_ + t];
    const float b = x[(size_t)row * D_ + t + 256];
    float s = a + b;
    float ss = a * a + b * b;
#pragma unroll
    for (int off = 32; off; off >>= 1) {
        s += __shfl_xor(s, off);
        ss += __shfl_xor(ss, off);
    }
    __shared__ float rs[4], rss[4];
    if ((t & 63) == 0) { rs[t >> 6] = s; rss[t >> 6] = ss; }
    __syncthreads();
    s = rs[0] + rs[1] + rs[2] + rs[3];
    ss = rss[0] + rss[1] + rss[2] + rss[3];
    const float mu = s * (1.0f / D_);
    const float var = ss * (1.0f / D_) - mu * mu;
    const float r = rsqrtf(var + LN_EPS_);
    const float y0 = (a - mu) * r * g[t] + be[t];
    const float y1 = (b - mu) * r * g[t + 256] + be[t + 256];
    unsigned short h0, l0, h1, l1;
    split2(y0, h0, l0);
    split2(y1, h1, l1);
    yh[(size_t)row * D_ + t] = h0;
    yh[(size_t)row * D_ + t + 256] = h1;
    yl[(size_t)row * D_ + t] = l0;
    yl[(size_t)row * D_ + t + 256] = l1;
}

// ------------------------------------------------- normalize memory rows (+planes)
__global__ __launch_bounds__(64) void mn_kernel(
    const float* __restrict__ mem, float* __restrict__ mn,
    unsigned short* __restrict__ mnh, unsigned short* __restrict__ mnl)
{
    const int row = blockIdx.x;
    const int lane = threadIdx.x;
    float v[8];
    float ss = 0.0f;
#pragma unroll
    for (int j = 0; j < 8; ++j) {
        v[j] = mem[(size_t)row * D_ + j * 64 + lane];
        ss += v[j] * v[j];
    }
#pragma unroll
    for (int off = 32; off; off >>= 1) ss += __shfl_xor(ss, off);
    const float inv = 1.0f / fmaxf(sqrtf(ss), 1e-12f);
#pragma unroll
    for (int j = 0; j < 8; ++j) {
        const float y = v[j] * inv;
        mn[(size_t)row * D_ + j * 64 + lane] = y;
        unsigned short h, l;
        split2(y, h, l);
        mnh[(size_t)row * D_ + j * 64 + lane] = h;
        mnl[(size_t)row * D_ + j * 64 + lane] = l;
    }
}

// ------------------------------------------------- MFMA GEMM (NT), 128x128 tile
enum { EP_QKV = 0, EP_OUTPROJ = 1, EP_SIM = 2, EP_FFN1 = 3, EP_FFN2 = 4 };

template <int SPLIT, int MODE>
__global__ __launch_bounds__(256) void gemm_mf(
    const unsigned short* __restrict__ Ahg, const unsigned short* __restrict__ Alg,
    const unsigned short* __restrict__ Bhg, const unsigned short* __restrict__ Blg,
    const float* __restrict__ bias, const float* __restrict__ res,
    float* __restrict__ C,
    unsigned short* __restrict__ Ch, unsigned short* __restrict__ Cl,
    int M, int N, int K)
{
    __shared__ __align__(16) unsigned short sm[(SPLIT == 3 ? 4 : 2) * 8192];
    unsigned short* Ah = sm;
    unsigned short* Al = sm + 8192;
    unsigned short* Bh = sm + (SPLIT == 3 ? 16384 : 8192);
    unsigned short* Bl = sm + 24576;

    const int tid = threadIdx.x;
    const int lane = tid & 63;
    const int w = tid >> 6;
    const int wr = w >> 1, wc = w & 1;
    const int g = lane >> 4, ln = lane & 15;
    const int m0 = blockIdx.x * 128, n0 = blockIdx.y * 128;
    const int lrow8 = lane >> 3, lchunk = lane & 7;

    const unsigned short* gsrc;
    unsigned short* lds;
    int rbase, rofs, nblk;
    if (SPLIT == 3) {
        nblk = 16; rofs = 0;
        if (w == 0)      { gsrc = Ahg; lds = Ah; rbase = m0; }
        else if (w == 1) { gsrc = Alg; lds = Al; rbase = m0; }
        else if (w == 2) { gsrc = Bhg; lds = Bh; rbase = n0; }
        else             { gsrc = Blg; lds = Bl; rbase = n0; }
    } else {
        nblk = 8; rofs = (w & 1) * 64;
        if (w < 2) { gsrc = Ahg; lds = Ah; rbase = m0; }
        else       { gsrc = Bhg; lds = Bh; rbase = n0; }
    }

    f32x4 acc[4][4];
#pragma unroll
    for (int i = 0; i < 4; ++i)
#pragma unroll
        for (int j = 0; j < 4; ++j) acc[i][j] = (f32x4){0.f, 0.f, 0.f, 0.f};

    for (int k0 = 0; k0 < K; k0 += 64) {
#pragma unroll
        for (int blk = 0; blk < nblk; ++blk) {
            const int row = rofs + blk * 8 + lrow8;
            const int sc = lchunk ^ SW7(row);
            gld16(gsrc + (size_t)(rbase + row) * K + k0 + sc * 8,
                  lds + (rofs + blk * 8) * 64);
        }
        __syncthreads();

#pragma unroll
        for (int ks = 0; ks < 2; ++ks) {
            bf16x8 a_h[4], a_l[4], b_h[4], b_l[4];
#pragma unroll
            for (int mi = 0; mi < 4; ++mi) {
                a_h[mi] = *frag(Ah, wr * 64 + mi * 16 + ln, ks * 4 + g);
                if (SPLIT == 3) a_l[mi] = *frag(Al, wr * 64 + mi * 16 + ln, ks * 4 + g);
            }
#pragma unroll
            for (int ni = 0; ni < 4; ++ni) {
                b_h[ni] = *frag(Bh, wc * 64 + ni * 16 + ln, ks * 4 + g);
                if (SPLIT == 3) b_l[ni] = *frag(Bl, wc * 64 + ni * 16 + ln, ks * 4 + g);
            }
#pragma unroll
            for (int mi = 0; mi < 4; ++mi)
#pragma unroll
                for (int ni = 0; ni < 4; ++ni) {
                    acc[mi][ni] = __builtin_amdgcn_mfma_f32_16x16x32_bf16(
                        a_h[mi], b_h[ni], acc[mi][ni], 0, 0, 0);
                    if (SPLIT == 3) {
                        acc[mi][ni] = __builtin_amdgcn_mfma_f32_16x16x32_bf16(
                            a_h[mi], b_l[ni], acc[mi][ni], 0, 0, 0);
                        acc[mi][ni] = __builtin_amdgcn_mfma_f32_16x16x32_bf16(
                            a_l[mi], b_h[ni], acc[mi][ni], 0, 0, 0);
                    }
                }
        }
        __syncthreads();
    }

#pragma unroll
    for (int mi = 0; mi < 4; ++mi) {
#pragma unroll
        for (int ni = 0; ni < 4; ++ni) {
            const int gn = n0 + wc * 64 + ni * 16 + ln;
            const float bz = (MODE == EP_SIM) ? 0.0f : bias[gn];
#pragma unroll
            for (int r2 = 0; r2 < 4; ++r2) {
                const int gm = m0 + wr * 64 + mi * 16 + g * 4 + r2;
                float v = acc[mi][ni][r2];
                if (MODE == EP_SIM) {
                    C[(size_t)gm * N + gn] = v;   // raw dot; per-row scale is order-invariant
                } else if (MODE == EP_QKV) {
                    v += bz;
                    if (gn < D_) v *= 0.125f;     // fold 1/sqrt(DH) into Q
                    unsigned short h16, l16;
                    split2(v, h16, l16);
                    Ch[(size_t)gm * N + gn] = h16;
                    Cl[(size_t)gm * N + gn] = l16;
                } else if (MODE == EP_OUTPROJ) {
                    v += bz + res[(size_t)gm * N + gn];
                    C[(size_t)gm * N + gn] = v;
                    unsigned short h16, l16;
                    split2(v, h16, l16);
                    Ch[(size_t)gm * N + gn] = h16;
                    Cl[(size_t)gm * N + gn] = l16;
                } else if (MODE == EP_FFN1) {
                    v += bz;
                    v = 0.5f * v * (1.0f + erff(v * 0.70710678118654752f));
                    unsigned short h16, l16;
                    split2(v, h16, l16);
                    Ch[(size_t)gm * N + gn] = h16;
                } else {   // EP_FFN2
                    v += bz + res[(size_t)gm * N + gn];
                    C[(size_t)gm * N + gn] = v;
                }
            }
        }
    }
}

// ------------------------------------------------- flash attention, MFMA bf16x3
// swapped QK^T: S^T in registers (lane-local softmax); PV computes O^T.
__global__ __launch_bounds__(256, 2) void attn_kernel(
    const unsigned short* __restrict__ qkvh, const unsigned short* __restrict__ qkvl,
    unsigned short* __restrict__ ctxh, unsigned short* __restrict__ ctxl)
{
    const int id = blockIdx.x;          // 0..511
    const int bh = id & 63;
    const int qt = id >> 6;             // 0..7
    const int b = bh >> 3, h = bh & 7;
    const int tok0 = b * SEQ_ + qt * 128;
    const int kbase0 = b * SEQ_;
    const int tid = threadIdx.x;
    const int lane = tid & 63;
    const int w = tid >> 6;             // wave: 32 q-rows
    const int ln = lane & 15, g = lane >> 4;
    const int lrow8 = lane >> 3, lchunk = lane & 7;

    // 64 KB: PP u32[128][64] (Q-stage -> P -> epilogue scratch) | Kh Kl Vth Vtl
    __shared__ __align__(16) unsigned char smb[65536];
    unsigned*       PP  = (unsigned*)smb;
    unsigned short* Qh  = (unsigned short*)smb;
    unsigned short* Ql  = (unsigned short*)(smb + 16384);
    unsigned short* Kh  = (unsigned short*)(smb + 32768);
    unsigned short* Kl  = (unsigned short*)(smb + 40960);
    unsigned short* Vth = (unsigned short*)(smb + 49152);
    unsigned short* Vtl = (unsigned short*)(smb + 57344);

    const int qoff = h * 64, koff = 512 + h * 64, voff = 1024 + h * 64;

    // ---- stage Q (pre-scaled), hoist fragments
#pragma unroll
    for (int blk = 0; blk < 4; ++blk) {
        const int row = w * 32 + blk * 8 + lrow8;
        const int sc = lchunk ^ SW7(row);
        gld16(qkvh + (size_t)(tok0 + row) * 1536 + qoff + sc * 8,
              Qh + (w * 32 + blk * 8) * 64);
        gld16(qkvl + (size_t)(tok0 + row) * 1536 + qoff + sc * 8,
              Ql + (w * 32 + blk * 8) * 64);
    }
    __syncthreads();
    bf16x8 qfh[2][2], qfl[2][2];
#pragma unroll
    for (int qi = 0; qi < 2; ++qi)
#pragma unroll
        for (int ks = 0; ks < 2; ++ks) {
            qfh[qi][ks] = *frag(Qh, w * 32 + qi * 16 + ln, ks * 4 + g);
            qfl[qi][ks] = *frag(Ql, w * 32 + qi * 16 + ln, ks * 4 + g);
        }
    __syncthreads();   // Q reads done before PP reused for P

    f32x4 o[4][2];      // O^T[d-tile di][q-tile qi]
#pragma unroll
    for (int di = 0; di < 4; ++di)
#pragma unroll
        for (int qi = 0; qi < 2; ++qi) o[di][qi] = (f32x4){0.f, 0.f, 0.f, 0.f};
    float mrow2[2] = {-INFINITY, -INFINITY};
    float lrow2[2] = {0.f, 0.f};

    const int p2 = tid & 31, dc = tid >> 5;   // V staging partition

    for (int kt = 0; kt < 16; ++kt) {
        const int kb2 = kbase0 + kt * 64;
        // ---- stage K
#pragma unroll
        for (int blk = 0; blk < 2; ++blk) {
            const int row = w * 16 + blk * 8 + lrow8;
            const int sc = lchunk ^ SW7(row);
            gld16(qkvh + (size_t)(kb2 + row) * 1536 + koff + sc * 8,
                  Kh + (w * 16 + blk * 8) * 64);
            gld16(qkvl + (size_t)(kb2 + row) * 1536 + koff + sc * 8,
                  Kl + (w * 16 + blk * 8) * 64);
        }
        // ---- stage V transposed (swizzled, packed b32)
        {
            const size_t b0 = (size_t)(kb2 + 2 * p2) * 1536 + voff + dc * 8;
            const bf16x8 h0 = *(const bf16x8*)(qkvh + b0);
            const bf16x8 h1 = *(const bf16x8*)(qkvh + b0 + 1536);
            const bf16x8 l0 = *(const bf16x8*)(qkvl + b0);
            const bf16x8 l1 = *(const bf16x8*)(qkvl + b0 + 1536);
#pragma unroll
            for (int j = 0; j < 8; ++j) {
                const int d = dc * 8 + j;
                const int idx = d * 64 + (((p2 >> 2) ^ SW7(d)) << 3) + ((p2 & 3) << 1);
                *(unsigned*)&Vth[idx] = (unsigned)(unsigned short)h0[j]
                                      | ((unsigned)(unsigned short)h1[j] << 16);
                *(unsigned*)&Vtl[idx] = (unsigned)(unsigned short)l0[j]
                                      | ((unsigned)(unsigned short)l1[j] << 16);
            }
        }
        __syncthreads();

        // ---- S^T = K Q^T (bf16x3): s[ki][qi], row=k (g*4+r2), col=q (ln)
        f32x4 s[4][2];
#pragma unroll
        for (int ki = 0; ki < 4; ++ki)
#pragma unroll
            for (int qi = 0; qi < 2; ++qi) s[ki][qi] = (f32x4){0.f, 0.f, 0.f, 0.f};
        __builtin_amdgcn_s_setprio(1);
#pragma unroll
        for (int ks = 0; ks < 2; ++ks) {
            bf16x8 kbh[4], kbl[4];
#pragma unroll
            for (int ki = 0; ki < 4; ++ki) {
                kbh[ki] = *frag(Kh, ki * 16 + ln, ks * 4 + g);
                kbl[ki] = *frag(Kl, ki * 16 + ln, ks * 4 + g);
            }
#pragma unroll
            for (int ki = 0; ki < 4; ++ki)
#pragma unroll
                for (int qi = 0; qi < 2; ++qi) {
                    s[ki][qi] = __builtin_amdgcn_mfma_f32_16x16x32_bf16(kbh[ki], qfh[qi][ks], s[ki][qi], 0, 0, 0);
                    s[ki][qi] = __builtin_amdgcn_mfma_f32_16x16x32_bf16(kbh[ki], qfl[qi][ks], s[ki][qi], 0, 0, 0);
                    s[ki][qi] = __builtin_amdgcn_mfma_f32_16x16x32_bf16(kbl[ki], qfh[qi][ks], s[ki][qi], 0, 0, 0);
                }
        }
        __builtin_amdgcn_s_setprio(0);

        // ---- online softmax: lane holds 16 k-values per qi for query q=qi*16+ln
        float tm2[2], alpha2[2], psum2[2];
#pragma unroll
        for (int qi = 0; qi < 2; ++qi) {
            float m01 = fmaxf(fmaxf(s[0][qi][0], s[0][qi][1]), fmaxf(s[0][qi][2], s[0][qi][3]));
            float m23 = fmaxf(fmaxf(s[1][qi][0], s[1][qi][1]), fmaxf(s[1][qi][2], s[1][qi][3]));
            float m45 = fmaxf(fmaxf(s[2][qi][0], s[2][qi][1]), fmaxf(s[2][qi][2], s[2][qi][3]));
            float m67 = fmaxf(fmaxf(s[3][qi][0], s[3][qi][1]), fmaxf(s[3][qi][2], s[3][qi][3]));
            tm2[qi] = fmaxf(fmaxf(m01, m23), fmaxf(m45, m67));
        }
#pragma unroll
        for (int qi = 0; qi < 2; ++qi) {
            tm2[qi] = fmaxf(tm2[qi], __shfl_xor(tm2[qi], 16));
            tm2[qi] = fmaxf(tm2[qi], __shfl_xor(tm2[qi], 32));
            const float mnew = fmaxf(mrow2[qi], tm2[qi]);
            alpha2[qi] = __expf(mrow2[qi] - mnew);
            mrow2[qi] = mnew;
            psum2[qi] = 0.f;
        }
        // P = exp(S^T - m): pack (h|l<<16), b128 write, ki-XOR swizzle
#pragma unroll
        for (int qi = 0; qi < 2; ++qi)
#pragma unroll
            for (int ki = 0; ki < 4; ++ki) {
                u32x4 pv;
#pragma unroll
                for (int r2 = 0; r2 < 4; ++r2) {
                    const float p = __expf(s[ki][qi][r2] - mrow2[qi]);
                    psum2[qi] += p;
                    unsigned short h16, l16;
                    split2(p, h16, l16);
                    pv[r2] = (unsigned)h16 | ((unsigned)l16 << 16);
                }
                *(u32x4*)&PP[(w * 32 + qi * 16 + ln) * 64 + ((ki ^ (ln & 3)) << 4) + (g << 2)] = pv;
            }
#pragma unroll
        for (int qi = 0; qi < 2; ++qi) {
            psum2[qi] += __shfl_xor(psum2[qi], 16);
            psum2[qi] += __shfl_xor(psum2[qi], 32);
            lrow2[qi] = lrow2[qi] * alpha2[qi] + psum2[qi];
        }
#pragma unroll
        for (int di = 0; di < 4; ++di)
#pragma unroll
            for (int qi = 0; qi < 2; ++qi)
#pragma unroll
                for (int r2 = 0; r2 < 4; ++r2)
                    o[di][qi][r2] *= alpha2[qi];

        // ---- O^T += Vt P^T (bf16x3): a=Vt rows(d), b=P rows(q)
        __builtin_amdgcn_s_setprio(1);
#pragma unroll
        for (int ks = 0; ks < 2; ++ks) {
            bf16x8 pah[2], pal[2];
#pragma unroll
            for (int qi = 0; qi < 2; ++qi) {
                const int kiR = 2 * ks + (g >> 1);
                const unsigned* pp = PP + (w * 32 + qi * 16 + ln) * 64
                                     + (((kiR ^ (ln & 3)) << 4) + ((g & 1) << 3));
                const u32x4 q0 = *(const u32x4*)pp;
                const u32x4 q1 = *(const u32x4*)(pp + 4);
                u32x4 hu, lu;
                hu[0] = __builtin_amdgcn_perm(q0[1], q0[0], 0x05040100u);
                hu[1] = __builtin_amdgcn_perm(q0[3], q0[2], 0x05040100u);
                hu[2] = __builtin_amdgcn_perm(q1[1], q1[0], 0x05040100u);
                hu[3] = __builtin_amdgcn_perm(q1[3], q1[2], 0x05040100u);
                lu[0] = __builtin_amdgcn_perm(q0[1], q0[0], 0x07060302u);
                lu[1] = __builtin_amdgcn_perm(q0[3], q0[2], 0x07060302u);
                lu[2] = __builtin_amdgcn_perm(q1[1], q1[0], 0x07060302u);
                lu[3] = __builtin_amdgcn_perm(q1[3], q1[2], 0x07060302u);
                pah[qi] = __builtin_bit_cast(bf16x8, hu);
                pal[qi] = __builtin_bit_cast(bf16x8, lu);
            }
            bf16x8 vbh[4], vbl[4];
#pragma unroll
            for (int di = 0; di < 4; ++di) {
                vbh[di] = *frag(Vth, di * 16 + ln, ks * 4 + g);
                vbl[di] = *frag(Vtl, di * 16 + ln, ks * 4 + g);
            }
#pragma unroll
            for (int di = 0; di < 4; ++di)
#pragma unroll
                for (int qi = 0; qi < 2; ++qi) {
                    o[di][qi] = __builtin_amdgcn_mfma_f32_16x16x32_bf16(vbh[di], pah[qi], o[di][qi], 0, 0, 0);
                    o[di][qi] = __builtin_amdgcn_mfma_f32_16x16x32_bf16(vbh[di], pal[qi], o[di][qi], 0, 0, 0);
                    o[di][qi] = __builtin_amdgcn_mfma_f32_16x16x32_bf16(vbl[di], pah[qi], o[di][qi], 0, 0, 0);
                }
        }
        __builtin_amdgcn_s_setprio(0);
        __syncthreads();   // PV done before next staging overwrites K/V
    }

    // ---- epilogue: O^T -> wave-private LDS transpose (reuse PP) -> coalesced stores
#pragma unroll
    for (int di = 0; di < 4; ++di)
#pragma unroll
        for (int qi = 0; qi < 2; ++qi) {
            const float inv = 1.0f / lrow2[qi];
            u32x4 tv;
#pragma unroll
            for (int r2 = 0; r2 < 4; ++r2) {
                const float v = o[di][qi][r2] * inv;
                unsigned short h16, l16;
                split2(v, h16, l16);
                tv[r2] = (unsigned)h16 | ((unsigned)l16 << 16);
            }
            *(u32x4*)&PP[(w * 32 + qi * 16 + ln) * 64 + ((di ^ (ln & 3)) << 4) + (g << 2)] = tv;
        }
    __syncthreads();
    {
        const int qrow = lane >> 1, halfd = lane & 1;
        const size_t gbase = (size_t)(tok0 + w * 32 + qrow) * D_ + h * 64;
#pragma unroll
        for (int gi = 0; gi < 2; ++gi) {
            const int di = halfd * 2 + gi;
            const unsigned* tp = PP + (w * 32 + qrow) * 64 + ((di ^ (qrow & 3)) << 4);
#pragma unroll
            for (int pr = 0; pr < 2; ++pr) {
                const u32x4 t0 = *(const u32x4*)(tp + pr * 8);
                const u32x4 t1 = *(const u32x4*)(tp + pr * 8 + 4);
                u32x4 hv, lv;
                hv[0] = __builtin_amdgcn_perm(t0[1], t0[0], 0x05040100u);
                hv[1] = __builtin_amdgcn_perm(t0[3], t0[2], 0x05040100u);
                hv[2] = __builtin_amdgcn_perm(t1[1], t1[0], 0x05040100u);
                hv[3] = __builtin_amdgcn_perm(t1[3], t1[2], 0x05040100u);
                lv[0] = __builtin_amdgcn_perm(t0[1], t0[0], 0x07060302u);
                lv[1] = __builtin_amdgcn_perm(t0[3], t0[2], 0x07060302u);
                lv[2] = __builtin_amdgcn_perm(t1[1], t1[0], 0x07060302u);
                lv[3] = __builtin_amdgcn_perm(t1[3], t1[2], 0x07060302u);
                *(u32x4*)(ctxh + gbase + di * 16 + pr * 8) = hv;
                *(u32x4*)(ctxl + gbase + di * 16 + pr * 8) = lv;
            }
        }
    }
}

// ---- top-8 -> fp32 refine -> top-5 + softmax + gather + residual + fused LN2
__global__ __launch_bounds__(64) void topk_kernel(
    const float* __restrict__ sim, const float* __restrict__ src2,
    const float* __restrict__ mn, const float* __restrict__ mem,
    const float* __restrict__ rs_ptr, const float* __restrict__ g2,
    const float* __restrict__ b2, float* __restrict__ out,
    unsigned short* __restrict__ h2h)
{
    const int row = blockIdx.x;
    const int lane = threadIdx.x;
    float v[16];
#pragma unroll
    for (int j = 0; j < 16; ++j)
        v[j] = sim[(size_t)row * SLOTS_ + j * 64 + lane];

    int ci[NCAND_];
#pragma unroll
    for (int t = 0; t < NCAND_; ++t) {
        float bv = -INFINITY;
        int bi = 0x7fffffff;
#pragma unroll
        for (int j = 0; j < 16; ++j) {
            const int idx = j * 64 + lane;
            if (v[j] > bv) { bv = v[j]; bi = idx; }
        }
#pragma unroll
        for (int off = 32; off; off >>= 1) {
            const float ov = __shfl_xor(bv, off);
            const int oi = __shfl_xor(bi, off);
            if (ov > bv || (ov == bv && oi < bi)) { bv = ov; bi = oi; }
        }
        ci[t] = bi;
#pragma unroll
        for (int j = 0; j < 16; ++j)
            if (j * 64 + lane == bi) v[j] = -INFINITY;
    }

    float x[8];
    float ss = 0.0f;
#pragma unroll
    for (int j = 0; j < 8; ++j) {
        x[j] = src2[(size_t)row * D_ + j * 64 + lane];
        ss += x[j] * x[j];
    }
#pragma unroll
    for (int off = 32; off; off >>= 1) ss += __shfl_xor(ss, off);
    const float invn = 1.0f / fmaxf(sqrtf(ss), 1e-12f);

    float rv[NCAND_];
#pragma unroll
    for (int t = 0; t < NCAND_; ++t) {
        const float* mrow = mn + (size_t)ci[t] * D_;
        float acc = 0.0f;
#pragma unroll
        for (int j = 0; j < 8; ++j)
            acc = fmaf(x[j], mrow[j * 64 + lane], acc);
#pragma unroll
        for (int off = 32; off; off >>= 1) acc += __shfl_xor(acc, off);
        rv[t] = acc * invn;
    }

    float wv[TOPK_];
    int wi[TOPK_];
    bool used[NCAND_];
#pragma unroll
    for (int t = 0; t < NCAND_; ++t) used[t] = false;
#pragma unroll
    for (int t = 0; t < TOPK_; ++t) {
        float bv = -INFINITY;
        int bi = 0x7fffffff, bu = 0;
#pragma unroll
        for (int u = 0; u < NCAND_; ++u) {
            if (!used[u] && (rv[u] > bv || (rv[u] == bv && ci[u] < bi))) {
                bv = rv[u]; bi = ci[u]; bu = u;
            }
        }
        used[bu] = true;
        wv[t] = bv;
        wi[t] = bi;
    }

    float m = wv[0];
#pragma unroll
    for (int t = 1; t < TOPK_; ++t) m = fmaxf(m, wv[t]);
    float w[TOPK_], ssum = 0.0f;
#pragma unroll
    for (int t = 0; t < TOPK_; ++t) { w[t] = expf(wv[t] - m); ssum += w[t]; }
    const float scale = rs_ptr[0] / ssum;

    float y[8];
    float s_ = 0.f, ss2 = 0.f;
#pragma unroll
    for (int j = 0; j < 8; ++j) {
        const int d = j * 64 + lane;
        float acc = 0.0f;
#pragma unroll
        for (int t = 0; t < TOPK_; ++t)
            acc += w[t] * mem[(size_t)wi[t] * D_ + d];
        y[j] = x[j] + scale * acc;
        out[(size_t)row * D_ + d] = y[j];
        s_ += y[j];
        ss2 += y[j] * y[j];
    }
    // fused LN2 -> h2h (hi plane only; FFN is bf16)
#pragma unroll
    for (int off = 32; off; off >>= 1) {
        s_ += __shfl_xor(s_, off);
        ss2 += __shfl_xor(ss2, off);
    }
    const float mu = s_ * (1.0f / D_);
    const float var = ss2 * (1.0f / D_) - mu * mu;
    const float r = rsqrtf(var + LN_EPS_);
#pragma unroll
    for (int j = 0; j < 8; ++j) {
        const int d = j * 64 + lane;
        const float h2 = (y[j] - mu) * r * g2[d] + b2[d];
        unsigned short h16, l16;
        split2(h2, h16, l16);
        h2h[(size_t)row * D_ + d] = h16;
    }
}

// ----------------------------------------------------------------- launch
extern "C" void kernel_launch(void* const* d_in, const int* in_sizes, int n_in,
                              void* d_out, int out_size, void* d_ws, size_t ws_size,
                              hipStream_t stream)
{
    const float* src  = (const float*)d_in[0];
    const float* inw  = (const float*)d_in[1];
    const float* inb  = (const float*)d_in[2];
    const float* outw = (const float*)d_in[3];
    const float* outb = (const float*)d_in[4];
    const float* mem  = (const float*)d_in[5];
    const float* rs   = (const float*)d_in[6];
    const float* ln1g = (const float*)d_in[7];
    const float* ln1b = (const float*)d_in[8];
    const float* ln2g = (const float*)d_in[9];
    const float* ln2b = (const float*)d_in[10];
    const float* w1   = (const float*)d_in[11];
    const float* b1   = (const float*)d_in[12];
    const float* w2   = (const float*)d_in[13];
    const float* b2   = (const float*)d_in[14];
    float* out = (float*)d_out;
    char* ws = (char*)d_ws;
    const size_t MB = 1024ull * 1024ull;
    typedef unsigned short u16;

    // fixed region
    float* mn   = (float*)(ws + 0);            // 0-2
    u16* mnh    = (u16*)(ws + 2 * MB);         // 2-3
    u16* mnl    = (u16*)(ws + 3 * MB);         // 3-4
    u16* h2h    = (u16*)(ws + 4 * MB);         // 4-12 [topk .. ffn1] (over dead inw/outw splits)
    u16* inwh   = (u16*)(ws + 4 * MB);         // 4-5.5 [split .. qkv]
    u16* inwl   = (u16*)(ws + 5 * MB + 512 * 1024);
    u16* outwh  = (u16*)(ws + 7 * MB);         // 7-7.5 [split .. outproj]
    u16* outwl  = (u16*)(ws + 7 * MB + 512 * 1024);
    u16* w1h    = (u16*)(ws + 77 * MB);        // 77-79 (persists to ffn1)
    u16* w2h    = (u16*)(ws + 79 * MB);        // 79-81 (persists to ffn2)
    // dynamic
    u16* hh     = (u16*)(ws + 13 * MB);        // 13-21 [ln1 .. qkv]
    u16* hl     = (u16*)(ws + 21 * MB);        // 21-29
    u16* qkvh   = (u16*)(ws + 29 * MB);        // 29-53 [qkv .. attn]
    u16* qkvl   = (u16*)(ws + 53 * MB);        // 53-77
    u16* ctxh   = (u16*)(ws + 13 * MB);        // 13-21 [attn .. outproj]
    u16* ctxl   = (u16*)(ws + 21 * MB);        // 21-29
    float* sim  = (float*)(ws + 13 * MB);      // 13-45 [sim .. topk]
    float* src2 = (float*)(ws + 45 * MB);      // 45-61 [outproj .. topk]
    u16* src2h  = (u16*)(ws + 61 * MB);        // 61-69 [outproj .. sim]
    u16* src2l  = (u16*)(ws + 69 * MB);        // 69-77
    u16* Gbf    = (u16*)(ws + 21 * MB);        // 21-53 [ffn1 .. ffn2]

    // 0) all weight splits in one launch
    splitall_kernel<<<dim3(3072), dim3(256), 0, stream>>>(
        inw, outw, w1, w2, inwh, inwl, outwh, outwl, w1h, w2h);
    // 1) normalize memory rows
    mn_kernel<<<dim3(SLOTS_), dim3(64), 0, stream>>>(mem, mn, mnh, mnl);
    // 2) LN1 -> planes
    ln_kernel<<<dim3(NTOK_), dim3(256), 0, stream>>>(src, ln1g, ln1b, hh, hl);
    // 3) QKV projection
    gemm_mf<3, EP_QKV><<<dim3(64, 12), dim3(256), 0, stream>>>(
        hh, hl, inwh, inwl, inb, nullptr, nullptr, qkvh, qkvl, NTOK_, 1536, 512);
    // 4) attention
    attn_kernel<<<dim3(512), dim3(256), 0, stream>>>(qkvh, qkvl, ctxh, ctxl);
    // 5) out projection + residual
    gemm_mf<3, EP_OUTPROJ><<<dim3(64, 4), dim3(256), 0, stream>>>(
        ctxh, ctxl, outwh, outwl, outb, src, src2, src2h, src2l, NTOK_, 512, 512);
    // 6) sim = src2 @ mn^T (raw; row-scale is order-invariant, refined in topk)
    gemm_mf<3, EP_SIM><<<dim3(64, 8), dim3(256), 0, stream>>>(
        src2h, src2l, mnh, mnl, nullptr, nullptr, sim, nullptr, nullptr, NTOK_, 1024, 512);
    // 7) topk + retrieval + residual + fused LN2
    topk_kernel<<<dim3(NTOK_), dim3(64), 0, stream>>>(
        sim, src2, mn, mem, rs, ln2g, ln2b, out, h2h);
    // 8) FFN1 + GELU
    gemm_mf<1, EP_FFN1><<<dim3(64, 16), dim3(256), 0, stream>>>(
        h2h, nullptr, w1h, nullptr, b1, nullptr, nullptr, Gbf, nullptr, NTOK_, 2048, 512);
    // 9) FFN2 + bias + residual
    gemm_mf<1, EP_FFN2><<<dim3(64, 4), dim3(256), 0, stream>>>(
        Gbf, nullptr, w2h, nullptr, b2, out, out, nullptr, nullptr, NTOK_, 512, 2048);
}

// Round 9
// 282.939 us; speedup vs baseline: 4.1029x; 1.0705x over previous
//
#include <hip/hip_runtime.h>
#include <math.h>

#define D_ 512
#define H_ 8
#define DFF_ 2048
#define SLOTS_ 1024
#define TOPK_ 5
#define NCAND_ 8
#define NTOK_ 8192
#define SEQ_ 1024
#define LN_EPS_ 1e-5f

typedef __attribute__((ext_vector_type(8))) short bf16x8;
typedef __attribute__((ext_vector_type(4))) float f32x4;
typedef __attribute__((ext_vector_type(4))) unsigned u32x4;
typedef unsigned short u16;

// split fp32 -> bf16 hi + bf16 lo (truncation; rem captured to ~2^-16 rel)
__device__ inline void split2(float x, unsigned short& hi, unsigned short& lo) {
    unsigned u = __builtin_bit_cast(unsigned, x);
    hi = (unsigned short)(u >> 16);
    float h = __builtin_bit_cast(float, u & 0xFFFF0000u);
    float rem = x - h;
    lo = (unsigned short)(__builtin_bit_cast(unsigned, rem) >> 16);
}

__device__ __forceinline__ void gld16(const void* g, void* l) {
    __builtin_amdgcn_global_load_lds(
        (const __attribute__((address_space(1))) void*)g,
        (__attribute__((address_space(3))) void*)l, 16, 0, 0);
}

__device__ __forceinline__ int SW7(int r) { return (r ^ (r >> 3)) & 7; }
__device__ __forceinline__ const bf16x8* frag(const unsigned short* p, int r, int c) {
    return (const bf16x8*)(p + r * 64 + ((c ^ SW7(r)) << 3));
}

// ---------------------------------------------------------------- prep: weight splits + mn + LN1
__global__ __launch_bounds__(256) void prep_kernel(
    const float* __restrict__ inw, const float* __restrict__ outw,
    const float* __restrict__ w1, const float* __restrict__ w2,
    const float* __restrict__ mem, const float* __restrict__ src,
    const float* __restrict__ ln1g, const float* __restrict__ ln1b,
    u16* __restrict__ inwh, u16* __restrict__ inwl,
    u16* __restrict__ outwh, u16* __restrict__ outwl,
    u16* __restrict__ w1h, u16* __restrict__ w2h,
    float* __restrict__ mn, u16* __restrict__ mnh, u16* __restrict__ mnl,
    u16* __restrict__ hh, u16* __restrict__ hl)
{
    const int bid = blockIdx.x;
    const int t = threadIdx.x;
    if (bid < 3072) {
        // ---- weight splits
        const int i = (bid * 256 + t) * 4;
        const float* x;
        u16 *hhp, *llp;
        int base;
        if (i < 786432)       { x = inw;  hhp = inwh;  llp = inwl;  base = 0; }
        else if (i < 1048576) { x = outw; hhp = outwh; llp = outwl; base = 786432; }
        else if (i < 2097152) { x = w1;   hhp = w1h;   llp = nullptr; base = 1048576; }
        else                  { x = w2;   hhp = w2h;   llp = nullptr; base = 2097152; }
        const int j = i - base;
        const float4 v = *(const float4*)(x + j);
        const float vv[4] = {v.x, v.y, v.z, v.w};
        u16 h[4], l[4];
#pragma unroll
        for (int e = 0; e < 4; ++e) split2(vv[e], h[e], l[e]);
        hhp[j + 0] = h[0]; hhp[j + 1] = h[1]; hhp[j + 2] = h[2]; hhp[j + 3] = h[3];
        if (llp) { llp[j + 0] = l[0]; llp[j + 1] = l[1]; llp[j + 2] = l[2]; llp[j + 3] = l[3]; }
    } else if (bid < 3328) {
        // ---- memory row normalize (+planes), 4 rows/block
        const int row = (bid - 3072) * 4 + (t >> 6);
        const int lane = t & 63;
        float v[8];
        float ss = 0.0f;
#pragma unroll
        for (int j = 0; j < 8; ++j) {
            v[j] = mem[(size_t)row * D_ + j * 64 + lane];
            ss += v[j] * v[j];
        }
#pragma unroll
        for (int off = 32; off; off >>= 1) ss += __shfl_xor(ss, off);
        const float inv = 1.0f / fmaxf(sqrtf(ss), 1e-12f);
#pragma unroll
        for (int j = 0; j < 8; ++j) {
            const float y = v[j] * inv;
            mn[(size_t)row * D_ + j * 64 + lane] = y;
            u16 h, l;
            split2(y, h, l);
            mnh[(size_t)row * D_ + j * 64 + lane] = h;
            mnl[(size_t)row * D_ + j * 64 + lane] = l;
        }
    } else {
        // ---- LN1 -> planes
        const int row = bid - 3328;
        const float a = src[(size_t)row * D_ + t];
        const float b = src[(size_t)row * D_ + t + 256];
        float s = a + b;
        float ss = a * a + b * b;
#pragma unroll
        for (int off = 32; off; off >>= 1) {
            s += __shfl_xor(s, off);
            ss += __shfl_xor(ss, off);
        }
        __shared__ float rs[4], rss[4];
        if ((t & 63) == 0) { rs[t >> 6] = s; rss[t >> 6] = ss; }
        __syncthreads();
        s = rs[0] + rs[1] + rs[2] + rs[3];
        ss = rss[0] + rss[1] + rss[2] + rss[3];
        const float mu = s * (1.0f / D_);
        const float var = ss * (1.0f / D_) - mu * mu;
        const float r = rsqrtf(var + LN_EPS_);
        const float y0 = (a - mu) * r * ln1g[t] + ln1b[t];
        const float y1 = (b - mu) * r * ln1g[t + 256] + ln1b[t + 256];
        u16 h0, l0, h1, l1;
        split2(y0, h0, l0);
        split2(y1, h1, l1);
        hh[(size_t)row * D_ + t] = h0;
        hh[(size_t)row * D_ + t + 256] = h1;
        hl[(size_t)row * D_ + t] = l0;
        hl[(size_t)row * D_ + t + 256] = l1;
    }
}

// ------------------------------------------------- MFMA GEMM (NT), 128x128 tile
enum { EP_QKV = 0, EP_OUTPROJ = 1, EP_SIM = 2, EP_FFN1 = 3, EP_FFN2 = 4 };

template <int SPLIT, int MODE>
__global__ __launch_bounds__(256) void gemm_mf(
    const unsigned short* __restrict__ Ahg, const unsigned short* __restrict__ Alg,
    const unsigned short* __restrict__ Bhg, const unsigned short* __restrict__ Blg,
    const float* __restrict__ bias, const float* __restrict__ res,
    float* __restrict__ C,
    unsigned short* __restrict__ Ch, unsigned short* __restrict__ Cl,
    int M, int N, int K)
{
    __shared__ __align__(16) unsigned short sm[(SPLIT == 3 ? 4 : 2) * 8192];
    unsigned short* Ah = sm;
    unsigned short* Al = sm + 8192;
    unsigned short* Bh = sm + (SPLIT == 3 ? 16384 : 8192);
    unsigned short* Bl = sm + 24576;

    const int tid = threadIdx.x;
    const int lane = tid & 63;
    const int w = tid >> 6;
    const int wr = w >> 1, wc = w & 1;
    const int g = lane >> 4, ln = lane & 15;
    const int m0 = blockIdx.x * 128, n0 = blockIdx.y * 128;
    const int lrow8 = lane >> 3, lchunk = lane & 7;

    const unsigned short* gsrc;
    unsigned short* lds;
    int rbase, rofs, nblk;
    if (SPLIT == 3) {
        nblk = 16; rofs = 0;
        if (w == 0)      { gsrc = Ahg; lds = Ah; rbase = m0; }
        else if (w == 1) { gsrc = Alg; lds = Al; rbase = m0; }
        else if (w == 2) { gsrc = Bhg; lds = Bh; rbase = n0; }
        else             { gsrc = Blg; lds = Bl; rbase = n0; }
    } else {
        nblk = 8; rofs = (w & 1) * 64;
        if (w < 2) { gsrc = Ahg; lds = Ah; rbase = m0; }
        else       { gsrc = Bhg; lds = Bh; rbase = n0; }
    }

    f32x4 acc[4][4];
#pragma unroll
    for (int i = 0; i < 4; ++i)
#pragma unroll
        for (int j = 0; j < 4; ++j) acc[i][j] = (f32x4){0.f, 0.f, 0.f, 0.f};

    for (int k0 = 0; k0 < K; k0 += 64) {
#pragma unroll
        for (int blk = 0; blk < nblk; ++blk) {
            const int row = rofs + blk * 8 + lrow8;
            const int sc = lchunk ^ SW7(row);
            gld16(gsrc + (size_t)(rbase + row) * K + k0 + sc * 8,
                  lds + (rofs + blk * 8) * 64);
        }
        __syncthreads();

#pragma unroll
        for (int ks = 0; ks < 2; ++ks) {
            bf16x8 a_h[4], a_l[4], b_h[4], b_l[4];
#pragma unroll
            for (int mi = 0; mi < 4; ++mi) {
                a_h[mi] = *frag(Ah, wr * 64 + mi * 16 + ln, ks * 4 + g);
                if (SPLIT == 3) a_l[mi] = *frag(Al, wr * 64 + mi * 16 + ln, ks * 4 + g);
            }
#pragma unroll
            for (int ni = 0; ni < 4; ++ni) {
                b_h[ni] = *frag(Bh, wc * 64 + ni * 16 + ln, ks * 4 + g);
                if (SPLIT == 3) b_l[ni] = *frag(Bl, wc * 64 + ni * 16 + ln, ks * 4 + g);
            }
#pragma unroll
            for (int mi = 0; mi < 4; ++mi)
#pragma unroll
                for (int ni = 0; ni < 4; ++ni) {
                    acc[mi][ni] = __builtin_amdgcn_mfma_f32_16x16x32_bf16(
                        a_h[mi], b_h[ni], acc[mi][ni], 0, 0, 0);
                    if (SPLIT == 3) {
                        acc[mi][ni] = __builtin_amdgcn_mfma_f32_16x16x32_bf16(
                            a_h[mi], b_l[ni], acc[mi][ni], 0, 0, 0);
                        acc[mi][ni] = __builtin_amdgcn_mfma_f32_16x16x32_bf16(
                            a_l[mi], b_h[ni], acc[mi][ni], 0, 0, 0);
                    }
                }
        }
        __syncthreads();
    }

#pragma unroll
    for (int mi = 0; mi < 4; ++mi) {
#pragma unroll
        for (int ni = 0; ni < 4; ++ni) {
            const int gn = n0 + wc * 64 + ni * 16 + ln;
            const float bz = (MODE == EP_SIM) ? 0.0f : bias[gn];
#pragma unroll
            for (int r2 = 0; r2 < 4; ++r2) {
                const int gm = m0 + wr * 64 + mi * 16 + g * 4 + r2;
                float v = acc[mi][ni][r2];
                if (MODE == EP_SIM) {
                    C[(size_t)gm * N + gn] = v;   // raw dot; order-invariant, refined in topk
                } else if (MODE == EP_QKV) {
                    v += bz;
                    if (gn < D_) v *= 0.125f;     // fold 1/sqrt(DH) into Q
                    unsigned short h16, l16;
                    split2(v, h16, l16);
                    Ch[(size_t)gm * N + gn] = h16;
                    Cl[(size_t)gm * N + gn] = l16;
                } else if (MODE == EP_OUTPROJ) {
                    v += bz + res[(size_t)gm * N + gn];
                    C[(size_t)gm * N + gn] = v;
                    unsigned short h16, l16;
                    split2(v, h16, l16);
                    Ch[(size_t)gm * N + gn] = h16;   // hi plane only (sim is SPLIT1)
                } else if (MODE == EP_FFN1) {
                    v += bz;
                    v = 0.5f * v * (1.0f + erff(v * 0.70710678118654752f));
                    unsigned short h16, l16;
                    split2(v, h16, l16);
                    Ch[(size_t)gm * N + gn] = h16;
                } else {   // EP_FFN2
                    v += bz + res[(size_t)gm * N + gn];
                    C[(size_t)gm * N + gn] = v;
                }
            }
        }
    }
}

// ------------------------------------------------- flash attention, MFMA bf16x3
// swapped QK^T: S^T in registers (lane-local softmax); PV computes O^T.
// P chunks (4 dwords) XOR-swizzled by row&7 -> conflict-free per 16-lane quarter.
__global__ __launch_bounds__(256, 2) void attn_kernel(
    const unsigned short* __restrict__ qkvh, const unsigned short* __restrict__ qkvl,
    unsigned short* __restrict__ ctxh, unsigned short* __restrict__ ctxl)
{
    const int id = blockIdx.x;          // 0..511
    const int bh = id & 63;
    const int qt = id >> 6;             // 0..7
    const int b = bh >> 3, h = bh & 7;
    const int tok0 = b * SEQ_ + qt * 128;
    const int kbase0 = b * SEQ_;
    const int tid = threadIdx.x;
    const int lane = tid & 63;
    const int w = tid >> 6;             // wave: 32 q-rows
    const int ln = lane & 15, g = lane >> 4;
    const int lrow8 = lane >> 3, lchunk = lane & 7;

    __shared__ __align__(16) unsigned char smb[65536];
    unsigned*       PP  = (unsigned*)smb;
    unsigned short* Qh  = (unsigned short*)smb;
    unsigned short* Ql  = (unsigned short*)(smb + 16384);
    unsigned short* Kh  = (unsigned short*)(smb + 32768);
    unsigned short* Kl  = (unsigned short*)(smb + 40960);
    unsigned short* Vth = (unsigned short*)(smb + 49152);
    unsigned short* Vtl = (unsigned short*)(smb + 57344);

    const int qoff = h * 64, koff = 512 + h * 64, voff = 1024 + h * 64;

    // ---- stage Q (pre-scaled), hoist fragments
#pragma unroll
    for (int blk = 0; blk < 4; ++blk) {
        const int row = w * 32 + blk * 8 + lrow8;
        const int sc = lchunk ^ SW7(row);
        gld16(qkvh + (size_t)(tok0 + row) * 1536 + qoff + sc * 8,
              Qh + (w * 32 + blk * 8) * 64);
        gld16(qkvl + (size_t)(tok0 + row) * 1536 + qoff + sc * 8,
              Ql + (w * 32 + blk * 8) * 64);
    }
    __syncthreads();
    bf16x8 qfh[2][2], qfl[2][2];
#pragma unroll
    for (int qi = 0; qi < 2; ++qi)
#pragma unroll
        for (int ks = 0; ks < 2; ++ks) {
            qfh[qi][ks] = *frag(Qh, w * 32 + qi * 16 + ln, ks * 4 + g);
            qfl[qi][ks] = *frag(Ql, w * 32 + qi * 16 + ln, ks * 4 + g);
        }
    __syncthreads();   // Q reads done before PP reused for P

    f32x4 o[4][2];      // O^T[d-tile di][q-tile qi]
#pragma unroll
    for (int di = 0; di < 4; ++di)
#pragma unroll
        for (int qi = 0; qi < 2; ++qi) o[di][qi] = (f32x4){0.f, 0.f, 0.f, 0.f};
    float mrow2[2] = {-INFINITY, -INFINITY};
    float lrow2[2] = {0.f, 0.f};

    const int p2 = tid & 31, dc = tid >> 5;   // V staging partition

    for (int kt = 0; kt < 16; ++kt) {
        const int kb2 = kbase0 + kt * 64;
        // ---- stage K
#pragma unroll
        for (int blk = 0; blk < 2; ++blk) {
            const int row = w * 16 + blk * 8 + lrow8;
            const int sc = lchunk ^ SW7(row);
            gld16(qkvh + (size_t)(kb2 + row) * 1536 + koff + sc * 8,
                  Kh + (w * 16 + blk * 8) * 64);
            gld16(qkvl + (size_t)(kb2 + row) * 1536 + koff + sc * 8,
                  Kl + (w * 16 + blk * 8) * 64);
        }
        // ---- stage V transposed (swizzled, packed b32)
        {
            const size_t b0 = (size_t)(kb2 + 2 * p2) * 1536 + voff + dc * 8;
            const bf16x8 h0 = *(const bf16x8*)(qkvh + b0);
            const bf16x8 h1 = *(const bf16x8*)(qkvh + b0 + 1536);
            const bf16x8 l0 = *(const bf16x8*)(qkvl + b0);
            const bf16x8 l1 = *(const bf16x8*)(qkvl + b0 + 1536);
#pragma unroll
            for (int j = 0; j < 8; ++j) {
                const int d = dc * 8 + j;
                const int idx = d * 64 + (((p2 >> 2) ^ SW7(d)) << 3) + ((p2 & 3) << 1);
                *(unsigned*)&Vth[idx] = (unsigned)(unsigned short)h0[j]
                                      | ((unsigned)(unsigned short)h1[j] << 16);
                *(unsigned*)&Vtl[idx] = (unsigned)(unsigned short)l0[j]
                                      | ((unsigned)(unsigned short)l1[j] << 16);
            }
        }
        __syncthreads();

        // ---- S^T = K Q^T (bf16x3): s[ki][qi], row=k (g*4+r2), col=q (ln)
        f32x4 s[4][2];
#pragma unroll
        for (int ki = 0; ki < 4; ++ki)
#pragma unroll
            for (int qi = 0; qi < 2; ++qi) s[ki][qi] = (f32x4){0.f, 0.f, 0.f, 0.f};
        __builtin_amdgcn_s_setprio(1);
#pragma unroll
        for (int ks = 0; ks < 2; ++ks) {
            bf16x8 kbh[4], kbl[4];
#pragma unroll
            for (int ki = 0; ki < 4; ++ki) {
                kbh[ki] = *frag(Kh, ki * 16 + ln, ks * 4 + g);
                kbl[ki] = *frag(Kl, ki * 16 + ln, ks * 4 + g);
            }
#pragma unroll
            for (int ki = 0; ki < 4; ++ki)
#pragma unroll
                for (int qi = 0; qi < 2; ++qi) {
                    s[ki][qi] = __builtin_amdgcn_mfma_f32_16x16x32_bf16(kbh[ki], qfh[qi][ks], s[ki][qi], 0, 0, 0);
                    s[ki][qi] = __builtin_amdgcn_mfma_f32_16x16x32_bf16(kbh[ki], qfl[qi][ks], s[ki][qi], 0, 0, 0);
                    s[ki][qi] = __builtin_amdgcn_mfma_f32_16x16x32_bf16(kbl[ki], qfh[qi][ks], s[ki][qi], 0, 0, 0);
                }
        }
        __builtin_amdgcn_s_setprio(0);

        // ---- online softmax: lane holds 16 k-values per qi for query q=qi*16+ln
        float tm2[2], alpha2[2], psum2[2];
#pragma unroll
        for (int qi = 0; qi < 2; ++qi) {
            float m01 = fmaxf(fmaxf(s[0][qi][0], s[0][qi][1]), fmaxf(s[0][qi][2], s[0][qi][3]));
            float m23 = fmaxf(fmaxf(s[1][qi][0], s[1][qi][1]), fmaxf(s[1][qi][2], s[1][qi][3]));
            float m45 = fmaxf(fmaxf(s[2][qi][0], s[2][qi][1]), fmaxf(s[2][qi][2], s[2][qi][3]));
            float m67 = fmaxf(fmaxf(s[3][qi][0], s[3][qi][1]), fmaxf(s[3][qi][2], s[3][qi][3]));
            tm2[qi] = fmaxf(fmaxf(m01, m23), fmaxf(m45, m67));
        }
#pragma unroll
        for (int qi = 0; qi < 2; ++qi) {
            tm2[qi] = fmaxf(tm2[qi], __shfl_xor(tm2[qi], 16));
            tm2[qi] = fmaxf(tm2[qi], __shfl_xor(tm2[qi], 32));
            const float mnew = fmaxf(mrow2[qi], tm2[qi]);
            alpha2[qi] = __expf(mrow2[qi] - mnew);
            mrow2[qi] = mnew;
            psum2[qi] = 0.f;
        }
        // P = exp(S^T - m): pack (h|l<<16); chunk (ki*4+g) ^ (ln&7) -> conflict-free
#pragma unroll
        for (int qi = 0; qi < 2; ++qi)
#pragma unroll
            for (int ki = 0; ki < 4; ++ki) {
                u32x4 pv;
#pragma unroll
                for (int r2 = 0; r2 < 4; ++r2) {
                    const float p = __expf(s[ki][qi][r2] - mrow2[qi]);
                    psum2[qi] += p;
                    unsigned short h16, l16;
                    split2(p, h16, l16);
                    pv[r2] = (unsigned)h16 | ((unsigned)l16 << 16);
                }
                *(u32x4*)&PP[(w * 32 + qi * 16 + ln) * 64 + (((ki * 4 + g) ^ (ln & 7)) << 2)] = pv;
            }
#pragma unroll
        for (int qi = 0; qi < 2; ++qi) {
            psum2[qi] += __shfl_xor(psum2[qi], 16);
            psum2[qi] += __shfl_xor(psum2[qi], 32);
            lrow2[qi] = lrow2[qi] * alpha2[qi] + psum2[qi];
        }
#pragma unroll
        for (int di = 0; di < 4; ++di)
#pragma unroll
            for (int qi = 0; qi < 2; ++qi)
#pragma unroll
                for (int r2 = 0; r2 < 4; ++r2)
                    o[di][qi][r2] *= alpha2[qi];

        // ---- O^T += Vt P^T (bf16x3)
        __builtin_amdgcn_s_setprio(1);
#pragma unroll
        for (int ks = 0; ks < 2; ++ks) {
            bf16x8 pah[2], pal[2];
#pragma unroll
            for (int qi = 0; qi < 2; ++qi) {
                const unsigned* rowp = PP + (w * 32 + qi * 16 + ln) * 64;
                const int c0 = (2 * ks + (g >> 1)) * 4 + (g & 1) * 2;
                const u32x4 q0 = *(const u32x4*)(rowp + (((c0    ) ^ (ln & 7)) << 2));
                const u32x4 q1 = *(const u32x4*)(rowp + (((c0 + 1) ^ (ln & 7)) << 2));
                u32x4 hu, lu;
                hu[0] = __builtin_amdgcn_perm(q0[1], q0[0], 0x05040100u);
                hu[1] = __builtin_amdgcn_perm(q0[3], q0[2], 0x05040100u);
                hu[2] = __builtin_amdgcn_perm(q1[1], q1[0], 0x05040100u);
                hu[3] = __builtin_amdgcn_perm(q1[3], q1[2], 0x05040100u);
                lu[0] = __builtin_amdgcn_perm(q0[1], q0[0], 0x07060302u);
                lu[1] = __builtin_amdgcn_perm(q0[3], q0[2], 0x07060302u);
                lu[2] = __builtin_amdgcn_perm(q1[1], q1[0], 0x07060302u);
                lu[3] = __builtin_amdgcn_perm(q1[3], q1[2], 0x07060302u);
                pah[qi] = __builtin_bit_cast(bf16x8, hu);
                pal[qi] = __builtin_bit_cast(bf16x8, lu);
            }
            bf16x8 vbh[4], vbl[4];
#pragma unroll
            for (int di = 0; di < 4; ++di) {
                vbh[di] = *frag(Vth, di * 16 + ln, ks * 4 + g);
                vbl[di] = *frag(Vtl, di * 16 + ln, ks * 4 + g);
            }
#pragma unroll
            for (int di = 0; di < 4; ++di)
#pragma unroll
                for (int qi = 0; qi < 2; ++qi) {
                    o[di][qi] = __builtin_amdgcn_mfma_f32_16x16x32_bf16(vbh[di], pah[qi], o[di][qi], 0, 0, 0);
                    o[di][qi] = __builtin_amdgcn_mfma_f32_16x16x32_bf16(vbh[di], pal[qi], o[di][qi], 0, 0, 0);
                    o[di][qi] = __builtin_amdgcn_mfma_f32_16x16x32_bf16(vbl[di], pah[qi], o[di][qi], 0, 0, 0);
                }
        }
        __builtin_amdgcn_s_setprio(0);
        __syncthreads();   // PV done before next staging overwrites K/V
    }

    // ---- epilogue: O^T -> wave-private LDS transpose (reuse PP) -> coalesced stores
#pragma unroll
    for (int di = 0; di < 4; ++di)
#pragma unroll
        for (int qi = 0; qi < 2; ++qi) {
            const float inv = 1.0f / lrow2[qi];
            u32x4 tv;
#pragma unroll
            for (int r2 = 0; r2 < 4; ++r2) {
                const float v = o[di][qi][r2] * inv;
                unsigned short h16, l16;
                split2(v, h16, l16);
                tv[r2] = (unsigned)h16 | ((unsigned)l16 << 16);
            }
            *(u32x4*)&PP[(w * 32 + qi * 16 + ln) * 64 + (((di * 4 + g) ^ (ln & 7)) << 2)] = tv;
        }
    __syncthreads();
    {
        const int qrow = lane >> 1, halfd = lane & 1;
        const unsigned* rowp = PP + (w * 32 + qrow) * 64;
        const size_t gbase = (size_t)(tok0 + w * 32 + qrow) * D_ + h * 64;
#pragma unroll
        for (int gi = 0; gi < 2; ++gi) {
            const int di = halfd * 2 + gi;
#pragma unroll
            for (int pr = 0; pr < 2; ++pr) {
                const int c = di * 4 + pr * 2;
                const u32x4 t0 = *(const u32x4*)(rowp + (((c    ) ^ (qrow & 7)) << 2));
                const u32x4 t1 = *(const u32x4*)(rowp + (((c + 1) ^ (qrow & 7)) << 2));
                u32x4 hv, lv;
                hv[0] = __builtin_amdgcn_perm(t0[1], t0[0], 0x05040100u);
                hv[1] = __builtin_amdgcn_perm(t0[3], t0[2], 0x05040100u);
                hv[2] = __builtin_amdgcn_perm(t1[1], t1[0], 0x05040100u);
                hv[3] = __builtin_amdgcn_perm(t1[3], t1[2], 0x05040100u);
                lv[0] = __builtin_amdgcn_perm(t0[1], t0[0], 0x07060302u);
                lv[1] = __builtin_amdgcn_perm(t0[3], t0[2], 0x07060302u);
                lv[2] = __builtin_amdgcn_perm(t1[1], t1[0], 0x07060302u);
                lv[3] = __builtin_amdgcn_perm(t1[3], t1[2], 0x07060302u);
                *(u32x4*)(ctxh + gbase + di * 16 + pr * 8) = hv;
                *(u32x4*)(ctxl + gbase + di * 16 + pr * 8) = lv;
            }
        }
    }
}

// ---- top-8 -> fp32 refine -> top-5 + softmax + gather + residual + fused LN2
__global__ __launch_bounds__(64) void topk_kernel(
    const float* __restrict__ sim, const float* __restrict__ src2,
    const float* __restrict__ mn, const float* __restrict__ mem,
    const float* __restrict__ rs_ptr, const float* __restrict__ g2,
    const float* __restrict__ b2, float* __restrict__ out,
    unsigned short* __restrict__ h2h)
{
    const int row = blockIdx.x;
    const int lane = threadIdx.x;
    float v[16];
#pragma unroll
    for (int j = 0; j < 16; ++j)
        v[j] = sim[(size_t)row * SLOTS_ + j * 64 + lane];

    int ci[NCAND_];
#pragma unroll
    for (int t = 0; t < NCAND_; ++t) {
        float bv = -INFINITY;
        int bi = 0x7fffffff;
#pragma unroll
        for (int j = 0; j < 16; ++j) {
            const int idx = j * 64 + lane;
            if (v[j] > bv) { bv = v[j]; bi = idx; }
        }
#pragma unroll
        for (int off = 32; off; off >>= 1) {
            const float ov = __shfl_xor(bv, off);
            const int oi = __shfl_xor(bi, off);
            if (ov > bv || (ov == bv && oi < bi)) { bv = ov; bi = oi; }
        }
        ci[t] = bi;
#pragma unroll
        for (int j = 0; j < 16; ++j)
            if (j * 64 + lane == bi) v[j] = -INFINITY;
    }

    float x[8];
    float ss = 0.0f;
#pragma unroll
    for (int j = 0; j < 8; ++j) {
        x[j] = src2[(size_t)row * D_ + j * 64 + lane];
        ss += x[j] * x[j];
    }
#pragma unroll
    for (int off = 32; off; off >>= 1) ss += __shfl_xor(ss, off);
    const float invn = 1.0f / fmaxf(sqrtf(ss), 1e-12f);

    float rv[NCAND_];
#pragma unroll
    for (int t = 0; t < NCAND_; ++t) {
        const float* mrow = mn + (size_t)ci[t] * D_;
        float acc = 0.0f;
#pragma unroll
        for (int j = 0; j < 8; ++j)
            acc = fmaf(x[j], mrow[j * 64 + lane], acc);
#pragma unroll
        for (int off = 32; off; off >>= 1) acc += __shfl_xor(acc, off);
        rv[t] = acc * invn;
    }

    float wv[TOPK_];
    int wi[TOPK_];
    bool used[NCAND_];
#pragma unroll
    for (int t = 0; t < NCAND_; ++t) used[t] = false;
#pragma unroll
    for (int t = 0; t < TOPK_; ++t) {
        float bv = -INFINITY;
        int bi = 0x7fffffff, bu = 0;
#pragma unroll
        for (int u = 0; u < NCAND_; ++u) {
            if (!used[u] && (rv[u] > bv || (rv[u] == bv && ci[u] < bi))) {
                bv = rv[u]; bi = ci[u]; bu = u;
            }
        }
        used[bu] = true;
        wv[t] = bv;
        wi[t] = bi;
    }

    float m = wv[0];
#pragma unroll
    for (int t = 1; t < TOPK_; ++t) m = fmaxf(m, wv[t]);
    float w[TOPK_], ssum = 0.0f;
#pragma unroll
    for (int t = 0; t < TOPK_; ++t) { w[t] = __expf(wv[t] - m); ssum += w[t]; }
    const float scale = rs_ptr[0] / ssum;

    float y[8];
    float s_ = 0.f, ss2 = 0.f;
#pragma unroll
    for (int j = 0; j < 8; ++j) {
        const int d = j * 64 + lane;
        float acc = 0.0f;
#pragma unroll
        for (int t = 0; t < TOPK_; ++t)
            acc += w[t] * mem[(size_t)wi[t] * D_ + d];
        y[j] = x[j] + scale * acc;
        out[(size_t)row * D_ + d] = y[j];
        s_ += y[j];
        ss2 += y[j] * y[j];
    }
#pragma unroll
    for (int off = 32; off; off >>= 1) {
        s_ += __shfl_xor(s_, off);
        ss2 += __shfl_xor(ss2, off);
    }
    const float mu = s_ * (1.0f / D_);
    const float var = ss2 * (1.0f / D_) - mu * mu;
    const float r = rsqrtf(var + LN_EPS_);
#pragma unroll
    for (int j = 0; j < 8; ++j) {
        const int d = j * 64 + lane;
        const float h2 = (y[j] - mu) * r * g2[d] + b2[d];
        unsigned short h16, l16;
        split2(h2, h16, l16);
        h2h[(size_t)row * D_ + d] = h16;
    }
}

// ----------------------------------------------------------------- launch
extern "C" void kernel_launch(void* const* d_in, const int* in_sizes, int n_in,
                              void* d_out, int out_size, void* d_ws, size_t ws_size,
                              hipStream_t stream)
{
    const float* src  = (const float*)d_in[0];
    const float* inw  = (const float*)d_in[1];
    const float* inb  = (const float*)d_in[2];
    const float* outw = (const float*)d_in[3];
    const float* outb = (const float*)d_in[4];
    const float* mem  = (const float*)d_in[5];
    const float* rs   = (const float*)d_in[6];
    const float* ln1g = (const float*)d_in[7];
    const float* ln1b = (const float*)d_in[8];
    const float* ln2g = (const float*)d_in[9];
    const float* ln2b = (const float*)d_in[10];
    const float* w1   = (const float*)d_in[11];
    const float* b1   = (const float*)d_in[12];
    const float* w2   = (const float*)d_in[13];
    const float* b2   = (const float*)d_in[14];
    float* out = (float*)d_out;
    char* ws = (char*)d_ws;
    const size_t MB = 1024ull * 1024ull;

    // fixed region
    float* mn   = (float*)(ws + 0);            // 0-2
    u16* mnh    = (u16*)(ws + 2 * MB);         // 2-3
    u16* mnl    = (u16*)(ws + 3 * MB);         // 3-4
    u16* h2h    = (u16*)(ws + 4 * MB);         // 4-12 [topk .. ffn1]
    u16* inwh   = (u16*)(ws + 4 * MB);         // 4-5.5 [prep .. qkv]
    u16* inwl   = (u16*)(ws + 5 * MB + 512 * 1024);
    u16* outwh  = (u16*)(ws + 7 * MB);         // 7-7.5 [prep .. outproj]
    u16* outwl  = (u16*)(ws + 7 * MB + 512 * 1024);
    u16* w1h    = (u16*)(ws + 77 * MB);        // 77-79
    u16* w2h    = (u16*)(ws + 79 * MB);        // 79-81
    // dynamic
    u16* hh     = (u16*)(ws + 13 * MB);        // 13-21 [prep .. qkv]
    u16* hl     = (u16*)(ws + 21 * MB);        // 21-29
    u16* qkvh   = (u16*)(ws + 29 * MB);        // 29-53 [qkv .. attn]
    u16* qkvl   = (u16*)(ws + 53 * MB);        // 53-77
    u16* ctxh   = (u16*)(ws + 13 * MB);        // 13-21 [attn .. outproj]
    u16* ctxl   = (u16*)(ws + 21 * MB);        // 21-29
    float* sim  = (float*)(ws + 13 * MB);      // 13-45 [sim .. topk]
    float* src2 = (float*)(ws + 45 * MB);      // 45-61 [outproj .. topk]
    u16* src2h  = (u16*)(ws + 61 * MB);        // 61-69 [outproj .. sim]
    u16* Gbf    = (u16*)(ws + 21 * MB);        // 21-53 [ffn1 .. ffn2]

    // 0) prep: weight splits + memory normalize + LN1
    prep_kernel<<<dim3(11520), dim3(256), 0, stream>>>(
        inw, outw, w1, w2, mem, src, ln1g, ln1b,
        inwh, inwl, outwh, outwl, w1h, w2h, mn, mnh, mnl, hh, hl);
    // 1) QKV projection
    gemm_mf<3, EP_QKV><<<dim3(64, 12), dim3(256), 0, stream>>>(
        hh, hl, inwh, inwl, inb, nullptr, nullptr, qkvh, qkvl, NTOK_, 1536, 512);
    // 2) attention
    attn_kernel<<<dim3(512), dim3(256), 0, stream>>>(qkvh, qkvl, ctxh, ctxl);
    // 3) out projection + residual
    gemm_mf<3, EP_OUTPROJ><<<dim3(64, 4), dim3(256), 0, stream>>>(
        ctxh, ctxl, outwh, outwl, outb, src, src2, src2h, nullptr, NTOK_, 512, 512);
    // 4) sim = src2 @ mn^T (bf16-hi only; candidate set refined in fp32 in topk)
    gemm_mf<1, EP_SIM><<<dim3(64, 8), dim3(256), 0, stream>>>(
        src2h, nullptr, mnh, nullptr, nullptr, nullptr, sim, nullptr, nullptr, NTOK_, 1024, 512);
    // 5) topk + retrieval + residual + fused LN2
    topk_kernel<<<dim3(NTOK_), dim3(64), 0, stream>>>(
        sim, src2, mn, mem, rs, ln2g, ln2b, out, h2h);
    // 6) FFN1 + GELU
    gemm_mf<1, EP_FFN1><<<dim3(64, 16), dim3(256), 0, stream>>>(
        h2h, nullptr, w1h, nullptr, b1, nullptr, nullptr, Gbf, nullptr, NTOK_, 2048, 512);
    // 7) FFN2 + bias + residual
    gemm_mf<1, EP_FFN2><<<dim3(64, 4), dim3(256), 0, stream>>>(
        Gbf, nullptr, w2h, nullptr, b2, out, out, nullptr, nullptr, NTOK_, 512, 2048);
}